// Round 10
// baseline (714.669 us; speedup 1.0000x reference)
//
#include <hip/hip_runtime.h>
#include <math.h>

// Problem constants
#define Bb 8
#define Nn 1024
#define Dd 768
#define Hh 12
#define Mm 8192   // Bb*Nn

typedef __attribute__((ext_vector_type(4))) float f32x4;
typedef __attribute__((ext_vector_type(8))) __bf16 bf16x8;

__device__ __forceinline__ float bf2f(unsigned short u) {
  union { unsigned int i; float f; } v; v.i = ((unsigned int)u) << 16; return v.f;
}
__device__ __forceinline__ unsigned short f2bf(float f) {
  union { float f; unsigned int i; } v; v.f = f;
  unsigned int u = v.i;
  return (unsigned short)((u + 0x7FFFu + ((u >> 16) & 1u)) >> 16);
}
__device__ __forceinline__ unsigned int pack2bf(float a, float b) {
  union { __bf16 h[2]; unsigned int u; } x;
  x.h[0] = (__bf16)a; x.h[1] = (__bf16)b; return x.u;
}

__device__ __forceinline__ void gload16(const void* g, void* l) {
  __builtin_amdgcn_global_load_lds(
      (const __attribute__((address_space(1))) unsigned int*)g,
      (__attribute__((address_space(3))) unsigned int*)l, 16, 0, 0);
}

// Branch-free GELU (erf via Abramowitz-Stegun 7.1.26, |eps|<=1.5e-7)
__device__ __forceinline__ float gelu_f(float v) {
  const float z = fabsf(v) * 0.7071067811865475f;
  const float t = __builtin_amdgcn_rcpf(1.f + 0.3275911f * z);
  const float poly = t*(0.254829592f + t*(-0.284496736f + t*(1.421413741f +
                     t*(-1.453152027f + t*1.061405429f))));
  float er = 1.f - poly * __expf(-z * z);
  er = copysignf(er, v);
  return 0.5f * v * (1.f + er);
}

// ---------------- GEMM: C[M,N] = epi(A[M,K] * Bt[N,K]^T + bias) ----------------
// BK=64 K-step, 2-phase. LDS rows 128B pitch, T2 XOR-swizzle (rule-#21 pattern).
// NT = 128 or 64. XCD-chunked bijective swizzle (m204).
// EPI 0: store bf16; 1: GELU->bf16; 2: Res += scale*v; 3: GLU (N/2 bf16);
// EPI 4: Res = Xin + scale*v; EPI 5: qkv with fused V-transpose (V cols -> Vtr)
template<int EPI, int NT>
__global__ __launch_bounds__(256)
void gemm_bt(const unsigned short* __restrict__ A,
             const unsigned short* __restrict__ Bt,
             const float* __restrict__ bias,
             unsigned short* __restrict__ Cbf,
             float* __restrict__ Res,
             const float* __restrict__ Xin,
             unsigned short* __restrict__ Vtr,
             int M, int N, int K, float scale)
{
  __shared__ __align__(16) unsigned short Asm[128*64];
  __shared__ __align__(16) unsigned short Bsm[NT*64];
  const int tid = threadIdx.x;
  const int wv = tid >> 6, lane = tid & 63;
  const int lr = lane & 15, lg = lane >> 4;
  const int wr = wv >> 1, wc = wv & 1;
  constexpr int JN = NT / 32;       // col-groups of 16 per wave

  // ---- bijective XCD-chunked swizzle ----
  const int gx = gridDim.x, gy = gridDim.y;
  const int nwg = gx * gy;
  const int lin = blockIdx.y * gx + blockIdx.x;
  const int q8 = nwg >> 3, r8 = nwg & 7;
  const int xcd = lin & 7, lidx = lin >> 3;
  const int wg = ((xcd < r8) ? xcd * (q8 + 1) : r8 * (q8 + 1) + (xcd - r8) * q8) + lidx;
  const int bx = wg % gx;
  const int by = wg / gx;

  const int n0 = bx * NT, m0 = by * 128;

  f32x4 acc[4][JN] = {};

  const int srow8 = lane >> 3;                    // row within 8-row group
  const int scol  = ((lane & 7) ^ srow8) * 8;     // pre-swizzled source col (elems)
  const unsigned short* Agp = A + (size_t)(m0 + wv*32 + srow8)*K + scol;
  const unsigned short* Bgp = (NT == 128)
      ? Bt + (size_t)(n0 + wv*32 + srow8)*K + scol
      : Bt + (size_t)(n0 + wv*16 + srow8)*K + scol;
  const int swr = (lr & 7) << 4;                  // read-side XOR (bytes)

  for (int kt = 0; kt < K; kt += 64) {
#pragma unroll
    for (int k = 0; k < 4; k++)
      gload16(Agp + (size_t)(k*8)*K + kt, Asm + (wv*32 + k*8)*64);
    if (NT == 128) {
#pragma unroll
      for (int k = 0; k < 4; k++)
        gload16(Bgp + (size_t)(k*8)*K + kt, Bsm + (wv*32 + k*8)*64);
    } else {
#pragma unroll
      for (int k = 0; k < 2; k++)
        gload16(Bgp + (size_t)(k*8)*K + kt, Bsm + (wv*16 + k*8)*64);
    }
    __syncthreads();   // drains vmcnt -> LDS tiles ready
    bf16x8 af[4], af2[4], bfr[JN], bfr2[JN];
#pragma unroll
    for (int i = 0; i < 4; i++) {
      const char* base = (const char*)Asm + (wr*64 + i*16 + lr)*128;
      af[i]  = *(const bf16x8*)(base + ((lg*16)      ^ swr));
      af2[i] = *(const bf16x8*)(base + ((lg*16 + 64) ^ swr));
    }
#pragma unroll
    for (int j = 0; j < JN; j++) {
      const char* base = (const char*)Bsm + (wc*(NT/2) + j*16 + lr)*128;
      bfr[j]  = *(const bf16x8*)(base + ((lg*16)      ^ swr));
      bfr2[j] = *(const bf16x8*)(base + ((lg*16 + 64) ^ swr));
    }
#pragma unroll
    for (int i = 0; i < 4; i++)
#pragma unroll
      for (int j = 0; j < JN; j++) {
        acc[i][j] = __builtin_amdgcn_mfma_f32_16x16x32_bf16(af[i],  bfr[j],  acc[i][j], 0, 0, 0);
        acc[i][j] = __builtin_amdgcn_mfma_f32_16x16x32_bf16(af2[i], bfr2[j], acc[i][j], 0, 0, 0);
      }
    __syncthreads();   // compute done before next stage overwrites
  }

#pragma unroll
  for (int i = 0; i < 4; i++) {
    const int rg = m0 + wr*64 + i*16 + lg*4;
    if (EPI == 3) {
      // GLU: col-groups alternate u (even) / gate (odd); write N/2 bf16 cols
#pragma unroll
      for (int j = 0; j < JN; j += 2) {
        const int cgu = n0 + wc*(NT/2) + j*16 + lr;
        const float bu = bias[cgu], bg = bias[cgu + 16];
        const int ocol = (n0 >> 1) + wc*(NT/4) + (j >> 1)*16 + lr;
#pragma unroll
        for (int e = 0; e < 4; e++) {
          float u  = acc[i][j][e]   + bu;
          float gt = acc[i][j+1][e] + bg;
          Cbf[(size_t)(rg + e) * (N >> 1) + ocol] = f2bf(u / (1.f + __expf(-gt)));
        }
      }
    } else if (EPI == 5 && n0 >= 1536) {
      // V columns: write transposed into Vtr[(b*Hh+h)*64 + d][n]
#pragma unroll
      for (int j = 0; j < JN; j++) {
        const int cg = n0 + wc*(NT/2) + j*16 + lr;
        const float bv = bias[cg];
        const int vo = cg - 1536;
        const int hh = vo >> 6, d = vo & 63;
        const int bb_ = rg >> 10, nn_ = rg & 1023;
        ushort4 o4;
        o4.x = f2bf(acc[i][j][0] + bv);
        o4.y = f2bf(acc[i][j][1] + bv);
        o4.z = f2bf(acc[i][j][2] + bv);
        o4.w = f2bf(acc[i][j][3] + bv);
        *(ushort4*)(Vtr + (((size_t)bb_*Hh + hh)*64 + d)*1024 + nn_) = o4;
      }
    } else {
#pragma unroll
      for (int j = 0; j < JN; j++) {
        const int cg = n0 + wc*(NT/2) + j*16 + lr;
        const float bv = bias[cg];
#pragma unroll
        for (int e = 0; e < 4; e++) {
          float v = acc[i][j][e] + bv;
          const size_t idx = (size_t)(rg + e) * N + cg;
          if (EPI == 1) {
            Cbf[idx] = f2bf(gelu_f(v));
          } else if (EPI == 0 || EPI == 5) {
            Cbf[idx] = f2bf(v);
          } else if (EPI == 2) {
            Res[idx] += scale * v;
          } else {  // EPI 4
            Res[idx] = Xin[idx] + scale * v;
          }
        }
      }
    }
  }
}

// ---------------- LayerNorm over D=768, one block per row ----------------
template<bool OBF>
__global__ __launch_bounds__(256)
void ln_kernel(const float* x, const float* __restrict__ g,
               const float* __restrict__ b, void* out)
{
  const int row = blockIdx.x, tid = threadIdx.x;
  const float* xr = x + (size_t)row * Dd;
  float v0 = xr[tid], v1 = xr[tid+256], v2 = xr[tid+512];
  float s = v0+v1+v2, q = v0*v0+v1*v1+v2*v2;
  for (int off = 32; off; off >>= 1) { s += __shfl_down(s, off); q += __shfl_down(q, off); }
  __shared__ float ps[4], pq[4];
  if ((tid & 63) == 0) { ps[tid>>6] = s; pq[tid>>6] = q; }
  __syncthreads();
  s = ps[0]+ps[1]+ps[2]+ps[3]; q = pq[0]+pq[1]+pq[2]+pq[3];
  const float mean = s * (1.f/768.f);
  const float rstd = rsqrtf(q*(1.f/768.f) - mean*mean + 1e-5f);
  float y0 = (v0-mean)*rstd*g[tid]     + b[tid];
  float y1 = (v1-mean)*rstd*g[tid+256] + b[tid+256];
  float y2 = (v2-mean)*rstd*g[tid+512] + b[tid+512];
  if (OBF) {
    unsigned short* o = (unsigned short*)out + (size_t)row * Dd;
    o[tid] = f2bf(y0); o[tid+256] = f2bf(y1); o[tid+512] = f2bf(y2);
  } else {
    float* o = (float*)out + (size_t)row * Dd;
    o[tid] = y0; o[tid+256] = y1; o[tid+512] = y2;
  }
}

// ---------------- weight prep ----------------
__global__ __launch_bounds__(256)
void transpose_w(const float* __restrict__ src, unsigned short* __restrict__ dst,
                 int K, int N)
{
  __shared__ float t[32][33];
  const int tx = threadIdx.x, ty = threadIdx.y;
  const int n0 = blockIdx.x * 32, k0 = blockIdx.y * 32;
#pragma unroll
  for (int i = 0; i < 4; i++) t[ty + i*8][tx] = src[(size_t)(k0 + ty + i*8)*N + n0 + tx];
  __syncthreads();
#pragma unroll
  for (int i = 0; i < 4; i++)
    dst[(size_t)(n0 + ty + i*8)*K + k0 + tx] = f2bf(t[tx][ty + i*8]);
}

__global__ __launch_bounds__(256)
void convert_bf(const float* __restrict__ src, unsigned short* __restrict__ dst, int n)
{
  for (int i = blockIdx.x*256 + threadIdx.x; i < n; i += gridDim.x*256)
    dst[i] = f2bf(src[i]);
}

// pwin weight permute+convert (u/gate interleave for GLU epilogue)
__global__ __launch_bounds__(256)
void perm_pwin(const float* __restrict__ w, const float* __restrict__ b,
               unsigned short* __restrict__ wt, float* __restrict__ bperm)
{
  const int r = blockIdx.x;             // 1536 rows
  const int blk = r >> 7, g = (r >> 4) & 7, t = r & 15;
  const int orig = blk*64 + ((g >> 1) << 4) + t + ((g & 1) ? 768 : 0);
  const float* src = w + (size_t)orig * 768;
  unsigned short* dst = wt + (size_t)r * 768;
  const int tid = threadIdx.x;
  dst[tid] = f2bf(src[tid]); dst[tid+256] = f2bf(src[tid+256]); dst[tid+512] = f2bf(src[tid+512]);
  if (tid == 0) bperm[r] = b[orig];
}

// dw_w (768,1,9) -> dwwT (9,768)
__global__ __launch_bounds__(256)
void dw_tr(const float* __restrict__ src, float* __restrict__ dst)
{
  const int id = blockIdx.x*256 + threadIdx.x;
  if (id >= 9*768) return;
  const int k = id / 768, d = id % 768;
  dst[id] = src[d*9 + k];
}

// ---------------- fused attention v5: QBLK=128, 8 waves, windowed bf16 rel-bias ----
// LDS = Kl 9216 + Vt 9344 + Pl 18432 + relh 2304 = 39296 B -> 4 blocks/CU x 8 waves
// = 32 waves/CU (HW cap); grid 768 blocks fully resident.
__global__ __launch_bounds__(512, 8)
void attn_kernel(const unsigned short* __restrict__ qkv,
                 const unsigned short* __restrict__ vtr,  // [bh][64][1024]
                 const float* __restrict__ rel,           // (2047, 12)
                 unsigned short* __restrict__ out)
{
  const int bh = blockIdx.x; const int b = bh / Hh, h = bh % Hh;
  const int q0 = blockIdx.y * 128;
  const int tid = threadIdx.x, wv = tid >> 6, lane = tid & 63;
  const int lr = lane & 15, lg = lane >> 4;

  __shared__ __align__(16) unsigned short Kl[64*72];        // [key][d], pitch 72
  __shared__ __align__(16) unsigned short Vt[64*72 + 64];   // [d][key], pitch 72 + stagger
  __shared__ __align__(16) unsigned short Pl[8*16*72];      // per-wave [q][key], pitch 72
  __shared__ unsigned short relh[1152];                     // bf16 window, *log2e

  // window covers rel indices [896-q0, 2046-q0]; offset = kt+127+c-wv*16-lr
  {
    const int base = 896 - q0;
    for (int i = tid; i < 1151; i += 512)
      relh[i] = f2bf(rel[(size_t)(base + i)*Hh + h] * 1.44269504f);
  }

  // Q fragments scaled by 0.125*log2e (exp2-domain softmax)
  const size_t qrow = (size_t)(b*Nn + q0 + wv*16 + lr);
  const bf16x8 qraw0 = *(const bf16x8*)(qkv + qrow*2304 + h*64 + lg*8);
  const bf16x8 qraw1 = *(const bf16x8*)(qkv + qrow*2304 + h*64 + 32 + lg*8);
  bf16x8 qf0, qf1;
#pragma unroll
  for (int e = 0; e < 8; e++) {
    qf0[e] = (__bf16)((float)qraw0[e] * 0.180336884f);
    qf1[e] = (__bf16)((float)qraw1[e] * 0.180336884f);
  }

  const int sd = tid >> 3;            // 0..63 (K: key row / V: d row)
  const int sc = (tid & 7) * 8;       // 8-elem chunk
  unsigned short* Pw = Pl + wv*16*72;

  // T14 async staging: one bf16x8 each for K and V per thread
  const unsigned short* kbase = qkv + (size_t)(b*Nn + sd)*2304 + 768 + h*64 + sc;
  const unsigned short* vbase = vtr + ((size_t)bh*64 + sd)*1024 + sc;
  bf16x8 kA = *(const bf16x8*)(kbase);
  bf16x8 vA = *(const bf16x8*)(vbase);

  f32x4 O[4] = {};
  float mrow = -1e30f, lsum = 0.f;    // log2 domain
  const int qq = q0 + wv*16 + lr;

  __syncthreads();  // relh ready

  for (int kt = 0; kt < Nn; kt += 64) {
    { // publish staged regs to LDS
      *(bf16x8*)&Kl[sd*72 + sc] = kA;
      *(bf16x8*)&Vt[sd*72 + (sd>>4)*16 + sc] = vA;
    }
    __syncthreads();

    // issue next tile's loads (latency hides under compute below)
    if (kt + 64 < Nn) {
      kA = *(const bf16x8*)(kbase + (size_t)(kt + 64)*2304);
      vA = *(const bf16x8*)(vbase + kt + 64);
    }

    // QK^T swapped, bias as MFMA C-init: S[key][q=lr]
    const int roff = kt + 127 - wv*16 - lr;
    f32x4 s[4];
#pragma unroll
    for (int kb = 0; kb < 4; kb++)
#pragma unroll
      for (int j = 0; j < 4; j++)
        s[kb][j] = bf2f(relh[roff + kb*16 + lg*4 + j]);
#pragma unroll
    for (int kb = 0; kb < 4; kb++) {
      bf16x8 kfa = *(const bf16x8*)&Kl[(kb*16 + lr)*72 + lg*8];
      bf16x8 kfb = *(const bf16x8*)&Kl[(kb*16 + lr)*72 + 32 + lg*8];
      s[kb] = __builtin_amdgcn_mfma_f32_16x16x32_bf16(kfa, qf0, s[kb], 0, 0, 0);
      s[kb] = __builtin_amdgcn_mfma_f32_16x16x32_bf16(kfb, qf1, s[kb], 0, 0, 0);
    }

    float r = -1e30f;
#pragma unroll
    for (int kb = 0; kb < 4; kb++)
#pragma unroll
      for (int j = 0; j < 4; j++) r = fmaxf(r, s[kb][j]);
    r = fmaxf(r, __shfl_xor(r, 16)); r = fmaxf(r, __shfl_xor(r, 32));

    // defer-max (T13), log2 domain
    if (!__all(r <= mrow + 11.5f)) {
      const float mn = fmaxf(mrow, r);
      const float al = __builtin_amdgcn_exp2f(mrow - mn);
      mrow = mn;
      lsum *= al;
#pragma unroll
      for (int ni = 0; ni < 4; ni++) {
        O[ni][0]*=al; O[ni][1]*=al; O[ni][2]*=al; O[ni][3]*=al;
      }
    }

    float rs = 0.f;
    unsigned int pk[8];
#pragma unroll
    for (int kb = 0; kb < 4; kb++) {
      float p0 = __builtin_amdgcn_exp2f(s[kb][0]-mrow), p1 = __builtin_amdgcn_exp2f(s[kb][1]-mrow);
      float p2 = __builtin_amdgcn_exp2f(s[kb][2]-mrow), p3 = __builtin_amdgcn_exp2f(s[kb][3]-mrow);
      rs += (p0+p1) + (p2+p3);
      pk[kb*2]   = pack2bf(p0, p1);
      pk[kb*2+1] = pack2bf(p2, p3);
    }
    rs += __shfl_xor(rs, 16); rs += __shfl_xor(rs, 32);
    lsum += rs;

#pragma unroll
    for (int kb0 = 0; kb0 < 4; kb0++) {
      const int kb = (kb0 + lg) & 3;
      *(unsigned int*)&Pw[lr*72 + kb*16 + lg*4]     = pk[kb*2];
      *(unsigned int*)&Pw[lr*72 + kb*16 + lg*4 + 2] = pk[kb*2+1];
    }

    // PV: O[d][q] += V^T . P^T (wave-private P; in-order LDS pipe)
    bf16x8 pf0 = *(const bf16x8*)&Pw[lr*72 + lg*8];
    bf16x8 pf1 = *(const bf16x8*)&Pw[lr*72 + 32 + lg*8];
#pragma unroll
    for (int dt = 0; dt < 4; dt++) {
      bf16x8 vf0 = *(const bf16x8*)&Vt[(dt*16 + lr)*72 + dt*16 + lg*8];
      bf16x8 vf1 = *(const bf16x8*)&Vt[(dt*16 + lr)*72 + dt*16 + 32 + lg*8];
      O[dt] = __builtin_amdgcn_mfma_f32_16x16x32_bf16(vf0, pf0, O[dt], 0, 0, 0);
      O[dt] = __builtin_amdgcn_mfma_f32_16x16x32_bf16(vf1, pf1, O[dt], 0, 0, 0);
    }
    __syncthreads();
  }

  const float rl = 1.f / lsum;
#pragma unroll
  for (int dt = 0; dt < 4; dt++) {
    ushort4 o4;
    o4.x = f2bf(O[dt][0]*rl); o4.y = f2bf(O[dt][1]*rl);
    o4.z = f2bf(O[dt][2]*rl); o4.w = f2bf(O[dt][3]*rl);
    *(ushort4*)(out + (size_t)(b*Nn + qq)*Dd + h*64 + dt*16 + lg*4) = o4;
  }
}

// ---------------- conv path ----------------
__global__ __launch_bounds__(256)
void dwconv(const unsigned short* __restrict__ glu, const float* __restrict__ dwwT,
            const float* __restrict__ dwb, unsigned short* __restrict__ z)
{
  const int id = blockIdx.x*256 + threadIdx.x;
  if (id >= Mm*96) return;
  const int row = id / 96, c8 = (id % 96) * 8;
  const int n = row % Nn;
  float acc[8] = {};
#pragma unroll
  for (int k = 0; k < 9; k++) {
    const int nn = n + k - 4;
    if (nn >= 0 && nn < Nn) {
      bf16x8 gv = *(const bf16x8*)&glu[(size_t)(row + k - 4)*768 + c8];
      const float4 w0 = *(const float4*)&dwwT[k*768 + c8];
      const float4 w1 = *(const float4*)&dwwT[k*768 + c8 + 4];
      acc[0] += w0.x*(float)gv[0]; acc[1] += w0.y*(float)gv[1];
      acc[2] += w0.z*(float)gv[2]; acc[3] += w0.w*(float)gv[3];
      acc[4] += w1.x*(float)gv[4]; acc[5] += w1.y*(float)gv[5];
      acc[6] += w1.z*(float)gv[6]; acc[7] += w1.w*(float)gv[7];
    }
  }
  bf16x8 o;
#pragma unroll
  for (int e = 0; e < 8; e++) o[e] = (__bf16)(acc[e] + dwb[c8+e]);
  *(bf16x8*)&z[(size_t)row*768 + c8] = o;
}

__global__ __launch_bounds__(192)
void bn_part(const unsigned short* __restrict__ z, float* __restrict__ psum,
             float* __restrict__ psq)
{
  const int blk = blockIdx.x, t = threadIdx.x;   // 64 blocks x 192 threads, 4 ch each
  const int c4 = t * 4;
  float s0=0,s1=0,s2=0,s3=0, q0=0,q1=0,q2=0,q3=0;
  for (int r = 0; r < 128; r++) {
    ushort4 v4 = *(const ushort4*)&z[(size_t)(blk*128 + r)*Dd + c4];
    float a = bf2f(v4.x), b_ = bf2f(v4.y), c = bf2f(v4.z), d = bf2f(v4.w);
    s0 += a; s1 += b_; s2 += c; s3 += d;
    q0 += a*a; q1 += b_*b_; q2 += c*c; q3 += d*d;
  }
  float4 sv = {s0, s1, s2, s3}, qv = {q0, q1, q2, q3};
  *(float4*)&psum[(size_t)blk*Dd + c4] = sv;
  *(float4*)&psq [(size_t)blk*Dd + c4] = qv;
}

__global__ __launch_bounds__(256)
void bn_final(const float* __restrict__ psum, const float* __restrict__ psq,
              const float* __restrict__ g, const float* __restrict__ bb,
              float* __restrict__ scale, float* __restrict__ shift)
{
  const int c = blockIdx.x*256 + threadIdx.x;
  if (c >= Dd) return;
  float s = 0.f, q = 0.f;
  for (int i = 0; i < 64; i++) { s += psum[(size_t)i*Dd + c]; q += psq[(size_t)i*Dd + c]; }
  const float mean = s / (float)Mm;
  const float var  = q / (float)Mm - mean*mean;
  const float sc = g[c] * rsqrtf(var + 1e-5f);
  scale[c] = sc; shift[c] = bb[c] - mean*sc;
}

__global__ __launch_bounds__(256)
void bn_silu(const unsigned short* __restrict__ z, const float* __restrict__ scale,
             const float* __restrict__ shift, unsigned short* __restrict__ out)
{
  const int id = blockIdx.x*256 + threadIdx.x;
  if (id >= Mm*96) return;
  const int row = id / 96, c8 = (id % 96) * 8;
  bf16x8 v = *(const bf16x8*)&z[(size_t)row*Dd + c8];
  bf16x8 o;
#pragma unroll
  for (int e = 0; e < 8; e++) {
    float t = (float)v[e] * scale[c8+e] + shift[c8+e];
    o[e] = (__bf16)(t / (1.f + __expf(-t)));
  }
  *(bf16x8*)&out[(size_t)row*Dd + c8] = o;
}

// ---------------- host ----------------
extern "C" void kernel_launch(void* const* d_in, const int* in_sizes, int n_in,
                              void* d_out, int out_size, void* d_ws, size_t ws_size,
                              hipStream_t stream)
{
  const float* x        = (const float*)d_in[0];
  const float* ff1_ln_g = (const float*)d_in[1];
  const float* ff1_ln_b = (const float*)d_in[2];
  const float* ff1_w1   = (const float*)d_in[3];
  const float* ff1_b1   = (const float*)d_in[4];
  const float* ff1_w2   = (const float*)d_in[5];
  const float* ff1_b2   = (const float*)d_in[6];
  const float* attn_ln_g= (const float*)d_in[7];
  const float* attn_ln_b= (const float*)d_in[8];
  const float* qkv_w    = (const float*)d_in[9];
  const float* qkv_b    = (const float*)d_in[10];
  const float* proj_w   = (const float*)d_in[11];
  const float* proj_b   = (const float*)d_in[12];
  const float* rel_tab  = (const float*)d_in[13];
  const float* conv_ln_g= (const float*)d_in[14];
  const float* conv_ln_b= (const float*)d_in[15];
  const float* pwin_w   = (const float*)d_in[16];
  const float* pwin_b   = (const float*)d_in[17];
  const float* dw_w     = (const float*)d_in[18];
  const float* dw_b     = (const float*)d_in[19];
  const float* bn_g     = (const float*)d_in[20];
  const float* bn_b     = (const float*)d_in[21];
  const float* pwout_w  = (const float*)d_in[22];
  const float* pwout_b  = (const float*)d_in[23];
  const float* ff2_ln_g = (const float*)d_in[24];
  const float* ff2_ln_b = (const float*)d_in[25];
  const float* ff2_w1   = (const float*)d_in[26];
  const float* ff2_b1   = (const float*)d_in[27];
  const float* ff2_w2   = (const float*)d_in[28];
  const float* ff2_b2   = (const float*)d_in[29];
  const float* fin_ln_g = (const float*)d_in[30];
  const float* fin_ln_b = (const float*)d_in[31];

  char* ws = (char*)d_ws;
  size_t off = 0;
  auto alloc = [&](size_t bytes) { char* p = ws + off; off += (bytes + 255) & ~(size_t)255; return p; };
  unsigned short* wt_ff1_1 = (unsigned short*)alloc((size_t)3072*768*2);
  unsigned short* wt_ff1_2 = (unsigned short*)alloc((size_t)768*3072*2);
  unsigned short* wt_qkv   = (unsigned short*)alloc((size_t)2304*768*2);
  unsigned short* wt_proj  = (unsigned short*)alloc((size_t)768*768*2);
  unsigned short* wt_pwin  = (unsigned short*)alloc((size_t)1536*768*2);
  unsigned short* wt_pwout = (unsigned short*)alloc((size_t)768*768*2);
  unsigned short* wt_ff2_1 = (unsigned short*)alloc((size_t)3072*768*2);
  unsigned short* wt_ff2_2 = (unsigned short*)alloc((size_t)768*3072*2);
  unsigned short* ybf      = (unsigned short*)alloc((size_t)Mm*768*2);
  unsigned short* big      = (unsigned short*)alloc((size_t)Mm*3072*2);
  unsigned short* abuf     = (unsigned short*)alloc((size_t)Mm*768*2);
  float* psum    = (float*)alloc((size_t)64*768*4);
  float* psq     = (float*)alloc((size_t)64*768*4);
  float* bnscale = (float*)alloc((size_t)768*4);
  float* bnshift = (float*)alloc((size_t)768*4);
  float* dwwT    = (float*)alloc((size_t)9*768*4);
  float* bperm   = (float*)alloc((size_t)1536*4);
  if (off > ws_size) return;

  // vtr lives in big's unused tail (qkv rows use pitch 2304 of the 3072 alloc)
  unsigned short* vtr = big + (size_t)Mm*2304;

  float* xres = (float*)d_out;
  const dim3 tb(256);

  // --- weight prep ---
  transpose_w<<<dim3(3072/32, 768/32), dim3(32,8), 0, stream>>>(ff1_w1, wt_ff1_1, 768, 3072);
  transpose_w<<<dim3(768/32, 3072/32), dim3(32,8), 0, stream>>>(ff1_w2, wt_ff1_2, 3072, 768);
  transpose_w<<<dim3(2304/32, 768/32), dim3(32,8), 0, stream>>>(qkv_w,  wt_qkv,  768, 2304);
  transpose_w<<<dim3(768/32, 768/32),  dim3(32,8), 0, stream>>>(proj_w, wt_proj, 768, 768);
  transpose_w<<<dim3(3072/32, 768/32), dim3(32,8), 0, stream>>>(ff2_w1, wt_ff2_1, 768, 3072);
  transpose_w<<<dim3(768/32, 3072/32), dim3(32,8), 0, stream>>>(ff2_w2, wt_ff2_2, 3072, 768);
  perm_pwin<<<1536, tb, 0, stream>>>(pwin_w, pwin_b, wt_pwin, bperm);
  convert_bf<<<2048, tb, 0, stream>>>(pwout_w, wt_pwout, 768*768);
  dw_tr<<<27, tb, 0, stream>>>(dw_w, dwwT);

  // --- FFN1: xres = x + 0.5*FFN(LN(x)) ---
  ln_kernel<true><<<Mm, tb, 0, stream>>>(x, ff1_ln_g, ff1_ln_b, ybf);
  gemm_bt<1,128><<<dim3(3072/128, Mm/128), tb, 0, stream>>>(ybf, wt_ff1_1, ff1_b1, big, nullptr, nullptr, nullptr, Mm, 3072, 768, 0.f);
  gemm_bt<4,64><<<dim3(768/64, Mm/128), tb, 0, stream>>>(big, wt_ff1_2, ff1_b2, nullptr, xres, x, nullptr, Mm, 768, 3072, 0.5f);

  // --- attention (qkv GEMM writes V transposed into vtr via EPI5) ---
  ln_kernel<true><<<Mm, tb, 0, stream>>>(xres, attn_ln_g, attn_ln_b, ybf);
  gemm_bt<5,128><<<dim3(2304/128, Mm/128), tb, 0, stream>>>(ybf, wt_qkv, qkv_b, big, nullptr, nullptr, vtr, Mm, 2304, 768, 0.f);
  attn_kernel<<<dim3(Bb*Hh, Nn/128), dim3(512), 0, stream>>>(big, vtr, rel_tab, abuf);
  gemm_bt<2,64><<<dim3(768/64, Mm/128), tb, 0, stream>>>(abuf, wt_proj, proj_b, nullptr, xres, nullptr, nullptr, Mm, 768, 768, 1.0f);

  // --- conv module ---
  ln_kernel<true><<<Mm, tb, 0, stream>>>(xres, conv_ln_g, conv_ln_b, ybf);
  gemm_bt<3,128><<<dim3(1536/128, Mm/128), tb, 0, stream>>>(ybf, wt_pwin, bperm, abuf, nullptr, nullptr, nullptr, Mm, 1536, 768, 0.f);
  dwconv<<<(Mm*96)/256, tb, 0, stream>>>(abuf, dwwT, dw_b, ybf);
  bn_part<<<64, dim3(192), 0, stream>>>(ybf, psum, psq);
  bn_final<<<3, tb, 0, stream>>>(psum, psq, bn_g, bn_b, bnscale, bnshift);
  bn_silu<<<(Mm*96)/256, tb, 0, stream>>>(ybf, bnscale, bnshift, abuf);
  gemm_bt<2,64><<<dim3(768/64, Mm/128), tb, 0, stream>>>(abuf, wt_pwout, pwout_b, nullptr, xres, nullptr, nullptr, Mm, 768, 768, 1.0f);

  // --- FFN2 ---
  ln_kernel<true><<<Mm, tb, 0, stream>>>(xres, ff2_ln_g, ff2_ln_b, ybf);
  gemm_bt<1,128><<<dim3(3072/128, Mm/128), tb, 0, stream>>>(ybf, wt_ff2_1, ff2_b1, big, nullptr, nullptr, nullptr, Mm, 3072, 768, 0.f);
  gemm_bt<2,64><<<dim3(768/64, Mm/128), tb, 0, stream>>>(big, wt_ff2_2, ff2_b2, nullptr, xres, nullptr, nullptr, Mm, 768, 3072, 0.5f);

  // --- final LN ---
  ln_kernel<false><<<Mm, tb, 0, stream>>>(xres, fin_ln_g, fin_ln_b, (void*)xres);
}

// Round 11
// 588.844 us; speedup vs baseline: 1.2137x; 1.2137x over previous
//
#include <hip/hip_runtime.h>
#include <math.h>

// Problem constants
#define Bb 8
#define Nn 1024
#define Dd 768
#define Hh 12
#define Mm 8192   // Bb*Nn

typedef __attribute__((ext_vector_type(4))) float f32x4;
typedef __attribute__((ext_vector_type(8))) __bf16 bf16x8;

__device__ __forceinline__ float bf2f(unsigned short u) {
  union { unsigned int i; float f; } v; v.i = ((unsigned int)u) << 16; return v.f;
}
__device__ __forceinline__ unsigned short f2bf(float f) {
  union { float f; unsigned int i; } v; v.f = f;
  unsigned int u = v.i;
  return (unsigned short)((u + 0x7FFFu + ((u >> 16) & 1u)) >> 16);
}
__device__ __forceinline__ unsigned int pack2bf(float a, float b) {
  union { __bf16 h[2]; unsigned int u; } x;
  x.h[0] = (__bf16)a; x.h[1] = (__bf16)b; return x.u;
}

__device__ __forceinline__ void gload16(const void* g, void* l) {
  __builtin_amdgcn_global_load_lds(
      (const __attribute__((address_space(1))) unsigned int*)g,
      (__attribute__((address_space(3))) unsigned int*)l, 16, 0, 0);
}

// Branch-free GELU (erf via Abramowitz-Stegun 7.1.26, |eps|<=1.5e-7)
__device__ __forceinline__ float gelu_f(float v) {
  const float z = fabsf(v) * 0.7071067811865475f;
  const float t = __builtin_amdgcn_rcpf(1.f + 0.3275911f * z);
  const float poly = t*(0.254829592f + t*(-0.284496736f + t*(1.421413741f +
                     t*(-1.453152027f + t*1.061405429f))));
  float er = 1.f - poly * __expf(-z * z);
  er = copysignf(er, v);
  return 0.5f * v * (1.f + er);
}

// ---------------- GEMM: C[M,N] = epi(A[M,K] * Bt[N,K]^T + bias) ----------------
// BK=64 K-step, 2-phase. LDS rows 128B pitch, T2 XOR-swizzle (rule-#21 pattern).
// NT = 128 or 64. XCD-chunked bijective swizzle (m204).
// EPI 0: store bf16; 1: GELU->bf16; 2: Res += scale*v; 3: GLU (N/2 bf16);
// EPI 4: Res = Xin + scale*v; EPI 5: qkv with fused V-transpose (V cols -> Vtr)
template<int EPI, int NT>
__global__ __launch_bounds__(256)
void gemm_bt(const unsigned short* __restrict__ A,
             const unsigned short* __restrict__ Bt,
             const float* __restrict__ bias,
             unsigned short* __restrict__ Cbf,
             float* __restrict__ Res,
             const float* __restrict__ Xin,
             unsigned short* __restrict__ Vtr,
             int M, int N, int K, float scale)
{
  __shared__ __align__(16) unsigned short Asm[128*64];
  __shared__ __align__(16) unsigned short Bsm[NT*64];
  const int tid = threadIdx.x;
  const int wv = tid >> 6, lane = tid & 63;
  const int lr = lane & 15, lg = lane >> 4;
  const int wr = wv >> 1, wc = wv & 1;
  constexpr int JN = NT / 32;       // col-groups of 16 per wave

  // ---- bijective XCD-chunked swizzle ----
  const int gx = gridDim.x, gy = gridDim.y;
  const int nwg = gx * gy;
  const int lin = blockIdx.y * gx + blockIdx.x;
  const int q8 = nwg >> 3, r8 = nwg & 7;
  const int xcd = lin & 7, lidx = lin >> 3;
  const int wg = ((xcd < r8) ? xcd * (q8 + 1) : r8 * (q8 + 1) + (xcd - r8) * q8) + lidx;
  const int bx = wg % gx;
  const int by = wg / gx;

  const int n0 = bx * NT, m0 = by * 128;

  f32x4 acc[4][JN] = {};

  const int srow8 = lane >> 3;                    // row within 8-row group
  const int scol  = ((lane & 7) ^ srow8) * 8;     // pre-swizzled source col (elems)
  const unsigned short* Agp = A + (size_t)(m0 + wv*32 + srow8)*K + scol;
  const unsigned short* Bgp = (NT == 128)
      ? Bt + (size_t)(n0 + wv*32 + srow8)*K + scol
      : Bt + (size_t)(n0 + wv*16 + srow8)*K + scol;
  const int swr = (lr & 7) << 4;                  // read-side XOR (bytes)

  for (int kt = 0; kt < K; kt += 64) {
#pragma unroll
    for (int k = 0; k < 4; k++)
      gload16(Agp + (size_t)(k*8)*K + kt, Asm + (wv*32 + k*8)*64);
    if (NT == 128) {
#pragma unroll
      for (int k = 0; k < 4; k++)
        gload16(Bgp + (size_t)(k*8)*K + kt, Bsm + (wv*32 + k*8)*64);
    } else {
#pragma unroll
      for (int k = 0; k < 2; k++)
        gload16(Bgp + (size_t)(k*8)*K + kt, Bsm + (wv*16 + k*8)*64);
    }
    __syncthreads();   // drains vmcnt -> LDS tiles ready
    bf16x8 af[4], af2[4], bfr[JN], bfr2[JN];
#pragma unroll
    for (int i = 0; i < 4; i++) {
      const char* base = (const char*)Asm + (wr*64 + i*16 + lr)*128;
      af[i]  = *(const bf16x8*)(base + ((lg*16)      ^ swr));
      af2[i] = *(const bf16x8*)(base + ((lg*16 + 64) ^ swr));
    }
#pragma unroll
    for (int j = 0; j < JN; j++) {
      const char* base = (const char*)Bsm + (wc*(NT/2) + j*16 + lr)*128;
      bfr[j]  = *(const bf16x8*)(base + ((lg*16)      ^ swr));
      bfr2[j] = *(const bf16x8*)(base + ((lg*16 + 64) ^ swr));
    }
#pragma unroll
    for (int i = 0; i < 4; i++)
#pragma unroll
      for (int j = 0; j < JN; j++) {
        acc[i][j] = __builtin_amdgcn_mfma_f32_16x16x32_bf16(af[i],  bfr[j],  acc[i][j], 0, 0, 0);
        acc[i][j] = __builtin_amdgcn_mfma_f32_16x16x32_bf16(af2[i], bfr2[j], acc[i][j], 0, 0, 0);
      }
    __syncthreads();   // compute done before next stage overwrites
  }

#pragma unroll
  for (int i = 0; i < 4; i++) {
    const int rg = m0 + wr*64 + i*16 + lg*4;
    if (EPI == 3) {
      // GLU: col-groups alternate u (even) / gate (odd); write N/2 bf16 cols
#pragma unroll
      for (int j = 0; j < JN; j += 2) {
        const int cgu = n0 + wc*(NT/2) + j*16 + lr;
        const float bu = bias[cgu], bg = bias[cgu + 16];
        const int ocol = (n0 >> 1) + wc*(NT/4) + (j >> 1)*16 + lr;
#pragma unroll
        for (int e = 0; e < 4; e++) {
          float u  = acc[i][j][e]   + bu;
          float gt = acc[i][j+1][e] + bg;
          Cbf[(size_t)(rg + e) * (N >> 1) + ocol] = f2bf(u / (1.f + __expf(-gt)));
        }
      }
    } else if (EPI == 5 && n0 >= 1536) {
      // V columns: write transposed into Vtr[(b*Hh+h)*64 + d][n]
#pragma unroll
      for (int j = 0; j < JN; j++) {
        const int cg = n0 + wc*(NT/2) + j*16 + lr;
        const float bv = bias[cg];
        const int vo = cg - 1536;
        const int hh = vo >> 6, d = vo & 63;
        const int bb_ = rg >> 10, nn_ = rg & 1023;
        ushort4 o4;
        o4.x = f2bf(acc[i][j][0] + bv);
        o4.y = f2bf(acc[i][j][1] + bv);
        o4.z = f2bf(acc[i][j][2] + bv);
        o4.w = f2bf(acc[i][j][3] + bv);
        *(ushort4*)(Vtr + (((size_t)bb_*Hh + hh)*64 + d)*1024 + nn_) = o4;
      }
    } else {
#pragma unroll
      for (int j = 0; j < JN; j++) {
        const int cg = n0 + wc*(NT/2) + j*16 + lr;
        const float bv = bias[cg];
#pragma unroll
        for (int e = 0; e < 4; e++) {
          float v = acc[i][j][e] + bv;
          const size_t idx = (size_t)(rg + e) * N + cg;
          if (EPI == 1) {
            Cbf[idx] = f2bf(gelu_f(v));
          } else if (EPI == 0 || EPI == 5) {
            Cbf[idx] = f2bf(v);
          } else if (EPI == 2) {
            Res[idx] += scale * v;
          } else {  // EPI 4
            Res[idx] = Xin[idx] + scale * v;
          }
        }
      }
    }
  }
}

// ---------------- LayerNorm over D=768, one block per row ----------------
template<bool OBF>
__global__ __launch_bounds__(256)
void ln_kernel(const float* x, const float* __restrict__ g,
               const float* __restrict__ b, void* out)
{
  const int row = blockIdx.x, tid = threadIdx.x;
  const float* xr = x + (size_t)row * Dd;
  float v0 = xr[tid], v1 = xr[tid+256], v2 = xr[tid+512];
  float s = v0+v1+v2, q = v0*v0+v1*v1+v2*v2;
  for (int off = 32; off; off >>= 1) { s += __shfl_down(s, off); q += __shfl_down(q, off); }
  __shared__ float ps[4], pq[4];
  if ((tid & 63) == 0) { ps[tid>>6] = s; pq[tid>>6] = q; }
  __syncthreads();
  s = ps[0]+ps[1]+ps[2]+ps[3]; q = pq[0]+pq[1]+pq[2]+pq[3];
  const float mean = s * (1.f/768.f);
  const float rstd = rsqrtf(q*(1.f/768.f) - mean*mean + 1e-5f);
  float y0 = (v0-mean)*rstd*g[tid]     + b[tid];
  float y1 = (v1-mean)*rstd*g[tid+256] + b[tid+256];
  float y2 = (v2-mean)*rstd*g[tid+512] + b[tid+512];
  if (OBF) {
    unsigned short* o = (unsigned short*)out + (size_t)row * Dd;
    o[tid] = f2bf(y0); o[tid+256] = f2bf(y1); o[tid+512] = f2bf(y2);
  } else {
    float* o = (float*)out + (size_t)row * Dd;
    o[tid] = y0; o[tid+256] = y1; o[tid+512] = y2;
  }
}

// ---------------- weight prep ----------------
__global__ __launch_bounds__(256)
void transpose_w(const float* __restrict__ src, unsigned short* __restrict__ dst,
                 int K, int N)
{
  __shared__ float t[32][33];
  const int tx = threadIdx.x, ty = threadIdx.y;
  const int n0 = blockIdx.x * 32, k0 = blockIdx.y * 32;
#pragma unroll
  for (int i = 0; i < 4; i++) t[ty + i*8][tx] = src[(size_t)(k0 + ty + i*8)*N + n0 + tx];
  __syncthreads();
#pragma unroll
  for (int i = 0; i < 4; i++)
    dst[(size_t)(n0 + ty + i*8)*K + k0 + tx] = f2bf(t[tx][ty + i*8]);
}

__global__ __launch_bounds__(256)
void convert_bf(const float* __restrict__ src, unsigned short* __restrict__ dst, int n)
{
  for (int i = blockIdx.x*256 + threadIdx.x; i < n; i += gridDim.x*256)
    dst[i] = f2bf(src[i]);
}

// pwin weight permute+convert (u/gate interleave for GLU epilogue)
__global__ __launch_bounds__(256)
void perm_pwin(const float* __restrict__ w, const float* __restrict__ b,
               unsigned short* __restrict__ wt, float* __restrict__ bperm)
{
  const int r = blockIdx.x;             // 1536 rows
  const int blk = r >> 7, g = (r >> 4) & 7, t = r & 15;
  const int orig = blk*64 + ((g >> 1) << 4) + t + ((g & 1) ? 768 : 0);
  const float* src = w + (size_t)orig * 768;
  unsigned short* dst = wt + (size_t)r * 768;
  const int tid = threadIdx.x;
  dst[tid] = f2bf(src[tid]); dst[tid+256] = f2bf(src[tid+256]); dst[tid+512] = f2bf(src[tid+512]);
  if (tid == 0) bperm[r] = b[orig];
}

// dw_w (768,1,9) -> dwwT (9,768)
__global__ __launch_bounds__(256)
void dw_tr(const float* __restrict__ src, float* __restrict__ dst)
{
  const int id = blockIdx.x*256 + threadIdx.x;
  if (id >= 9*768) return;
  const int k = id / 768, d = id % 768;
  dst[id] = src[d*9 + k];
}

// ---------------- fused attention v5b: QBLK=128, 8 waves, windowed bf16 rel-bias ---
// LDS = Kl 9216 + Vt 9344 + Pl 18432 + relh 2304 = 39296 B -> 4 blocks/CU x 8 waves
// (natural VGPR ~48 <= 64 allows 8 waves/SIMD; NO min-waves bound — R9's forced
//  bound clamped VGPR to 32 and spilled ~1 GB to scratch).
__global__ __launch_bounds__(512)
void attn_kernel(const unsigned short* __restrict__ qkv,
                 const unsigned short* __restrict__ vtr,  // [bh][64][1024]
                 const float* __restrict__ rel,           // (2047, 12)
                 unsigned short* __restrict__ out)
{
  const int bh = blockIdx.x; const int b = bh / Hh, h = bh % Hh;
  const int q0 = blockIdx.y * 128;
  const int tid = threadIdx.x, wv = tid >> 6, lane = tid & 63;
  const int lr = lane & 15, lg = lane >> 4;

  __shared__ __align__(16) unsigned short Kl[64*72];        // [key][d], pitch 72
  __shared__ __align__(16) unsigned short Vt[64*72 + 64];   // [d][key], pitch 72 + stagger
  __shared__ __align__(16) unsigned short Pl[8*16*72];      // per-wave [q][key], pitch 72
  __shared__ unsigned short relh[1152];                     // bf16 window, *log2e

  // window covers rel indices [896-q0, 2046-q0]; offset = kt+127+c-wv*16-lr
  {
    const int base = 896 - q0;
    for (int i = tid; i < 1151; i += 512)
      relh[i] = f2bf(rel[(size_t)(base + i)*Hh + h] * 1.44269504f);
  }

  // Q fragments scaled by 0.125*log2e (exp2-domain softmax)
  const size_t qrow = (size_t)(b*Nn + q0 + wv*16 + lr);
  const bf16x8 qraw0 = *(const bf16x8*)(qkv + qrow*2304 + h*64 + lg*8);
  const bf16x8 qraw1 = *(const bf16x8*)(qkv + qrow*2304 + h*64 + 32 + lg*8);
  bf16x8 qf0, qf1;
#pragma unroll
  for (int e = 0; e < 8; e++) {
    qf0[e] = (__bf16)((float)qraw0[e] * 0.180336884f);
    qf1[e] = (__bf16)((float)qraw1[e] * 0.180336884f);
  }

  const int sd = tid >> 3;            // 0..63 (K: key row / V: d row)
  const int sc = (tid & 7) * 8;       // 8-elem chunk
  unsigned short* Pw = Pl + wv*16*72;

  // T14 async staging: one bf16x8 each for K and V per thread
  const unsigned short* kbase = qkv + (size_t)(b*Nn + sd)*2304 + 768 + h*64 + sc;
  const unsigned short* vbase = vtr + ((size_t)bh*64 + sd)*1024 + sc;
  bf16x8 kA = *(const bf16x8*)(kbase);
  bf16x8 vA = *(const bf16x8*)(vbase);

  f32x4 O[4] = {};
  float mrow = -1e30f, lsum = 0.f;    // log2 domain
  const int qq = q0 + wv*16 + lr;

  __syncthreads();  // relh ready

  for (int kt = 0; kt < Nn; kt += 64) {
    { // publish staged regs to LDS
      *(bf16x8*)&Kl[sd*72 + sc] = kA;
      *(bf16x8*)&Vt[sd*72 + (sd>>4)*16 + sc] = vA;
    }
    __syncthreads();

    // issue next tile's loads (latency hides under compute below)
    if (kt + 64 < Nn) {
      kA = *(const bf16x8*)(kbase + (size_t)(kt + 64)*2304);
      vA = *(const bf16x8*)(vbase + kt + 64);
    }

    // QK^T swapped, bias as MFMA C-init: S[key][q=lr]
    const int roff = kt + 127 - wv*16 - lr;
    f32x4 s[4];
#pragma unroll
    for (int kb = 0; kb < 4; kb++)
#pragma unroll
      for (int j = 0; j < 4; j++)
        s[kb][j] = bf2f(relh[roff + kb*16 + lg*4 + j]);
#pragma unroll
    for (int kb = 0; kb < 4; kb++) {
      bf16x8 kfa = *(const bf16x8*)&Kl[(kb*16 + lr)*72 + lg*8];
      bf16x8 kfb = *(const bf16x8*)&Kl[(kb*16 + lr)*72 + 32 + lg*8];
      s[kb] = __builtin_amdgcn_mfma_f32_16x16x32_bf16(kfa, qf0, s[kb], 0, 0, 0);
      s[kb] = __builtin_amdgcn_mfma_f32_16x16x32_bf16(kfb, qf1, s[kb], 0, 0, 0);
    }

    float r = -1e30f;
#pragma unroll
    for (int kb = 0; kb < 4; kb++)
#pragma unroll
      for (int j = 0; j < 4; j++) r = fmaxf(r, s[kb][j]);
    r = fmaxf(r, __shfl_xor(r, 16)); r = fmaxf(r, __shfl_xor(r, 32));

    // defer-max (T13), log2 domain
    if (!__all(r <= mrow + 11.5f)) {
      const float mn = fmaxf(mrow, r);
      const float al = __builtin_amdgcn_exp2f(mrow - mn);
      mrow = mn;
      lsum *= al;
#pragma unroll
      for (int ni = 0; ni < 4; ni++) {
        O[ni][0]*=al; O[ni][1]*=al; O[ni][2]*=al; O[ni][3]*=al;
      }
    }

    float rs = 0.f;
    unsigned int pk[8];
#pragma unroll
    for (int kb = 0; kb < 4; kb++) {
      float p0 = __builtin_amdgcn_exp2f(s[kb][0]-mrow), p1 = __builtin_amdgcn_exp2f(s[kb][1]-mrow);
      float p2 = __builtin_amdgcn_exp2f(s[kb][2]-mrow), p3 = __builtin_amdgcn_exp2f(s[kb][3]-mrow);
      rs += (p0+p1) + (p2+p3);
      pk[kb*2]   = pack2bf(p0, p1);
      pk[kb*2+1] = pack2bf(p2, p3);
    }
    rs += __shfl_xor(rs, 16); rs += __shfl_xor(rs, 32);
    lsum += rs;

#pragma unroll
    for (int kb0 = 0; kb0 < 4; kb0++) {
      const int kb = (kb0 + lg) & 3;
      *(unsigned int*)&Pw[lr*72 + kb*16 + lg*4]     = pk[kb*2];
      *(unsigned int*)&Pw[lr*72 + kb*16 + lg*4 + 2] = pk[kb*2+1];
    }

    // PV: O[d][q] += V^T . P^T (wave-private P; in-order LDS pipe)
    bf16x8 pf0 = *(const bf16x8*)&Pw[lr*72 + lg*8];
    bf16x8 pf1 = *(const bf16x8*)&Pw[lr*72 + 32 + lg*8];
#pragma unroll
    for (int dt = 0; dt < 4; dt++) {
      bf16x8 vf0 = *(const bf16x8*)&Vt[(dt*16 + lr)*72 + dt*16 + lg*8];
      bf16x8 vf1 = *(const bf16x8*)&Vt[(dt*16 + lr)*72 + dt*16 + 32 + lg*8];
      O[dt] = __builtin_amdgcn_mfma_f32_16x16x32_bf16(vf0, pf0, O[dt], 0, 0, 0);
      O[dt] = __builtin_amdgcn_mfma_f32_16x16x32_bf16(vf1, pf1, O[dt], 0, 0, 0);
    }
    __syncthreads();
  }

  const float rl = 1.f / lsum;
#pragma unroll
  for (int dt = 0; dt < 4; dt++) {
    ushort4 o4;
    o4.x = f2bf(O[dt][0]*rl); o4.y = f2bf(O[dt][1]*rl);
    o4.z = f2bf(O[dt][2]*rl); o4.w = f2bf(O[dt][3]*rl);
    *(ushort4*)(out + (size_t)(b*Nn + qq)*Dd + h*64 + dt*16 + lg*4) = o4;
  }
}

// ---------------- conv path ----------------
__global__ __launch_bounds__(256)
void dwconv(const unsigned short* __restrict__ glu, const float* __restrict__ dwwT,
            const float* __restrict__ dwb, unsigned short* __restrict__ z)
{
  const int id = blockIdx.x*256 + threadIdx.x;
  if (id >= Mm*96) return;
  const int row = id / 96, c8 = (id % 96) * 8;
  const int n = row % Nn;
  float acc[8] = {};
#pragma unroll
  for (int k = 0; k < 9; k++) {
    const int nn = n + k - 4;
    if (nn >= 0 && nn < Nn) {
      bf16x8 gv = *(const bf16x8*)&glu[(size_t)(row + k - 4)*768 + c8];
      const float4 w0 = *(const float4*)&dwwT[k*768 + c8];
      const float4 w1 = *(const float4*)&dwwT[k*768 + c8 + 4];
      acc[0] += w0.x*(float)gv[0]; acc[1] += w0.y*(float)gv[1];
      acc[2] += w0.z*(float)gv[2]; acc[3] += w0.w*(float)gv[3];
      acc[4] += w1.x*(float)gv[4]; acc[5] += w1.y*(float)gv[5];
      acc[6] += w1.z*(float)gv[6]; acc[7] += w1.w*(float)gv[7];
    }
  }
  bf16x8 o;
#pragma unroll
  for (int e = 0; e < 8; e++) o[e] = (__bf16)(acc[e] + dwb[c8+e]);
  *(bf16x8*)&z[(size_t)row*768 + c8] = o;
}

__global__ __launch_bounds__(192)
void bn_part(const unsigned short* __restrict__ z, float* __restrict__ psum,
             float* __restrict__ psq)
{
  const int blk = blockIdx.x, t = threadIdx.x;   // 64 blocks x 192 threads, 4 ch each
  const int c4 = t * 4;
  float s0=0,s1=0,s2=0,s3=0, q0=0,q1=0,q2=0,q3=0;
  for (int r = 0; r < 128; r++) {
    ushort4 v4 = *(const ushort4*)&z[(size_t)(blk*128 + r)*Dd + c4];
    float a = bf2f(v4.x), b_ = bf2f(v4.y), c = bf2f(v4.z), d = bf2f(v4.w);
    s0 += a; s1 += b_; s2 += c; s3 += d;
    q0 += a*a; q1 += b_*b_; q2 += c*c; q3 += d*d;
  }
  float4 sv = {s0, s1, s2, s3}, qv = {q0, q1, q2, q3};
  *(float4*)&psum[(size_t)blk*Dd + c4] = sv;
  *(float4*)&psq [(size_t)blk*Dd + c4] = qv;
}

__global__ __launch_bounds__(256)
void bn_final(const float* __restrict__ psum, const float* __restrict__ psq,
              const float* __restrict__ g, const float* __restrict__ bb,
              float* __restrict__ scale, float* __restrict__ shift)
{
  const int c = blockIdx.x*256 + threadIdx.x;
  if (c >= Dd) return;
  float s = 0.f, q = 0.f;
  for (int i = 0; i < 64; i++) { s += psum[(size_t)i*Dd + c]; q += psq[(size_t)i*Dd + c]; }
  const float mean = s / (float)Mm;
  const float var  = q / (float)Mm - mean*mean;
  const float sc = g[c] * rsqrtf(var + 1e-5f);
  scale[c] = sc; shift[c] = bb[c] - mean*sc;
}

__global__ __launch_bounds__(256)
void bn_silu(const unsigned short* __restrict__ z, const float* __restrict__ scale,
             const float* __restrict__ shift, unsigned short* __restrict__ out)
{
  const int id = blockIdx.x*256 + threadIdx.x;
  if (id >= Mm*96) return;
  const int row = id / 96, c8 = (id % 96) * 8;
  bf16x8 v = *(const bf16x8*)&z[(size_t)row*Dd + c8];
  bf16x8 o;
#pragma unroll
  for (int e = 0; e < 8; e++) {
    float t = (float)v[e] * scale[c8+e] + shift[c8+e];
    o[e] = (__bf16)(t / (1.f + __expf(-t)));
  }
  *(bf16x8*)&out[(size_t)row*Dd + c8] = o;
}

// ---------------- host ----------------
extern "C" void kernel_launch(void* const* d_in, const int* in_sizes, int n_in,
                              void* d_out, int out_size, void* d_ws, size_t ws_size,
                              hipStream_t stream)
{
  const float* x        = (const float*)d_in[0];
  const float* ff1_ln_g = (const float*)d_in[1];
  const float* ff1_ln_b = (const float*)d_in[2];
  const float* ff1_w1   = (const float*)d_in[3];
  const float* ff1_b1   = (const float*)d_in[4];
  const float* ff1_w2   = (const float*)d_in[5];
  const float* ff1_b2   = (const float*)d_in[6];
  const float* attn_ln_g= (const float*)d_in[7];
  const float* attn_ln_b= (const float*)d_in[8];
  const float* qkv_w    = (const float*)d_in[9];
  const float* qkv_b    = (const float*)d_in[10];
  const float* proj_w   = (const float*)d_in[11];
  const float* proj_b   = (const float*)d_in[12];
  const float* rel_tab  = (const float*)d_in[13];
  const float* conv_ln_g= (const float*)d_in[14];
  const float* conv_ln_b= (const float*)d_in[15];
  const float* pwin_w   = (const float*)d_in[16];
  const float* pwin_b   = (const float*)d_in[17];
  const float* dw_w     = (const float*)d_in[18];
  const float* dw_b     = (const float*)d_in[19];
  const float* bn_g     = (const float*)d_in[20];
  const float* bn_b     = (const float*)d_in[21];
  const float* pwout_w  = (const float*)d_in[22];
  const float* pwout_b  = (const float*)d_in[23];
  const float* ff2_ln_g = (const float*)d_in[24];
  const float* ff2_ln_b = (const float*)d_in[25];
  const float* ff2_w1   = (const float*)d_in[26];
  const float* ff2_b1   = (const float*)d_in[27];
  const float* ff2_w2   = (const float*)d_in[28];
  const float* ff2_b2   = (const float*)d_in[29];
  const float* fin_ln_g = (const float*)d_in[30];
  const float* fin_ln_b = (const float*)d_in[31];

  char* ws = (char*)d_ws;
  size_t off = 0;
  auto alloc = [&](size_t bytes) { char* p = ws + off; off += (bytes + 255) & ~(size_t)255; return p; };
  unsigned short* wt_ff1_1 = (unsigned short*)alloc((size_t)3072*768*2);
  unsigned short* wt_ff1_2 = (unsigned short*)alloc((size_t)768*3072*2);
  unsigned short* wt_qkv   = (unsigned short*)alloc((size_t)2304*768*2);
  unsigned short* wt_proj  = (unsigned short*)alloc((size_t)768*768*2);
  unsigned short* wt_pwin  = (unsigned short*)alloc((size_t)1536*768*2);
  unsigned short* wt_pwout = (unsigned short*)alloc((size_t)768*768*2);
  unsigned short* wt_ff2_1 = (unsigned short*)alloc((size_t)3072*768*2);
  unsigned short* wt_ff2_2 = (unsigned short*)alloc((size_t)768*3072*2);
  unsigned short* ybf      = (unsigned short*)alloc((size_t)Mm*768*2);
  unsigned short* big      = (unsigned short*)alloc((size_t)Mm*3072*2);
  unsigned short* abuf     = (unsigned short*)alloc((size_t)Mm*768*2);
  float* psum    = (float*)alloc((size_t)64*768*4);
  float* psq     = (float*)alloc((size_t)64*768*4);
  float* bnscale = (float*)alloc((size_t)768*4);
  float* bnshift = (float*)alloc((size_t)768*4);
  float* dwwT    = (float*)alloc((size_t)9*768*4);
  float* bperm   = (float*)alloc((size_t)1536*4);
  if (off > ws_size) return;

  // vtr lives in big's unused tail (qkv rows use pitch 2304 of the 3072 alloc)
  unsigned short* vtr = big + (size_t)Mm*2304;

  float* xres = (float*)d_out;
  const dim3 tb(256);

  // --- weight prep ---
  transpose_w<<<dim3(3072/32, 768/32), dim3(32,8), 0, stream>>>(ff1_w1, wt_ff1_1, 768, 3072);
  transpose_w<<<dim3(768/32, 3072/32), dim3(32,8), 0, stream>>>(ff1_w2, wt_ff1_2, 3072, 768);
  transpose_w<<<dim3(2304/32, 768/32), dim3(32,8), 0, stream>>>(qkv_w,  wt_qkv,  768, 2304);
  transpose_w<<<dim3(768/32, 768/32),  dim3(32,8), 0, stream>>>(proj_w, wt_proj, 768, 768);
  transpose_w<<<dim3(3072/32, 768/32), dim3(32,8), 0, stream>>>(ff2_w1, wt_ff2_1, 768, 3072);
  transpose_w<<<dim3(768/32, 3072/32), dim3(32,8), 0, stream>>>(ff2_w2, wt_ff2_2, 3072, 768);
  perm_pwin<<<1536, tb, 0, stream>>>(pwin_w, pwin_b, wt_pwin, bperm);
  convert_bf<<<2048, tb, 0, stream>>>(pwout_w, wt_pwout, 768*768);
  dw_tr<<<27, tb, 0, stream>>>(dw_w, dwwT);

  // --- FFN1: xres = x + 0.5*FFN(LN(x)) ---
  ln_kernel<true><<<Mm, tb, 0, stream>>>(x, ff1_ln_g, ff1_ln_b, ybf);
  gemm_bt<1,128><<<dim3(3072/128, Mm/128), tb, 0, stream>>>(ybf, wt_ff1_1, ff1_b1, big, nullptr, nullptr, nullptr, Mm, 3072, 768, 0.f);
  gemm_bt<4,64><<<dim3(768/64, Mm/128), tb, 0, stream>>>(big, wt_ff1_2, ff1_b2, nullptr, xres, x, nullptr, Mm, 768, 3072, 0.5f);

  // --- attention (qkv GEMM writes V transposed into vtr via EPI5) ---
  ln_kernel<true><<<Mm, tb, 0, stream>>>(xres, attn_ln_g, attn_ln_b, ybf);
  gemm_bt<5,128><<<dim3(2304/128, Mm/128), tb, 0, stream>>>(ybf, wt_qkv, qkv_b, big, nullptr, nullptr, vtr, Mm, 2304, 768, 0.f);
  attn_kernel<<<dim3(Bb*Hh, Nn/128), dim3(512), 0, stream>>>(big, vtr, rel_tab, abuf);
  gemm_bt<2,64><<<dim3(768/64, Mm/128), tb, 0, stream>>>(abuf, wt_proj, proj_b, nullptr, xres, nullptr, nullptr, Mm, 768, 768, 1.0f);

  // --- conv module ---
  ln_kernel<true><<<Mm, tb, 0, stream>>>(xres, conv_ln_g, conv_ln_b, ybf);
  gemm_bt<3,128><<<dim3(1536/128, Mm/128), tb, 0, stream>>>(ybf, wt_pwin, bperm, abuf, nullptr, nullptr, nullptr, Mm, 1536, 768, 0.f);
  dwconv<<<(Mm*96)/256, tb, 0, stream>>>(abuf, dwwT, dw_b, ybf);
  bn_part<<<64, dim3(192), 0, stream>>>(ybf, psum, psq);
  bn_final<<<3, tb, 0, stream>>>(psum, psq, bn_g, bn_b, bnscale, bnshift);
  bn_silu<<<(Mm*96)/256, tb, 0, stream>>>(ybf, bnscale, bnshift, abuf);
  gemm_bt<2,64><<<dim3(768/64, Mm/128), tb, 0, stream>>>(abuf, wt_pwout, pwout_b, nullptr, xres, nullptr, nullptr, Mm, 768, 768, 1.0f);

  // --- FFN2 ---
  ln_kernel<true><<<Mm, tb, 0, stream>>>(xres, ff2_ln_g, ff2_ln_b, ybf);
  gemm_bt<1,128><<<dim3(3072/128, Mm/128), tb, 0, stream>>>(ybf, wt_ff2_1, ff2_b1, big, nullptr, nullptr, nullptr, Mm, 3072, 768, 0.f);
  gemm_bt<2,64><<<dim3(768/64, Mm/128), tb, 0, stream>>>(big, wt_ff2_2, ff2_b2, nullptr, xres, nullptr, nullptr, Mm, 768, 3072, 0.5f);

  // --- final LN ---
  ln_kernel<false><<<Mm, tb, 0, stream>>>(xres, fin_ln_g, fin_ln_b, (void*)xres);
}

// Round 12
// 548.058 us; speedup vs baseline: 1.3040x; 1.0744x over previous
//
#include <hip/hip_runtime.h>
#include <math.h>

// Problem constants
#define Bb 8
#define Nn 1024
#define Dd 768
#define Hh 12
#define Mm 8192   // Bb*Nn

typedef __attribute__((ext_vector_type(4))) float f32x4;
typedef __attribute__((ext_vector_type(8))) __bf16 bf16x8;

__device__ __forceinline__ float bf2f(unsigned short u) {
  union { unsigned int i; float f; } v; v.i = ((unsigned int)u) << 16; return v.f;
}
__device__ __forceinline__ unsigned short f2bf(float f) {
  union { float f; unsigned int i; } v; v.f = f;
  unsigned int u = v.i;
  return (unsigned short)((u + 0x7FFFu + ((u >> 16) & 1u)) >> 16);
}
__device__ __forceinline__ unsigned int pack2bf(float a, float b) {
  union { __bf16 h[2]; unsigned int u; } x;
  x.h[0] = (__bf16)a; x.h[1] = (__bf16)b; return x.u;
}

__device__ __forceinline__ void gload16(const void* g, void* l) {
  __builtin_amdgcn_global_load_lds(
      (const __attribute__((address_space(1))) unsigned int*)g,
      (__attribute__((address_space(3))) unsigned int*)l, 16, 0, 0);
}

// Branch-free GELU (erf via Abramowitz-Stegun 7.1.26, |eps|<=1.5e-7)
__device__ __forceinline__ float gelu_f(float v) {
  const float z = fabsf(v) * 0.7071067811865475f;
  const float t = __builtin_amdgcn_rcpf(1.f + 0.3275911f * z);
  const float poly = t*(0.254829592f + t*(-0.284496736f + t*(1.421413741f +
                     t*(-1.453152027f + t*1.061405429f))));
  float er = 1.f - poly * __expf(-z * z);
  er = copysignf(er, v);
  return 0.5f * v * (1.f + er);
}

// ---------------- GEMM: C[M,N] = epi(A[M,K] * Bt[N,K]^T + bias) ----------------
// BK=64 K-step, 2-phase. LDS rows 128B pitch, T2 XOR-swizzle (rule-#21 pattern).
// NT = 128 or 64. XCD-chunked bijective swizzle (m204).
// EPI 0: store bf16; 1: GELU->bf16; 2: Res += scale*v; 3: GLU (N/2 bf16);
// EPI 4: Res = Xin + scale*v; EPI 5: qkv with fused V-transpose (V cols -> Vtr)
template<int EPI, int NT>
__global__ __launch_bounds__(256)
void gemm_bt(const unsigned short* __restrict__ A,
             const unsigned short* __restrict__ Bt,
             const float* __restrict__ bias,
             unsigned short* __restrict__ Cbf,
             float* __restrict__ Res,
             const float* __restrict__ Xin,
             unsigned short* __restrict__ Vtr,
             int M, int N, int K, float scale)
{
  __shared__ __align__(16) unsigned short Asm[128*64];
  __shared__ __align__(16) unsigned short Bsm[NT*64];
  const int tid = threadIdx.x;
  const int wv = tid >> 6, lane = tid & 63;
  const int lr = lane & 15, lg = lane >> 4;
  const int wr = wv >> 1, wc = wv & 1;
  constexpr int JN = NT / 32;       // col-groups of 16 per wave

  // ---- bijective XCD-chunked swizzle ----
  const int gx = gridDim.x, gy = gridDim.y;
  const int nwg = gx * gy;
  const int lin = blockIdx.y * gx + blockIdx.x;
  const int q8 = nwg >> 3, r8 = nwg & 7;
  const int xcd = lin & 7, lidx = lin >> 3;
  const int wg = ((xcd < r8) ? xcd * (q8 + 1) : r8 * (q8 + 1) + (xcd - r8) * q8) + lidx;
  const int bx = wg % gx;
  const int by = wg / gx;

  const int n0 = bx * NT, m0 = by * 128;

  f32x4 acc[4][JN] = {};

  const int srow8 = lane >> 3;                    // row within 8-row group
  const int scol  = ((lane & 7) ^ srow8) * 8;     // pre-swizzled source col (elems)
  const unsigned short* Agp = A + (size_t)(m0 + wv*32 + srow8)*K + scol;
  const unsigned short* Bgp = (NT == 128)
      ? Bt + (size_t)(n0 + wv*32 + srow8)*K + scol
      : Bt + (size_t)(n0 + wv*16 + srow8)*K + scol;
  const int swr = (lr & 7) << 4;                  // read-side XOR (bytes)

  for (int kt = 0; kt < K; kt += 64) {
#pragma unroll
    for (int k = 0; k < 4; k++)
      gload16(Agp + (size_t)(k*8)*K + kt, Asm + (wv*32 + k*8)*64);
    if (NT == 128) {
#pragma unroll
      for (int k = 0; k < 4; k++)
        gload16(Bgp + (size_t)(k*8)*K + kt, Bsm + (wv*32 + k*8)*64);
    } else {
#pragma unroll
      for (int k = 0; k < 2; k++)
        gload16(Bgp + (size_t)(k*8)*K + kt, Bsm + (wv*16 + k*8)*64);
    }
    __syncthreads();   // drains vmcnt -> LDS tiles ready
    bf16x8 af[4], af2[4], bfr[JN], bfr2[JN];
#pragma unroll
    for (int i = 0; i < 4; i++) {
      const char* base = (const char*)Asm + (wr*64 + i*16 + lr)*128;
      af[i]  = *(const bf16x8*)(base + ((lg*16)      ^ swr));
      af2[i] = *(const bf16x8*)(base + ((lg*16 + 64) ^ swr));
    }
#pragma unroll
    for (int j = 0; j < JN; j++) {
      const char* base = (const char*)Bsm + (wc*(NT/2) + j*16 + lr)*128;
      bfr[j]  = *(const bf16x8*)(base + ((lg*16)      ^ swr));
      bfr2[j] = *(const bf16x8*)(base + ((lg*16 + 64) ^ swr));
    }
#pragma unroll
    for (int i = 0; i < 4; i++)
#pragma unroll
      for (int j = 0; j < JN; j++) {
        acc[i][j] = __builtin_amdgcn_mfma_f32_16x16x32_bf16(af[i],  bfr[j],  acc[i][j], 0, 0, 0);
        acc[i][j] = __builtin_amdgcn_mfma_f32_16x16x32_bf16(af2[i], bfr2[j], acc[i][j], 0, 0, 0);
      }
    __syncthreads();   // compute done before next stage overwrites
  }

#pragma unroll
  for (int i = 0; i < 4; i++) {
    const int rg = m0 + wr*64 + i*16 + lg*4;
    if (EPI == 3) {
      // GLU: col-groups alternate u (even) / gate (odd); write N/2 bf16 cols
#pragma unroll
      for (int j = 0; j < JN; j += 2) {
        const int cgu = n0 + wc*(NT/2) + j*16 + lr;
        const float bu = bias[cgu], bg = bias[cgu + 16];
        const int ocol = (n0 >> 1) + wc*(NT/4) + (j >> 1)*16 + lr;
#pragma unroll
        for (int e = 0; e < 4; e++) {
          float u  = acc[i][j][e]   + bu;
          float gt = acc[i][j+1][e] + bg;
          Cbf[(size_t)(rg + e) * (N >> 1) + ocol] = f2bf(u / (1.f + __expf(-gt)));
        }
      }
    } else if (EPI == 5 && n0 >= 1536) {
      // V columns: write transposed into Vtr[(b*Hh+h)*64 + d][n]
#pragma unroll
      for (int j = 0; j < JN; j++) {
        const int cg = n0 + wc*(NT/2) + j*16 + lr;
        const float bv = bias[cg];
        const int vo = cg - 1536;
        const int hh = vo >> 6, d = vo & 63;
        const int bb_ = rg >> 10, nn_ = rg & 1023;
        ushort4 o4;
        o4.x = f2bf(acc[i][j][0] + bv);
        o4.y = f2bf(acc[i][j][1] + bv);
        o4.z = f2bf(acc[i][j][2] + bv);
        o4.w = f2bf(acc[i][j][3] + bv);
        *(ushort4*)(Vtr + (((size_t)bb_*Hh + hh)*64 + d)*1024 + nn_) = o4;
      }
    } else {
#pragma unroll
      for (int j = 0; j < JN; j++) {
        const int cg = n0 + wc*(NT/2) + j*16 + lr;
        const float bv = bias[cg];
#pragma unroll
        for (int e = 0; e < 4; e++) {
          float v = acc[i][j][e] + bv;
          const size_t idx = (size_t)(rg + e) * N + cg;
          if (EPI == 1) {
            Cbf[idx] = f2bf(gelu_f(v));
          } else if (EPI == 0 || EPI == 5) {
            Cbf[idx] = f2bf(v);
          } else if (EPI == 2) {
            Res[idx] += scale * v;
          } else {  // EPI 4
            Res[idx] = Xin[idx] + scale * v;
          }
        }
      }
    }
  }
}

// ---------------- LayerNorm over D=768, one block per row ----------------
template<bool OBF>
__global__ __launch_bounds__(256)
void ln_kernel(const float* x, const float* __restrict__ g,
               const float* __restrict__ b, void* out)
{
  const int row = blockIdx.x, tid = threadIdx.x;
  const float* xr = x + (size_t)row * Dd;
  float v0 = xr[tid], v1 = xr[tid+256], v2 = xr[tid+512];
  float s = v0+v1+v2, q = v0*v0+v1*v1+v2*v2;
  for (int off = 32; off; off >>= 1) { s += __shfl_down(s, off); q += __shfl_down(q, off); }
  __shared__ float ps[4], pq[4];
  if ((tid & 63) == 0) { ps[tid>>6] = s; pq[tid>>6] = q; }
  __syncthreads();
  s = ps[0]+ps[1]+ps[2]+ps[3]; q = pq[0]+pq[1]+pq[2]+pq[3];
  const float mean = s * (1.f/768.f);
  const float rstd = rsqrtf(q*(1.f/768.f) - mean*mean + 1e-5f);
  float y0 = (v0-mean)*rstd*g[tid]     + b[tid];
  float y1 = (v1-mean)*rstd*g[tid+256] + b[tid+256];
  float y2 = (v2-mean)*rstd*g[tid+512] + b[tid+512];
  if (OBF) {
    unsigned short* o = (unsigned short*)out + (size_t)row * Dd;
    o[tid] = f2bf(y0); o[tid+256] = f2bf(y1); o[tid+512] = f2bf(y2);
  } else {
    float* o = (float*)out + (size_t)row * Dd;
    o[tid] = y0; o[tid+256] = y1; o[tid+512] = y2;
  }
}

// ---------------- weight prep ----------------
__global__ __launch_bounds__(256)
void transpose_w(const float* __restrict__ src, unsigned short* __restrict__ dst,
                 int K, int N)
{
  __shared__ float t[32][33];
  const int tx = threadIdx.x, ty = threadIdx.y;
  const int n0 = blockIdx.x * 32, k0 = blockIdx.y * 32;
#pragma unroll
  for (int i = 0; i < 4; i++) t[ty + i*8][tx] = src[(size_t)(k0 + ty + i*8)*N + n0 + tx];
  __syncthreads();
#pragma unroll
  for (int i = 0; i < 4; i++)
    dst[(size_t)(n0 + ty + i*8)*K + k0 + tx] = f2bf(t[tx][ty + i*8]);
}

__global__ __launch_bounds__(256)
void convert_bf(const float* __restrict__ src, unsigned short* __restrict__ dst, int n)
{
  for (int i = blockIdx.x*256 + threadIdx.x; i < n; i += gridDim.x*256)
    dst[i] = f2bf(src[i]);
}

// pwin weight permute+convert (u/gate interleave for GLU epilogue)
__global__ __launch_bounds__(256)
void perm_pwin(const float* __restrict__ w, const float* __restrict__ b,
               unsigned short* __restrict__ wt, float* __restrict__ bperm)
{
  const int r = blockIdx.x;             // 1536 rows
  const int blk = r >> 7, g = (r >> 4) & 7, t = r & 15;
  const int orig = blk*64 + ((g >> 1) << 4) + t + ((g & 1) ? 768 : 0);
  const float* src = w + (size_t)orig * 768;
  unsigned short* dst = wt + (size_t)r * 768;
  const int tid = threadIdx.x;
  dst[tid] = f2bf(src[tid]); dst[tid+256] = f2bf(src[tid+256]); dst[tid+512] = f2bf(src[tid+512]);
  if (tid == 0) bperm[r] = b[orig];
}

// dw_w (768,1,9) -> dwwT (9,768)
__global__ __launch_bounds__(256)
void dw_tr(const float* __restrict__ src, float* __restrict__ dst)
{
  const int id = blockIdx.x*256 + threadIdx.x;
  if (id >= 9*768) return;
  const int k = id / 768, d = id % 768;
  dst[id] = src[d*9 + k];
}

// ---------------- fused attention v4 (R8-proven): QBLK=128, 8 waves ----------------
// LDS = Kl 9216 + Vt 9344 + Pl 18432 + relh 8192 = 45184 B -> 3 blocks/CU x 8 waves;
// grid 768 = exactly 3/CU. Natural VGPR ~48 (no min-waves bound — see R9 spill).
__global__ __launch_bounds__(512)
void attn_kernel(const unsigned short* __restrict__ qkv,
                 const unsigned short* __restrict__ vtr,  // [bh][64][1024]
                 const float* __restrict__ rel,           // (2047, 12)
                 unsigned short* __restrict__ out)
{
  const int bh = blockIdx.x; const int b = bh / Hh, h = bh % Hh;
  const int q0 = blockIdx.y * 128;
  const int tid = threadIdx.x, wv = tid >> 6, lane = tid & 63;
  const int lr = lane & 15, lg = lane >> 4;

  __shared__ __align__(16) unsigned short Kl[64*72];        // [key][d], pitch 72
  __shared__ __align__(16) unsigned short Vt[64*72 + 64];   // [d][key], pitch 72 + stagger
  __shared__ __align__(16) unsigned short Pl[8*16*72];      // per-wave [q][key], pitch 72
  __shared__ float relh[2048];

  for (int i = tid; i < 2047; i += 512) relh[i] = rel[(size_t)i*Hh + h] * 1.44269504f;

  // Q fragments scaled by 0.125*log2e (exp2-domain softmax)
  const size_t qrow = (size_t)(b*Nn + q0 + wv*16 + lr);
  const bf16x8 qraw0 = *(const bf16x8*)(qkv + qrow*2304 + h*64 + lg*8);
  const bf16x8 qraw1 = *(const bf16x8*)(qkv + qrow*2304 + h*64 + 32 + lg*8);
  bf16x8 qf0, qf1;
#pragma unroll
  for (int e = 0; e < 8; e++) {
    qf0[e] = (__bf16)((float)qraw0[e] * 0.180336884f);
    qf1[e] = (__bf16)((float)qraw1[e] * 0.180336884f);
  }

  const int sd = tid >> 3;            // 0..63 (K: key row / V: d row)
  const int sc = (tid & 7) * 8;       // 8-elem chunk
  unsigned short* Pw = Pl + wv*16*72;

  // T14 async staging: one bf16x8 each for K and V per thread
  const unsigned short* kbase = qkv + (size_t)(b*Nn + sd)*2304 + 768 + h*64 + sc;
  const unsigned short* vbase = vtr + ((size_t)bh*64 + sd)*1024 + sc;
  bf16x8 kA = *(const bf16x8*)(kbase);
  bf16x8 vA = *(const bf16x8*)(vbase);

  f32x4 O[4] = {};
  float mrow = -1e30f, lsum = 0.f;    // log2 domain
  const int qq = q0 + wv*16 + lr;

  __syncthreads();  // relh ready

  for (int kt = 0; kt < Nn; kt += 64) {
    { // publish staged regs to LDS
      *(bf16x8*)&Kl[sd*72 + sc] = kA;
      *(bf16x8*)&Vt[sd*72 + (sd>>4)*16 + sc] = vA;
    }
    __syncthreads();

    // issue next tile's loads (latency hides under compute below)
    if (kt + 64 < Nn) {
      kA = *(const bf16x8*)(kbase + (size_t)(kt + 64)*2304);
      vA = *(const bf16x8*)(vbase + kt + 64);
    }

    // QK^T swapped, bias as MFMA C-init: S[key][q=lr]
    const int bidx = kt - qq + (Nn - 1);
    f32x4 s[4];
#pragma unroll
    for (int kb = 0; kb < 4; kb++)
#pragma unroll
      for (int j = 0; j < 4; j++)
        s[kb][j] = relh[bidx + kb*16 + lg*4 + j];
#pragma unroll
    for (int kb = 0; kb < 4; kb++) {
      bf16x8 kfa = *(const bf16x8*)&Kl[(kb*16 + lr)*72 + lg*8];
      bf16x8 kfb = *(const bf16x8*)&Kl[(kb*16 + lr)*72 + 32 + lg*8];
      s[kb] = __builtin_amdgcn_mfma_f32_16x16x32_bf16(kfa, qf0, s[kb], 0, 0, 0);
      s[kb] = __builtin_amdgcn_mfma_f32_16x16x32_bf16(kfb, qf1, s[kb], 0, 0, 0);
    }

    float r = -1e30f;
#pragma unroll
    for (int kb = 0; kb < 4; kb++)
#pragma unroll
      for (int j = 0; j < 4; j++) r = fmaxf(r, s[kb][j]);
    r = fmaxf(r, __shfl_xor(r, 16)); r = fmaxf(r, __shfl_xor(r, 32));

    // defer-max (T13), log2 domain
    if (!__all(r <= mrow + 11.5f)) {
      const float mn = fmaxf(mrow, r);
      const float al = __builtin_amdgcn_exp2f(mrow - mn);
      mrow = mn;
      lsum *= al;
#pragma unroll
      for (int ni = 0; ni < 4; ni++) {
        O[ni][0]*=al; O[ni][1]*=al; O[ni][2]*=al; O[ni][3]*=al;
      }
    }

    float rs = 0.f;
    unsigned int pk[8];
#pragma unroll
    for (int kb = 0; kb < 4; kb++) {
      float p0 = __builtin_amdgcn_exp2f(s[kb][0]-mrow), p1 = __builtin_amdgcn_exp2f(s[kb][1]-mrow);
      float p2 = __builtin_amdgcn_exp2f(s[kb][2]-mrow), p3 = __builtin_amdgcn_exp2f(s[kb][3]-mrow);
      rs += (p0+p1) + (p2+p3);
      pk[kb*2]   = pack2bf(p0, p1);
      pk[kb*2+1] = pack2bf(p2, p3);
    }
    rs += __shfl_xor(rs, 16); rs += __shfl_xor(rs, 32);
    lsum += rs;

#pragma unroll
    for (int kb0 = 0; kb0 < 4; kb0++) {
      const int kb = (kb0 + lg) & 3;
      *(unsigned int*)&Pw[lr*72 + kb*16 + lg*4]     = pk[kb*2];
      *(unsigned int*)&Pw[lr*72 + kb*16 + lg*4 + 2] = pk[kb*2+1];
    }

    // PV: O[d][q] += V^T . P^T (wave-private P; in-order LDS pipe)
    bf16x8 pf0 = *(const bf16x8*)&Pw[lr*72 + lg*8];
    bf16x8 pf1 = *(const bf16x8*)&Pw[lr*72 + 32 + lg*8];
#pragma unroll
    for (int dt = 0; dt < 4; dt++) {
      bf16x8 vf0 = *(const bf16x8*)&Vt[(dt*16 + lr)*72 + dt*16 + lg*8];
      bf16x8 vf1 = *(const bf16x8*)&Vt[(dt*16 + lr)*72 + dt*16 + 32 + lg*8];
      O[dt] = __builtin_amdgcn_mfma_f32_16x16x32_bf16(vf0, pf0, O[dt], 0, 0, 0);
      O[dt] = __builtin_amdgcn_mfma_f32_16x16x32_bf16(vf1, pf1, O[dt], 0, 0, 0);
    }
    __syncthreads();
  }

  const float rl = 1.f / lsum;
#pragma unroll
  for (int dt = 0; dt < 4; dt++) {
    ushort4 o4;
    o4.x = f2bf(O[dt][0]*rl); o4.y = f2bf(O[dt][1]*rl);
    o4.z = f2bf(O[dt][2]*rl); o4.w = f2bf(O[dt][3]*rl);
    *(ushort4*)(out + (size_t)(b*Nn + qq)*Dd + h*64 + dt*16 + lg*4) = o4;
  }
}

// ---------------- conv path ----------------
// dwconv v2: each thread computes 4 consecutive n for 8 channels.
// Loads 12 glu rows once (vs 4x9) -> 3x read reduction. out[n0+j] = sum_k w[k]*g[j+k].
__global__ __launch_bounds__(256)
void dwconv(const unsigned short* __restrict__ glu, const float* __restrict__ dwwT,
            const float* __restrict__ dwb, unsigned short* __restrict__ z)
{
  const int id = blockIdx.x*256 + threadIdx.x;
  if (id >= (Mm/4)*96) return;
  const int t = id / 96, c8 = (id % 96) * 8;
  const int b = t / (Nn/4), n0 = (t % (Nn/4)) * 4;

  bf16x8 zero;
#pragma unroll
  for (int e = 0; e < 8; e++) zero[e] = (__bf16)0.f;

  bf16x8 g[12];
#pragma unroll
  for (int rr = 0; rr < 12; rr++) {
    const int nn = n0 + rr - 4;
    g[rr] = (nn >= 0 && nn < Nn)
        ? *(const bf16x8*)&glu[(size_t)(b*Nn + nn)*768 + c8] : zero;
  }

  float acc[4][8];
#pragma unroll
  for (int j = 0; j < 4; j++)
#pragma unroll
    for (int e = 0; e < 8; e++) acc[j][e] = dwb[c8 + e];

#pragma unroll
  for (int k = 0; k < 9; k++) {
    const float4 w0 = *(const float4*)&dwwT[k*768 + c8];
    const float4 w1 = *(const float4*)&dwwT[k*768 + c8 + 4];
    const float w[8] = {w0.x, w0.y, w0.z, w0.w, w1.x, w1.y, w1.z, w1.w};
#pragma unroll
    for (int j = 0; j < 4; j++)
#pragma unroll
      for (int e = 0; e < 8; e++)
        acc[j][e] += w[e] * (float)g[j + k][e];
  }

#pragma unroll
  for (int j = 0; j < 4; j++) {
    bf16x8 o;
#pragma unroll
    for (int e = 0; e < 8; e++) o[e] = (__bf16)acc[j][e];
    *(bf16x8*)&z[(size_t)(b*Nn + n0 + j)*768 + c8] = o;
  }
}

__global__ __launch_bounds__(192)
void bn_part(const unsigned short* __restrict__ z, float* __restrict__ psum,
             float* __restrict__ psq)
{
  const int blk = blockIdx.x, t = threadIdx.x;   // 64 blocks x 192 threads, 4 ch each
  const int c4 = t * 4;
  float s0=0,s1=0,s2=0,s3=0, q0=0,q1=0,q2=0,q3=0;
  for (int r = 0; r < 128; r++) {
    ushort4 v4 = *(const ushort4*)&z[(size_t)(blk*128 + r)*Dd + c4];
    float a = bf2f(v4.x), b_ = bf2f(v4.y), c = bf2f(v4.z), d = bf2f(v4.w);
    s0 += a; s1 += b_; s2 += c; s3 += d;
    q0 += a*a; q1 += b_*b_; q2 += c*c; q3 += d*d;
  }
  float4 sv = {s0, s1, s2, s3}, qv = {q0, q1, q2, q3};
  *(float4*)&psum[(size_t)blk*Dd + c4] = sv;
  *(float4*)&psq [(size_t)blk*Dd + c4] = qv;
}

__global__ __launch_bounds__(256)
void bn_final(const float* __restrict__ psum, const float* __restrict__ psq,
              const float* __restrict__ g, const float* __restrict__ bb,
              float* __restrict__ scale, float* __restrict__ shift)
{
  const int c = blockIdx.x*256 + threadIdx.x;
  if (c >= Dd) return;
  float s = 0.f, q = 0.f;
  for (int i = 0; i < 64; i++) { s += psum[(size_t)i*Dd + c]; q += psq[(size_t)i*Dd + c]; }
  const float mean = s / (float)Mm;
  const float var  = q / (float)Mm - mean*mean;
  const float sc = g[c] * rsqrtf(var + 1e-5f);
  scale[c] = sc; shift[c] = bb[c] - mean*sc;
}

__global__ __launch_bounds__(256)
void bn_silu(const unsigned short* __restrict__ z, const float* __restrict__ scale,
             const float* __restrict__ shift, unsigned short* __restrict__ out)
{
  const int id = blockIdx.x*256 + threadIdx.x;
  if (id >= Mm*96) return;
  const int row = id / 96, c8 = (id % 96) * 8;
  bf16x8 v = *(const bf16x8*)&z[(size_t)row*Dd + c8];
  bf16x8 o;
#pragma unroll
  for (int e = 0; e < 8; e++) {
    float t = (float)v[e] * scale[c8+e] + shift[c8+e];
    o[e] = (__bf16)(t / (1.f + __expf(-t)));
  }
  *(bf16x8*)&out[(size_t)row*Dd + c8] = o;
}

// ---------------- host ----------------
extern "C" void kernel_launch(void* const* d_in, const int* in_sizes, int n_in,
                              void* d_out, int out_size, void* d_ws, size_t ws_size,
                              hipStream_t stream)
{
  const float* x        = (const float*)d_in[0];
  const float* ff1_ln_g = (const float*)d_in[1];
  const float* ff1_ln_b = (const float*)d_in[2];
  const float* ff1_w1   = (const float*)d_in[3];
  const float* ff1_b1   = (const float*)d_in[4];
  const float* ff1_w2   = (const float*)d_in[5];
  const float* ff1_b2   = (const float*)d_in[6];
  const float* attn_ln_g= (const float*)d_in[7];
  const float* attn_ln_b= (const float*)d_in[8];
  const float* qkv_w    = (const float*)d_in[9];
  const float* qkv_b    = (const float*)d_in[10];
  const float* proj_w   = (const float*)d_in[11];
  const float* proj_b   = (const float*)d_in[12];
  const float* rel_tab  = (const float*)d_in[13];
  const float* conv_ln_g= (const float*)d_in[14];
  const float* conv_ln_b= (const float*)d_in[15];
  const float* pwin_w   = (const float*)d_in[16];
  const float* pwin_b   = (const float*)d_in[17];
  const float* dw_w     = (const float*)d_in[18];
  const float* dw_b     = (const float*)d_in[19];
  const float* bn_g     = (const float*)d_in[20];
  const float* bn_b     = (const float*)d_in[21];
  const float* pwout_w  = (const float*)d_in[22];
  const float* pwout_b  = (const float*)d_in[23];
  const float* ff2_ln_g = (const float*)d_in[24];
  const float* ff2_ln_b = (const float*)d_in[25];
  const float* ff2_w1   = (const float*)d_in[26];
  const float* ff2_b1   = (const float*)d_in[27];
  const float* ff2_w2   = (const float*)d_in[28];
  const float* ff2_b2   = (const float*)d_in[29];
  const float* fin_ln_g = (const float*)d_in[30];
  const float* fin_ln_b = (const float*)d_in[31];

  char* ws = (char*)d_ws;
  size_t off = 0;
  auto alloc = [&](size_t bytes) { char* p = ws + off; off += (bytes + 255) & ~(size_t)255; return p; };
  unsigned short* wt_ff1_1 = (unsigned short*)alloc((size_t)3072*768*2);
  unsigned short* wt_ff1_2 = (unsigned short*)alloc((size_t)768*3072*2);
  unsigned short* wt_qkv   = (unsigned short*)alloc((size_t)2304*768*2);
  unsigned short* wt_proj  = (unsigned short*)alloc((size_t)768*768*2);
  unsigned short* wt_pwin  = (unsigned short*)alloc((size_t)1536*768*2);
  unsigned short* wt_pwout = (unsigned short*)alloc((size_t)768*768*2);
  unsigned short* wt_ff2_1 = (unsigned short*)alloc((size_t)3072*768*2);
  unsigned short* wt_ff2_2 = (unsigned short*)alloc((size_t)768*3072*2);
  unsigned short* ybf      = (unsigned short*)alloc((size_t)Mm*768*2);
  unsigned short* big      = (unsigned short*)alloc((size_t)Mm*3072*2);
  unsigned short* abuf     = (unsigned short*)alloc((size_t)Mm*768*2);
  float* psum    = (float*)alloc((size_t)64*768*4);
  float* psq     = (float*)alloc((size_t)64*768*4);
  float* bnscale = (float*)alloc((size_t)768*4);
  float* bnshift = (float*)alloc((size_t)768*4);
  float* dwwT    = (float*)alloc((size_t)9*768*4);
  float* bperm   = (float*)alloc((size_t)1536*4);
  if (off > ws_size) return;

  // vtr lives in big's unused tail (qkv rows use pitch 2304 of the 3072 alloc)
  unsigned short* vtr = big + (size_t)Mm*2304;

  float* xres = (float*)d_out;
  const dim3 tb(256);

  // --- weight prep ---
  transpose_w<<<dim3(3072/32, 768/32), dim3(32,8), 0, stream>>>(ff1_w1, wt_ff1_1, 768, 3072);
  transpose_w<<<dim3(768/32, 3072/32), dim3(32,8), 0, stream>>>(ff1_w2, wt_ff1_2, 3072, 768);
  transpose_w<<<dim3(2304/32, 768/32), dim3(32,8), 0, stream>>>(qkv_w,  wt_qkv,  768, 2304);
  transpose_w<<<dim3(768/32, 768/32),  dim3(32,8), 0, stream>>>(proj_w, wt_proj, 768, 768);
  transpose_w<<<dim3(3072/32, 768/32), dim3(32,8), 0, stream>>>(ff2_w1, wt_ff2_1, 768, 3072);
  transpose_w<<<dim3(768/32, 3072/32), dim3(32,8), 0, stream>>>(ff2_w2, wt_ff2_2, 3072, 768);
  perm_pwin<<<1536, tb, 0, stream>>>(pwin_w, pwin_b, wt_pwin, bperm);
  convert_bf<<<2048, tb, 0, stream>>>(pwout_w, wt_pwout, 768*768);
  dw_tr<<<27, tb, 0, stream>>>(dw_w, dwwT);

  // --- FFN1: xres = x + 0.5*FFN(LN(x)) ---
  ln_kernel<true><<<Mm, tb, 0, stream>>>(x, ff1_ln_g, ff1_ln_b, ybf);
  gemm_bt<1,128><<<dim3(3072/128, Mm/128), tb, 0, stream>>>(ybf, wt_ff1_1, ff1_b1, big, nullptr, nullptr, nullptr, Mm, 3072, 768, 0.f);
  gemm_bt<4,64><<<dim3(768/64, Mm/128), tb, 0, stream>>>(big, wt_ff1_2, ff1_b2, nullptr, xres, x, nullptr, Mm, 768, 3072, 0.5f);

  // --- attention (qkv GEMM writes V transposed into vtr via EPI5) ---
  ln_kernel<true><<<Mm, tb, 0, stream>>>(xres, attn_ln_g, attn_ln_b, ybf);
  gemm_bt<5,128><<<dim3(2304/128, Mm/128), tb, 0, stream>>>(ybf, wt_qkv, qkv_b, big, nullptr, nullptr, vtr, Mm, 2304, 768, 0.f);
  attn_kernel<<<dim3(Bb*Hh, Nn/128), dim3(512), 0, stream>>>(big, vtr, rel_tab, abuf);
  gemm_bt<2,64><<<dim3(768/64, Mm/128), tb, 0, stream>>>(abuf, wt_proj, proj_b, nullptr, xres, nullptr, nullptr, Mm, 768, 768, 1.0f);

  // --- conv module ---
  ln_kernel<true><<<Mm, tb, 0, stream>>>(xres, conv_ln_g, conv_ln_b, ybf);
  gemm_bt<3,128><<<dim3(1536/128, Mm/128), tb, 0, stream>>>(ybf, wt_pwin, bperm, abuf, nullptr, nullptr, nullptr, Mm, 1536, 768, 0.f);
  dwconv<<<((Mm/4)*96)/256, tb, 0, stream>>>(abuf, dwwT, dw_b, ybf);
  bn_part<<<64, dim3(192), 0, stream>>>(ybf, psum, psq);
  bn_final<<<3, tb, 0, stream>>>(psum, psq, bn_g, bn_b, bnscale, bnshift);
  bn_silu<<<(Mm*96)/256, tb, 0, stream>>>(ybf, bnscale, bnshift, abuf);
  gemm_bt<2,64><<<dim3(768/64, Mm/128), tb, 0, stream>>>(abuf, wt_pwout, pwout_b, nullptr, xres, nullptr, nullptr, Mm, 768, 768, 1.0f);

  // --- FFN2 ---
  ln_kernel<true><<<Mm, tb, 0, stream>>>(xres, ff2_ln_g, ff2_ln_b, ybf);
  gemm_bt<1,128><<<dim3(3072/128, Mm/128), tb, 0, stream>>>(ybf, wt_ff2_1, ff2_b1, big, nullptr, nullptr, nullptr, Mm, 3072, 768, 0.f);
  gemm_bt<2,64><<<dim3(768/64, Mm/128), tb, 0, stream>>>(big, wt_ff2_2, ff2_b2, nullptr, xres, nullptr, nullptr, Mm, 768, 3072, 0.5f);

  // --- final LN ---
  ln_kernel<false><<<Mm, tb, 0, stream>>>(xres, fin_ln_g, fin_ln_b, (void*)xres);
}

// Round 13
// 532.427 us; speedup vs baseline: 1.3423x; 1.0294x over previous
//
#include <hip/hip_runtime.h>
#include <math.h>

// Problem constants
#define Bb 8
#define Nn 1024
#define Dd 768
#define Hh 12
#define Mm 8192   // Bb*Nn

typedef __attribute__((ext_vector_type(4))) float f32x4;
typedef __attribute__((ext_vector_type(8))) __bf16 bf16x8;

__device__ __forceinline__ float bf2f(unsigned short u) {
  union { unsigned int i; float f; } v; v.i = ((unsigned int)u) << 16; return v.f;
}
__device__ __forceinline__ unsigned short f2bf(float f) {
  union { float f; unsigned int i; } v; v.f = f;
  unsigned int u = v.i;
  return (unsigned short)((u + 0x7FFFu + ((u >> 16) & 1u)) >> 16);
}
__device__ __forceinline__ unsigned int pack2bf(float a, float b) {
  union { __bf16 h[2]; unsigned int u; } x;
  x.h[0] = (__bf16)a; x.h[1] = (__bf16)b; return x.u;
}

__device__ __forceinline__ void gload16(const void* g, void* l) {
  __builtin_amdgcn_global_load_lds(
      (const __attribute__((address_space(1))) unsigned int*)g,
      (__attribute__((address_space(3))) unsigned int*)l, 16, 0, 0);
}

// Branch-free GELU (erf via Abramowitz-Stegun 7.1.26, |eps|<=1.5e-7)
__device__ __forceinline__ float gelu_f(float v) {
  const float z = fabsf(v) * 0.7071067811865475f;
  const float t = __builtin_amdgcn_rcpf(1.f + 0.3275911f * z);
  const float poly = t*(0.254829592f + t*(-0.284496736f + t*(1.421413741f +
                     t*(-1.453152027f + t*1.061405429f))));
  float er = 1.f - poly * __expf(-z * z);
  er = copysignf(er, v);
  return 0.5f * v * (1.f + er);
}

// ---------------- GEMM: C[M,N] = epi(A[M,K] * Bt[N,K]^T + bias) ----------------
// BK=64 K-step, 2-phase. LDS rows 128B pitch, T2 XOR-swizzle (rule-#21 pattern).
// NT = 128 or 64. XCD-chunked bijective swizzle (m204).
// EPI 0: store bf16; 1: GELU->bf16; 2: Res += scale*v; 3: GLU (N/2 bf16);
// EPI 4: Res = Xin + scale*v; EPI 5: qkv with fused V-transpose (V cols -> Vtr)
template<int EPI, int NT>
__global__ __launch_bounds__(256)
void gemm_bt(const unsigned short* __restrict__ A,
             const unsigned short* __restrict__ Bt,
             const float* __restrict__ bias,
             unsigned short* __restrict__ Cbf,
             float* __restrict__ Res,
             const float* __restrict__ Xin,
             unsigned short* __restrict__ Vtr,
             int M, int N, int K, float scale)
{
  __shared__ __align__(16) unsigned short Asm[128*64];
  __shared__ __align__(16) unsigned short Bsm[NT*64];
  const int tid = threadIdx.x;
  const int wv = tid >> 6, lane = tid & 63;
  const int lr = lane & 15, lg = lane >> 4;
  const int wr = wv >> 1, wc = wv & 1;
  constexpr int JN = NT / 32;       // col-groups of 16 per wave

  // ---- bijective XCD-chunked swizzle ----
  const int gx = gridDim.x, gy = gridDim.y;
  const int nwg = gx * gy;
  const int lin = blockIdx.y * gx + blockIdx.x;
  const int q8 = nwg >> 3, r8 = nwg & 7;
  const int xcd = lin & 7, lidx = lin >> 3;
  const int wg = ((xcd < r8) ? xcd * (q8 + 1) : r8 * (q8 + 1) + (xcd - r8) * q8) + lidx;
  const int bx = wg % gx;
  const int by = wg / gx;

  const int n0 = bx * NT, m0 = by * 128;

  f32x4 acc[4][JN] = {};

  const int srow8 = lane >> 3;                    // row within 8-row group
  const int scol  = ((lane & 7) ^ srow8) * 8;     // pre-swizzled source col (elems)
  const unsigned short* Agp = A + (size_t)(m0 + wv*32 + srow8)*K + scol;
  const unsigned short* Bgp = (NT == 128)
      ? Bt + (size_t)(n0 + wv*32 + srow8)*K + scol
      : Bt + (size_t)(n0 + wv*16 + srow8)*K + scol;
  const int swr = (lr & 7) << 4;                  // read-side XOR (bytes)

  for (int kt = 0; kt < K; kt += 64) {
#pragma unroll
    for (int k = 0; k < 4; k++)
      gload16(Agp + (size_t)(k*8)*K + kt, Asm + (wv*32 + k*8)*64);
    if (NT == 128) {
#pragma unroll
      for (int k = 0; k < 4; k++)
        gload16(Bgp + (size_t)(k*8)*K + kt, Bsm + (wv*32 + k*8)*64);
    } else {
#pragma unroll
      for (int k = 0; k < 2; k++)
        gload16(Bgp + (size_t)(k*8)*K + kt, Bsm + (wv*16 + k*8)*64);
    }
    __syncthreads();   // drains vmcnt -> LDS tiles ready
    bf16x8 af[4], af2[4], bfr[JN], bfr2[JN];
#pragma unroll
    for (int i = 0; i < 4; i++) {
      const char* base = (const char*)Asm + (wr*64 + i*16 + lr)*128;
      af[i]  = *(const bf16x8*)(base + ((lg*16)      ^ swr));
      af2[i] = *(const bf16x8*)(base + ((lg*16 + 64) ^ swr));
    }
#pragma unroll
    for (int j = 0; j < JN; j++) {
      const char* base = (const char*)Bsm + (wc*(NT/2) + j*16 + lr)*128;
      bfr[j]  = *(const bf16x8*)(base + ((lg*16)      ^ swr));
      bfr2[j] = *(const bf16x8*)(base + ((lg*16 + 64) ^ swr));
    }
#pragma unroll
    for (int i = 0; i < 4; i++)
#pragma unroll
      for (int j = 0; j < JN; j++) {
        acc[i][j] = __builtin_amdgcn_mfma_f32_16x16x32_bf16(af[i],  bfr[j],  acc[i][j], 0, 0, 0);
        acc[i][j] = __builtin_amdgcn_mfma_f32_16x16x32_bf16(af2[i], bfr2[j], acc[i][j], 0, 0, 0);
      }
    __syncthreads();   // compute done before next stage overwrites
  }

#pragma unroll
  for (int i = 0; i < 4; i++) {
    const int rg = m0 + wr*64 + i*16 + lg*4;
    if (EPI == 3) {
      // GLU: col-groups alternate u (even) / gate (odd); write N/2 bf16 cols
#pragma unroll
      for (int j = 0; j < JN; j += 2) {
        const int cgu = n0 + wc*(NT/2) + j*16 + lr;
        const float bu = bias[cgu], bg = bias[cgu + 16];
        const int ocol = (n0 >> 1) + wc*(NT/4) + (j >> 1)*16 + lr;
#pragma unroll
        for (int e = 0; e < 4; e++) {
          float u  = acc[i][j][e]   + bu;
          float gt = acc[i][j+1][e] + bg;
          Cbf[(size_t)(rg + e) * (N >> 1) + ocol] = f2bf(u / (1.f + __expf(-gt)));
        }
      }
    } else if (EPI == 5 && n0 >= 1536) {
      // V columns: write transposed into Vtr[(b*Hh+h)*64 + d][n]
#pragma unroll
      for (int j = 0; j < JN; j++) {
        const int cg = n0 + wc*(NT/2) + j*16 + lr;
        const float bv = bias[cg];
        const int vo = cg - 1536;
        const int hh = vo >> 6, d = vo & 63;
        const int bb_ = rg >> 10, nn_ = rg & 1023;
        ushort4 o4;
        o4.x = f2bf(acc[i][j][0] + bv);
        o4.y = f2bf(acc[i][j][1] + bv);
        o4.z = f2bf(acc[i][j][2] + bv);
        o4.w = f2bf(acc[i][j][3] + bv);
        *(ushort4*)(Vtr + (((size_t)bb_*Hh + hh)*64 + d)*1024 + nn_) = o4;
      }
    } else {
#pragma unroll
      for (int j = 0; j < JN; j++) {
        const int cg = n0 + wc*(NT/2) + j*16 + lr;
        const float bv = bias[cg];
#pragma unroll
        for (int e = 0; e < 4; e++) {
          float v = acc[i][j][e] + bv;
          const size_t idx = (size_t)(rg + e) * N + cg;
          if (EPI == 1) {
            Cbf[idx] = f2bf(gelu_f(v));
          } else if (EPI == 0 || EPI == 5) {
            Cbf[idx] = f2bf(v);
          } else if (EPI == 2) {
            Res[idx] += scale * v;
          } else {  // EPI 4
            Res[idx] = Xin[idx] + scale * v;
          }
        }
      }
    }
  }
}

// ---------------- LayerNorm over D=768, one block per row ----------------
template<bool OBF>
__global__ __launch_bounds__(256)
void ln_kernel(const float* x, const float* __restrict__ g,
               const float* __restrict__ b, void* out)
{
  const int row = blockIdx.x, tid = threadIdx.x;
  const float* xr = x + (size_t)row * Dd;
  float v0 = xr[tid], v1 = xr[tid+256], v2 = xr[tid+512];
  float s = v0+v1+v2, q = v0*v0+v1*v1+v2*v2;
  for (int off = 32; off; off >>= 1) { s += __shfl_down(s, off); q += __shfl_down(q, off); }
  __shared__ float ps[4], pq[4];
  if ((tid & 63) == 0) { ps[tid>>6] = s; pq[tid>>6] = q; }
  __syncthreads();
  s = ps[0]+ps[1]+ps[2]+ps[3]; q = pq[0]+pq[1]+pq[2]+pq[3];
  const float mean = s * (1.f/768.f);
  const float rstd = rsqrtf(q*(1.f/768.f) - mean*mean + 1e-5f);
  float y0 = (v0-mean)*rstd*g[tid]     + b[tid];
  float y1 = (v1-mean)*rstd*g[tid+256] + b[tid+256];
  float y2 = (v2-mean)*rstd*g[tid+512] + b[tid+512];
  if (OBF) {
    unsigned short* o = (unsigned short*)out + (size_t)row * Dd;
    o[tid] = f2bf(y0); o[tid+256] = f2bf(y1); o[tid+512] = f2bf(y2);
  } else {
    float* o = (float*)out + (size_t)row * Dd;
    o[tid] = y0; o[tid+256] = y1; o[tid+512] = y2;
  }
}

// ---------------- unified weight prep (single dispatch) ----------------
// seg layout (block ranges):
//  [0,2304)      transpose ff1_w1 (768x3072 -> 3072x768 bf16), gx=96
//  [2304,4608)   transpose ff1_w2 (3072x768 -> 768x3072), gx=24
//  [4608,6336)   transpose qkv_w  (768x2304 -> 2304x768), gx=72
//  [6336,6912)   transpose proj_w (768x768), gx=24
//  [6912,9216)   transpose ff2_w1, gx=96
//  [9216,11520)  transpose ff2_w2, gx=24
//  [11520,13056) perm_pwin (1536 rows)
//  [13056,14080) convert pwout (589824 elems, grid-stride over 1024 blocks)
//  [14080,14107) dw_tr (6912 elems)
__global__ __launch_bounds__(256)
void prep_all(const float* __restrict__ ff1_w1, const float* __restrict__ ff1_w2,
              const float* __restrict__ qkv_w,  const float* __restrict__ proj_w,
              const float* __restrict__ ff2_w1, const float* __restrict__ ff2_w2,
              const float* __restrict__ pwin_w, const float* __restrict__ pwin_b,
              const float* __restrict__ pwout_w, const float* __restrict__ dw_w,
              unsigned short* __restrict__ wt_ff1_1, unsigned short* __restrict__ wt_ff1_2,
              unsigned short* __restrict__ wt_qkv,   unsigned short* __restrict__ wt_proj,
              unsigned short* __restrict__ wt_ff2_1, unsigned short* __restrict__ wt_ff2_2,
              unsigned short* __restrict__ wt_pwin,  float* __restrict__ bperm,
              unsigned short* __restrict__ wt_pwout, float* __restrict__ dwwT)
{
  __shared__ float t[32][33];
  const int tid = threadIdx.x;
  int bid = blockIdx.x;

  const float* src = nullptr; unsigned short* dst = nullptr;
  int K = 0, N = 0, gx = 0;
  if (bid < 2304)        { src = ff1_w1; dst = wt_ff1_1; K = 768;  N = 3072; gx = 96; }
  else if ((bid -= 2304) < 2304) { src = ff1_w2; dst = wt_ff1_2; K = 3072; N = 768;  gx = 24; }
  else if ((bid -= 2304) < 1728) { src = qkv_w;  dst = wt_qkv;   K = 768;  N = 2304; gx = 72; }
  else if ((bid -= 1728) < 576)  { src = proj_w; dst = wt_proj;  K = 768;  N = 768;  gx = 24; }
  else if ((bid -= 576)  < 2304) { src = ff2_w1; dst = wt_ff2_1; K = 768;  N = 3072; gx = 96; }
  else if ((bid -= 2304) < 2304) { src = ff2_w2; dst = wt_ff2_2; K = 3072; N = 768;  gx = 24; }
  else if ((bid -= 2304) < 1536) {
    // perm_pwin: row r of the interleaved layout
    const int r = bid;
    const int blk = r >> 7, g = (r >> 4) & 7, tt = r & 15;
    const int orig = blk*64 + ((g >> 1) << 4) + tt + ((g & 1) ? 768 : 0);
    const float* s2 = pwin_w + (size_t)orig * 768;
    unsigned short* d2 = wt_pwin + (size_t)r * 768;
    d2[tid] = f2bf(s2[tid]); d2[tid+256] = f2bf(s2[tid+256]); d2[tid+512] = f2bf(s2[tid+512]);
    if (tid == 0) bperm[r] = pwin_b[orig];
    return;
  }
  else if ((bid -= 1536) < 1024) {
    for (int i = bid*256 + tid; i < 768*768; i += 1024*256)
      wt_pwout[i] = f2bf(pwout_w[i]);
    return;
  }
  else {
    const int id = (bid - 1024)*256 + tid;
    if (id < 9*768) {
      const int k = id / 768, d = id % 768;
      dwwT[id] = dw_w[d*9 + k];
    }
    return;
  }

  // 32x32 transpose tile: src K x N -> dst N x K (bf16)
  const int tx = tid & 31, ty = tid >> 5;    // (32, 8)
  const int n0 = (bid % gx) * 32, k0 = (bid / gx) * 32;
#pragma unroll
  for (int i = 0; i < 4; i++) t[ty + i*8][tx] = src[(size_t)(k0 + ty + i*8)*N + n0 + tx];
  __syncthreads();
#pragma unroll
  for (int i = 0; i < 4; i++)
    dst[(size_t)(n0 + ty + i*8)*K + k0 + tx] = f2bf(t[tx][ty + i*8]);
}

// ---------------- fused attention v4 (R8-proven): QBLK=128, 8 waves ----------------
// LDS = Kl 9216 + Vt 9344 + Pl 18432 + relh 8192 = 45184 B -> 3 blocks/CU x 8 waves;
// grid 768 = exactly 3/CU. Natural VGPR ~48 (no min-waves bound — see R9 spill).
__global__ __launch_bounds__(512)
void attn_kernel(const unsigned short* __restrict__ qkv,
                 const unsigned short* __restrict__ vtr,  // [bh][64][1024]
                 const float* __restrict__ rel,           // (2047, 12)
                 unsigned short* __restrict__ out)
{
  const int bh = blockIdx.x; const int b = bh / Hh, h = bh % Hh;
  const int q0 = blockIdx.y * 128;
  const int tid = threadIdx.x, wv = tid >> 6, lane = tid & 63;
  const int lr = lane & 15, lg = lane >> 4;

  __shared__ __align__(16) unsigned short Kl[64*72];        // [key][d], pitch 72
  __shared__ __align__(16) unsigned short Vt[64*72 + 64];   // [d][key], pitch 72 + stagger
  __shared__ __align__(16) unsigned short Pl[8*16*72];      // per-wave [q][key], pitch 72
  __shared__ float relh[2048];

  for (int i = tid; i < 2047; i += 512) relh[i] = rel[(size_t)i*Hh + h] * 1.44269504f;

  // Q fragments scaled by 0.125*log2e (exp2-domain softmax)
  const size_t qrow = (size_t)(b*Nn + q0 + wv*16 + lr);
  const bf16x8 qraw0 = *(const bf16x8*)(qkv + qrow*2304 + h*64 + lg*8);
  const bf16x8 qraw1 = *(const bf16x8*)(qkv + qrow*2304 + h*64 + 32 + lg*8);
  bf16x8 qf0, qf1;
#pragma unroll
  for (int e = 0; e < 8; e++) {
    qf0[e] = (__bf16)((float)qraw0[e] * 0.180336884f);
    qf1[e] = (__bf16)((float)qraw1[e] * 0.180336884f);
  }

  const int sd = tid >> 3;            // 0..63 (K: key row / V: d row)
  const int sc = (tid & 7) * 8;       // 8-elem chunk
  unsigned short* Pw = Pl + wv*16*72;

  // T14 async staging: one bf16x8 each for K and V per thread
  const unsigned short* kbase = qkv + (size_t)(b*Nn + sd)*2304 + 768 + h*64 + sc;
  const unsigned short* vbase = vtr + ((size_t)bh*64 + sd)*1024 + sc;
  bf16x8 kA = *(const bf16x8*)(kbase);
  bf16x8 vA = *(const bf16x8*)(vbase);

  f32x4 O[4] = {};
  float mrow = -1e30f, lsum = 0.f;    // log2 domain
  const int qq = q0 + wv*16 + lr;

  __syncthreads();  // relh ready

  for (int kt = 0; kt < Nn; kt += 64) {
    { // publish staged regs to LDS
      *(bf16x8*)&Kl[sd*72 + sc] = kA;
      *(bf16x8*)&Vt[sd*72 + (sd>>4)*16 + sc] = vA;
    }
    __syncthreads();

    // issue next tile's loads (latency hides under compute below)
    if (kt + 64 < Nn) {
      kA = *(const bf16x8*)(kbase + (size_t)(kt + 64)*2304);
      vA = *(const bf16x8*)(vbase + kt + 64);
    }

    // QK^T swapped, bias as MFMA C-init: S[key][q=lr]
    const int bidx = kt - qq + (Nn - 1);
    f32x4 s[4];
#pragma unroll
    for (int kb = 0; kb < 4; kb++)
#pragma unroll
      for (int j = 0; j < 4; j++)
        s[kb][j] = relh[bidx + kb*16 + lg*4 + j];
#pragma unroll
    for (int kb = 0; kb < 4; kb++) {
      bf16x8 kfa = *(const bf16x8*)&Kl[(kb*16 + lr)*72 + lg*8];
      bf16x8 kfb = *(const bf16x8*)&Kl[(kb*16 + lr)*72 + 32 + lg*8];
      s[kb] = __builtin_amdgcn_mfma_f32_16x16x32_bf16(kfa, qf0, s[kb], 0, 0, 0);
      s[kb] = __builtin_amdgcn_mfma_f32_16x16x32_bf16(kfb, qf1, s[kb], 0, 0, 0);
    }

    float r = -1e30f;
#pragma unroll
    for (int kb = 0; kb < 4; kb++)
#pragma unroll
      for (int j = 0; j < 4; j++) r = fmaxf(r, s[kb][j]);
    r = fmaxf(r, __shfl_xor(r, 16)); r = fmaxf(r, __shfl_xor(r, 32));

    // defer-max (T13), log2 domain
    if (!__all(r <= mrow + 11.5f)) {
      const float mn = fmaxf(mrow, r);
      const float al = __builtin_amdgcn_exp2f(mrow - mn);
      mrow = mn;
      lsum *= al;
#pragma unroll
      for (int ni = 0; ni < 4; ni++) {
        O[ni][0]*=al; O[ni][1]*=al; O[ni][2]*=al; O[ni][3]*=al;
      }
    }

    float rs = 0.f;
    unsigned int pk[8];
#pragma unroll
    for (int kb = 0; kb < 4; kb++) {
      float p0 = __builtin_amdgcn_exp2f(s[kb][0]-mrow), p1 = __builtin_amdgcn_exp2f(s[kb][1]-mrow);
      float p2 = __builtin_amdgcn_exp2f(s[kb][2]-mrow), p3 = __builtin_amdgcn_exp2f(s[kb][3]-mrow);
      rs += (p0+p1) + (p2+p3);
      pk[kb*2]   = pack2bf(p0, p1);
      pk[kb*2+1] = pack2bf(p2, p3);
    }
    rs += __shfl_xor(rs, 16); rs += __shfl_xor(rs, 32);
    lsum += rs;

#pragma unroll
    for (int kb0 = 0; kb0 < 4; kb0++) {
      const int kb = (kb0 + lg) & 3;
      *(unsigned int*)&Pw[lr*72 + kb*16 + lg*4]     = pk[kb*2];
      *(unsigned int*)&Pw[lr*72 + kb*16 + lg*4 + 2] = pk[kb*2+1];
    }

    // PV: O[d][q] += V^T . P^T (wave-private P; in-order LDS pipe)
    bf16x8 pf0 = *(const bf16x8*)&Pw[lr*72 + lg*8];
    bf16x8 pf1 = *(const bf16x8*)&Pw[lr*72 + 32 + lg*8];
#pragma unroll
    for (int dt = 0; dt < 4; dt++) {
      bf16x8 vf0 = *(const bf16x8*)&Vt[(dt*16 + lr)*72 + dt*16 + lg*8];
      bf16x8 vf1 = *(const bf16x8*)&Vt[(dt*16 + lr)*72 + dt*16 + 32 + lg*8];
      O[dt] = __builtin_amdgcn_mfma_f32_16x16x32_bf16(vf0, pf0, O[dt], 0, 0, 0);
      O[dt] = __builtin_amdgcn_mfma_f32_16x16x32_bf16(vf1, pf1, O[dt], 0, 0, 0);
    }
    __syncthreads();
  }

  const float rl = 1.f / lsum;
#pragma unroll
  for (int dt = 0; dt < 4; dt++) {
    ushort4 o4;
    o4.x = f2bf(O[dt][0]*rl); o4.y = f2bf(O[dt][1]*rl);
    o4.z = f2bf(O[dt][2]*rl); o4.w = f2bf(O[dt][3]*rl);
    *(ushort4*)(out + (size_t)(b*Nn + qq)*Dd + h*64 + dt*16 + lg*4) = o4;
  }
}

// ---------------- conv path ----------------
// dwconv v2: each thread computes 4 consecutive n for 8 channels.
__global__ __launch_bounds__(256)
void dwconv(const unsigned short* __restrict__ glu, const float* __restrict__ dwwT,
            const float* __restrict__ dwb, unsigned short* __restrict__ z)
{
  const int id = blockIdx.x*256 + threadIdx.x;
  if (id >= (Mm/4)*96) return;
  const int t = id / 96, c8 = (id % 96) * 8;
  const int b = t / (Nn/4), n0 = (t % (Nn/4)) * 4;

  bf16x8 zero;
#pragma unroll
  for (int e = 0; e < 8; e++) zero[e] = (__bf16)0.f;

  bf16x8 g[12];
#pragma unroll
  for (int rr = 0; rr < 12; rr++) {
    const int nn = n0 + rr - 4;
    g[rr] = (nn >= 0 && nn < Nn)
        ? *(const bf16x8*)&glu[(size_t)(b*Nn + nn)*768 + c8] : zero;
  }

  float acc[4][8];
#pragma unroll
  for (int j = 0; j < 4; j++)
#pragma unroll
    for (int e = 0; e < 8; e++) acc[j][e] = dwb[c8 + e];

#pragma unroll
  for (int k = 0; k < 9; k++) {
    const float4 w0 = *(const float4*)&dwwT[k*768 + c8];
    const float4 w1 = *(const float4*)&dwwT[k*768 + c8 + 4];
    const float w[8] = {w0.x, w0.y, w0.z, w0.w, w1.x, w1.y, w1.z, w1.w};
#pragma unroll
    for (int j = 0; j < 4; j++)
#pragma unroll
      for (int e = 0; e < 8; e++)
        acc[j][e] += w[e] * (float)g[j + k][e];
  }

#pragma unroll
  for (int j = 0; j < 4; j++) {
    bf16x8 o;
#pragma unroll
    for (int e = 0; e < 8; e++) o[e] = (__bf16)acc[j][e];
    *(bf16x8*)&z[(size_t)(b*Nn + n0 + j)*768 + c8] = o;
  }
}

__global__ __launch_bounds__(192)
void bn_part(const unsigned short* __restrict__ z, float* __restrict__ psum,
             float* __restrict__ psq)
{
  const int blk = blockIdx.x, t = threadIdx.x;   // 64 blocks x 192 threads, 4 ch each
  const int c4 = t * 4;
  float s0=0,s1=0,s2=0,s3=0, q0=0,q1=0,q2=0,q3=0;
  for (int r = 0; r < 128; r++) {
    ushort4 v4 = *(const ushort4*)&z[(size_t)(blk*128 + r)*Dd + c4];
    float a = bf2f(v4.x), b_ = bf2f(v4.y), c = bf2f(v4.z), d = bf2f(v4.w);
    s0 += a; s1 += b_; s2 += c; s3 += d;
    q0 += a*a; q1 += b_*b_; q2 += c*c; q3 += d*d;
  }
  float4 sv = {s0, s1, s2, s3}, qv = {q0, q1, q2, q3};
  *(float4*)&psum[(size_t)blk*Dd + c4] = sv;
  *(float4*)&psq [(size_t)blk*Dd + c4] = qv;
}

__global__ __launch_bounds__(256)
void bn_final(const float* __restrict__ psum, const float* __restrict__ psq,
              const float* __restrict__ g, const float* __restrict__ bb,
              float* __restrict__ scale, float* __restrict__ shift)
{
  const int c = blockIdx.x*256 + threadIdx.x;
  if (c >= Dd) return;
  float s = 0.f, q = 0.f;
  for (int i = 0; i < 64; i++) { s += psum[(size_t)i*Dd + c]; q += psq[(size_t)i*Dd + c]; }
  const float mean = s / (float)Mm;
  const float var  = q / (float)Mm - mean*mean;
  const float sc = g[c] * rsqrtf(var + 1e-5f);
  scale[c] = sc; shift[c] = bb[c] - mean*sc;
}

__global__ __launch_bounds__(256)
void bn_silu(const unsigned short* __restrict__ z, const float* __restrict__ scale,
             const float* __restrict__ shift, unsigned short* __restrict__ out)
{
  const int id = blockIdx.x*256 + threadIdx.x;
  if (id >= Mm*96) return;
  const int row = id / 96, c8 = (id % 96) * 8;
  bf16x8 v = *(const bf16x8*)&z[(size_t)row*Dd + c8];
  bf16x8 o;
#pragma unroll
  for (int e = 0; e < 8; e++) {
    float t = (float)v[e] * scale[c8+e] + shift[c8+e];
    o[e] = (__bf16)(t / (1.f + __expf(-t)));
  }
  *(bf16x8*)&out[(size_t)row*Dd + c8] = o;
}

// ---------------- host ----------------
extern "C" void kernel_launch(void* const* d_in, const int* in_sizes, int n_in,
                              void* d_out, int out_size, void* d_ws, size_t ws_size,
                              hipStream_t stream)
{
  const float* x        = (const float*)d_in[0];
  const float* ff1_ln_g = (const float*)d_in[1];
  const float* ff1_ln_b = (const float*)d_in[2];
  const float* ff1_w1   = (const float*)d_in[3];
  const float* ff1_b1   = (const float*)d_in[4];
  const float* ff1_w2   = (const float*)d_in[5];
  const float* ff1_b2   = (const float*)d_in[6];
  const float* attn_ln_g= (const float*)d_in[7];
  const float* attn_ln_b= (const float*)d_in[8];
  const float* qkv_w    = (const float*)d_in[9];
  const float* qkv_b    = (const float*)d_in[10];
  const float* proj_w   = (const float*)d_in[11];
  const float* proj_b   = (const float*)d_in[12];
  const float* rel_tab  = (const float*)d_in[13];
  const float* conv_ln_g= (const float*)d_in[14];
  const float* conv_ln_b= (const float*)d_in[15];
  const float* pwin_w   = (const float*)d_in[16];
  const float* pwin_b   = (const float*)d_in[17];
  const float* dw_w     = (const float*)d_in[18];
  const float* dw_b     = (const float*)d_in[19];
  const float* bn_g     = (const float*)d_in[20];
  const float* bn_b     = (const float*)d_in[21];
  const float* pwout_w  = (const float*)d_in[22];
  const float* pwout_b  = (const float*)d_in[23];
  const float* ff2_ln_g = (const float*)d_in[24];
  const float* ff2_ln_b = (const float*)d_in[25];
  const float* ff2_w1   = (const float*)d_in[26];
  const float* ff2_b1   = (const float*)d_in[27];
  const float* ff2_w2   = (const float*)d_in[28];
  const float* ff2_b2   = (const float*)d_in[29];
  const float* fin_ln_g = (const float*)d_in[30];
  const float* fin_ln_b = (const float*)d_in[31];

  char* ws = (char*)d_ws;
  size_t off = 0;
  auto alloc = [&](size_t bytes) { char* p = ws + off; off += (bytes + 255) & ~(size_t)255; return p; };
  unsigned short* wt_ff1_1 = (unsigned short*)alloc((size_t)3072*768*2);
  unsigned short* wt_ff1_2 = (unsigned short*)alloc((size_t)768*3072*2);
  unsigned short* wt_qkv   = (unsigned short*)alloc((size_t)2304*768*2);
  unsigned short* wt_proj  = (unsigned short*)alloc((size_t)768*768*2);
  unsigned short* wt_pwin  = (unsigned short*)alloc((size_t)1536*768*2);
  unsigned short* wt_pwout = (unsigned short*)alloc((size_t)768*768*2);
  unsigned short* wt_ff2_1 = (unsigned short*)alloc((size_t)3072*768*2);
  unsigned short* wt_ff2_2 = (unsigned short*)alloc((size_t)768*3072*2);
  unsigned short* ybf      = (unsigned short*)alloc((size_t)Mm*768*2);
  unsigned short* big      = (unsigned short*)alloc((size_t)Mm*3072*2);
  unsigned short* abuf     = (unsigned short*)alloc((size_t)Mm*768*2);
  float* psum    = (float*)alloc((size_t)64*768*4);
  float* psq     = (float*)alloc((size_t)64*768*4);
  float* bnscale = (float*)alloc((size_t)768*4);
  float* bnshift = (float*)alloc((size_t)768*4);
  float* dwwT    = (float*)alloc((size_t)9*768*4);
  float* bperm   = (float*)alloc((size_t)1536*4);
  if (off > ws_size) return;

  // vtr lives in big's unused tail (qkv rows use pitch 2304 of the 3072 alloc)
  unsigned short* vtr = big + (size_t)Mm*2304;

  float* xres = (float*)d_out;
  const dim3 tb(256);

  // --- unified weight prep (1 dispatch; was 9) ---
  prep_all<<<14107, tb, 0, stream>>>(ff1_w1, ff1_w2, qkv_w, proj_w, ff2_w1, ff2_w2,
                                     pwin_w, pwin_b, pwout_w, dw_w,
                                     wt_ff1_1, wt_ff1_2, wt_qkv, wt_proj,
                                     wt_ff2_1, wt_ff2_2, wt_pwin, bperm,
                                     wt_pwout, dwwT);

  // --- FFN1: xres = x + 0.5*FFN(LN(x)) ---
  ln_kernel<true><<<Mm, tb, 0, stream>>>(x, ff1_ln_g, ff1_ln_b, ybf);
  gemm_bt<1,128><<<dim3(3072/128, Mm/128), tb, 0, stream>>>(ybf, wt_ff1_1, ff1_b1, big, nullptr, nullptr, nullptr, Mm, 3072, 768, 0.f);
  gemm_bt<4,64><<<dim3(768/64, Mm/128), tb, 0, stream>>>(big, wt_ff1_2, ff1_b2, nullptr, xres, x, nullptr, Mm, 768, 3072, 0.5f);

  // --- attention (qkv GEMM writes V transposed into vtr via EPI5) ---
  ln_kernel<true><<<Mm, tb, 0, stream>>>(xres, attn_ln_g, attn_ln_b, ybf);
  gemm_bt<5,128><<<dim3(2304/128, Mm/128), tb, 0, stream>>>(ybf, wt_qkv, qkv_b, big, nullptr, nullptr, vtr, Mm, 2304, 768, 0.f);
  attn_kernel<<<dim3(Bb*Hh, Nn/128), dim3(512), 0, stream>>>(big, vtr, rel_tab, abuf);
  gemm_bt<2,64><<<dim3(768/64, Mm/128), tb, 0, stream>>>(abuf, wt_proj, proj_b, nullptr, xres, nullptr, nullptr, Mm, 768, 768, 1.0f);

  // --- conv module ---
  ln_kernel<true><<<Mm, tb, 0, stream>>>(xres, conv_ln_g, conv_ln_b, ybf);
  gemm_bt<3,128><<<dim3(1536/128, Mm/128), tb, 0, stream>>>(ybf, wt_pwin, bperm, abuf, nullptr, nullptr, nullptr, Mm, 1536, 768, 0.f);
  dwconv<<<((Mm/4)*96)/256, tb, 0, stream>>>(abuf, dwwT, dw_b, ybf);
  bn_part<<<64, dim3(192), 0, stream>>>(ybf, psum, psq);
  bn_final<<<3, tb, 0, stream>>>(psum, psq, bn_g, bn_b, bnscale, bnshift);
  bn_silu<<<(Mm*96)/256, tb, 0, stream>>>(ybf, bnscale, bnshift, abuf);
  gemm_bt<2,64><<<dim3(768/64, Mm/128), tb, 0, stream>>>(abuf, wt_pwout, pwout_b, nullptr, xres, nullptr, nullptr, Mm, 768, 768, 1.0f);

  // --- FFN2 ---
  ln_kernel<true><<<Mm, tb, 0, stream>>>(xres, ff2_ln_g, ff2_ln_b, ybf);
  gemm_bt<1,128><<<dim3(3072/128, Mm/128), tb, 0, stream>>>(ybf, wt_ff2_1, ff2_b1, big, nullptr, nullptr, nullptr, Mm, 3072, 768, 0.f);
  gemm_bt<2,64><<<dim3(768/64, Mm/128), tb, 0, stream>>>(big, wt_ff2_2, ff2_b2, nullptr, xres, nullptr, nullptr, Mm, 768, 3072, 0.5f);

  // --- final LN ---
  ln_kernel<false><<<Mm, tb, 0, stream>>>(xres, fin_ln_g, fin_ln_b, (void*)xres);
}

// Round 14
// 528.256 us; speedup vs baseline: 1.3529x; 1.0079x over previous
//
#include <hip/hip_runtime.h>
#include <math.h>

// Problem constants
#define Bb 8
#define Nn 1024
#define Dd 768
#define Hh 12
#define Mm 8192   // Bb*Nn

typedef __attribute__((ext_vector_type(4))) float f32x4;
typedef __attribute__((ext_vector_type(8))) __bf16 bf16x8;

__device__ __forceinline__ float bf2f(unsigned short u) {
  union { unsigned int i; float f; } v; v.i = ((unsigned int)u) << 16; return v.f;
}
__device__ __forceinline__ unsigned short f2bf(float f) {
  union { float f; unsigned int i; } v; v.f = f;
  unsigned int u = v.i;
  return (unsigned short)((u + 0x7FFFu + ((u >> 16) & 1u)) >> 16);
}
__device__ __forceinline__ unsigned int pack2bf(float a, float b) {
  union { __bf16 h[2]; unsigned int u; } x;
  x.h[0] = (__bf16)a; x.h[1] = (__bf16)b; return x.u;
}

__device__ __forceinline__ void gload16(const void* g, void* l) {
  __builtin_amdgcn_global_load_lds(
      (const __attribute__((address_space(1))) unsigned int*)g,
      (__attribute__((address_space(3))) unsigned int*)l, 16, 0, 0);
}

// Branch-free GELU (erf via Abramowitz-Stegun 7.1.26, |eps|<=1.5e-7)
__device__ __forceinline__ float gelu_f(float v) {
  const float z = fabsf(v) * 0.7071067811865475f;
  const float t = __builtin_amdgcn_rcpf(1.f + 0.3275911f * z);
  const float poly = t*(0.254829592f + t*(-0.284496736f + t*(1.421413741f +
                     t*(-1.453152027f + t*1.061405429f))));
  float er = 1.f - poly * __expf(-z * z);
  er = copysignf(er, v);
  return 0.5f * v * (1.f + er);
}

// ---------------- GEMM: C[M,N] = epi(A[M,K] * Bt[N,K]^T + bias) ----------------
// BK=64 K-step, 2-phase. LDS rows 128B pitch, T2 XOR-swizzle (rule-#21 pattern).
// NT = 128 or 64. XCD-chunked bijective swizzle (m204).
// EPI 0: store bf16; 1: GELU->bf16; 2: Resb += scale*v (bf16 residual RMW);
// EPI 3: GLU (N/2 bf16); EPI 4: Resb = Xin(fp32) + scale*v (bf16);
// EPI 5: qkv with fused V-transpose (V cols -> Vtr)
template<int EPI, int NT>
__global__ __launch_bounds__(256)
void gemm_bt(const unsigned short* __restrict__ A,
             const unsigned short* __restrict__ Bt,
             const float* __restrict__ bias,
             unsigned short* __restrict__ Cbf,
             unsigned short* __restrict__ Resb,
             const float* __restrict__ Xin,
             unsigned short* __restrict__ Vtr,
             int M, int N, int K, float scale)
{
  __shared__ __align__(16) unsigned short Asm[128*64];
  __shared__ __align__(16) unsigned short Bsm[NT*64];
  const int tid = threadIdx.x;
  const int wv = tid >> 6, lane = tid & 63;
  const int lr = lane & 15, lg = lane >> 4;
  const int wr = wv >> 1, wc = wv & 1;
  constexpr int JN = NT / 32;       // col-groups of 16 per wave

  // ---- bijective XCD-chunked swizzle ----
  const int gx = gridDim.x, gy = gridDim.y;
  const int nwg = gx * gy;
  const int lin = blockIdx.y * gx + blockIdx.x;
  const int q8 = nwg >> 3, r8 = nwg & 7;
  const int xcd = lin & 7, lidx = lin >> 3;
  const int wg = ((xcd < r8) ? xcd * (q8 + 1) : r8 * (q8 + 1) + (xcd - r8) * q8) + lidx;
  const int bx = wg % gx;
  const int by = wg / gx;

  const int n0 = bx * NT, m0 = by * 128;

  f32x4 acc[4][JN] = {};

  const int srow8 = lane >> 3;                    // row within 8-row group
  const int scol  = ((lane & 7) ^ srow8) * 8;     // pre-swizzled source col (elems)
  const unsigned short* Agp = A + (size_t)(m0 + wv*32 + srow8)*K + scol;
  const unsigned short* Bgp = (NT == 128)
      ? Bt + (size_t)(n0 + wv*32 + srow8)*K + scol
      : Bt + (size_t)(n0 + wv*16 + srow8)*K + scol;
  const int swr = (lr & 7) << 4;                  // read-side XOR (bytes)

  for (int kt = 0; kt < K; kt += 64) {
#pragma unroll
    for (int k = 0; k < 4; k++)
      gload16(Agp + (size_t)(k*8)*K + kt, Asm + (wv*32 + k*8)*64);
    if (NT == 128) {
#pragma unroll
      for (int k = 0; k < 4; k++)
        gload16(Bgp + (size_t)(k*8)*K + kt, Bsm + (wv*32 + k*8)*64);
    } else {
#pragma unroll
      for (int k = 0; k < 2; k++)
        gload16(Bgp + (size_t)(k*8)*K + kt, Bsm + (wv*16 + k*8)*64);
    }
    __syncthreads();   // drains vmcnt -> LDS tiles ready
    bf16x8 af[4], af2[4], bfr[JN], bfr2[JN];
#pragma unroll
    for (int i = 0; i < 4; i++) {
      const char* base = (const char*)Asm + (wr*64 + i*16 + lr)*128;
      af[i]  = *(const bf16x8*)(base + ((lg*16)      ^ swr));
      af2[i] = *(const bf16x8*)(base + ((lg*16 + 64) ^ swr));
    }
#pragma unroll
    for (int j = 0; j < JN; j++) {
      const char* base = (const char*)Bsm + (wc*(NT/2) + j*16 + lr)*128;
      bfr[j]  = *(const bf16x8*)(base + ((lg*16)      ^ swr));
      bfr2[j] = *(const bf16x8*)(base + ((lg*16 + 64) ^ swr));
    }
#pragma unroll
    for (int i = 0; i < 4; i++)
#pragma unroll
      for (int j = 0; j < JN; j++) {
        acc[i][j] = __builtin_amdgcn_mfma_f32_16x16x32_bf16(af[i],  bfr[j],  acc[i][j], 0, 0, 0);
        acc[i][j] = __builtin_amdgcn_mfma_f32_16x16x32_bf16(af2[i], bfr2[j], acc[i][j], 0, 0, 0);
      }
    __syncthreads();   // compute done before next stage overwrites
  }

#pragma unroll
  for (int i = 0; i < 4; i++) {
    const int rg = m0 + wr*64 + i*16 + lg*4;
    if (EPI == 3) {
      // GLU: col-groups alternate u (even) / gate (odd); write N/2 bf16 cols
#pragma unroll
      for (int j = 0; j < JN; j += 2) {
        const int cgu = n0 + wc*(NT/2) + j*16 + lr;
        const float bu = bias[cgu], bg = bias[cgu + 16];
        const int ocol = (n0 >> 1) + wc*(NT/4) + (j >> 1)*16 + lr;
#pragma unroll
        for (int e = 0; e < 4; e++) {
          float u  = acc[i][j][e]   + bu;
          float gt = acc[i][j+1][e] + bg;
          Cbf[(size_t)(rg + e) * (N >> 1) + ocol] = f2bf(u / (1.f + __expf(-gt)));
        }
      }
    } else if (EPI == 5 && n0 >= 1536) {
      // V columns: write transposed into Vtr[(b*Hh+h)*64 + d][n]
#pragma unroll
      for (int j = 0; j < JN; j++) {
        const int cg = n0 + wc*(NT/2) + j*16 + lr;
        const float bv = bias[cg];
        const int vo = cg - 1536;
        const int hh = vo >> 6, d = vo & 63;
        const int bb_ = rg >> 10, nn_ = rg & 1023;
        ushort4 o4;
        o4.x = f2bf(acc[i][j][0] + bv);
        o4.y = f2bf(acc[i][j][1] + bv);
        o4.z = f2bf(acc[i][j][2] + bv);
        o4.w = f2bf(acc[i][j][3] + bv);
        *(ushort4*)(Vtr + (((size_t)bb_*Hh + hh)*64 + d)*1024 + nn_) = o4;
      }
    } else {
#pragma unroll
      for (int j = 0; j < JN; j++) {
        const int cg = n0 + wc*(NT/2) + j*16 + lr;
        const float bv = bias[cg];
#pragma unroll
        for (int e = 0; e < 4; e++) {
          float v = acc[i][j][e] + bv;
          const size_t idx = (size_t)(rg + e) * N + cg;
          if (EPI == 1) {
            Cbf[idx] = f2bf(gelu_f(v));
          } else if (EPI == 0 || EPI == 5) {
            Cbf[idx] = f2bf(v);
          } else if (EPI == 2) {
            Resb[idx] = f2bf(bf2f(Resb[idx]) + scale * v);
          } else {  // EPI 4
            Resb[idx] = f2bf(Xin[idx] + scale * v);
          }
        }
      }
    }
  }
}

// ---------------- LayerNorm over D=768 ----------------
// IBF: input bf16 (residual stream) vs fp32; OBF: output bf16 vs fp32.
// 192 active threads x 4 elems, vectorized loads/stores.
template<bool IBF, bool OBF>
__global__ __launch_bounds__(256)
void ln_kernel(const void* __restrict__ xin, const float* __restrict__ g,
               const float* __restrict__ b, void* out)
{
  const int row = blockIdx.x, tid = threadIdx.x;
  const int c4 = tid * 4;
  const bool act = tid < 192;
  float v0 = 0.f, v1 = 0.f, v2 = 0.f, v3 = 0.f;
  if (act) {
    if (IBF) {
      ushort4 u = *(const ushort4*)((const unsigned short*)xin + (size_t)row*Dd + c4);
      v0 = bf2f(u.x); v1 = bf2f(u.y); v2 = bf2f(u.z); v3 = bf2f(u.w);
    } else {
      float4 f = *(const float4*)((const float*)xin + (size_t)row*Dd + c4);
      v0 = f.x; v1 = f.y; v2 = f.z; v3 = f.w;
    }
  }
  float s = v0+v1+v2+v3, q = v0*v0+v1*v1+v2*v2+v3*v3;
  for (int off = 32; off; off >>= 1) { s += __shfl_down(s, off); q += __shfl_down(q, off); }
  __shared__ float ps[4], pq[4];
  if ((tid & 63) == 0) { ps[tid>>6] = s; pq[tid>>6] = q; }
  __syncthreads();
  s = ps[0]+ps[1]+ps[2]+ps[3]; q = pq[0]+pq[1]+pq[2]+pq[3];
  const float mean = s * (1.f/768.f);
  const float rstd = rsqrtf(q*(1.f/768.f) - mean*mean + 1e-5f);
  if (act) {
    const float4 gg = *(const float4*)&g[c4];
    const float4 bb4 = *(const float4*)&b[c4];
    float y0 = (v0-mean)*rstd*gg.x + bb4.x;
    float y1 = (v1-mean)*rstd*gg.y + bb4.y;
    float y2 = (v2-mean)*rstd*gg.z + bb4.z;
    float y3 = (v3-mean)*rstd*gg.w + bb4.w;
    if (OBF) {
      ushort4 o4 = { f2bf(y0), f2bf(y1), f2bf(y2), f2bf(y3) };
      *(ushort4*)((unsigned short*)out + (size_t)row*Dd + c4) = o4;
    } else {
      float4 o4 = { y0, y1, y2, y3 };
      *(float4*)((float*)out + (size_t)row*Dd + c4) = o4;
    }
  }
}

// ---------------- unified weight prep (single dispatch) ----------------
__global__ __launch_bounds__(256)
void prep_all(const float* __restrict__ ff1_w1, const float* __restrict__ ff1_w2,
              const float* __restrict__ qkv_w,  const float* __restrict__ proj_w,
              const float* __restrict__ ff2_w1, const float* __restrict__ ff2_w2,
              const float* __restrict__ pwin_w, const float* __restrict__ pwin_b,
              const float* __restrict__ pwout_w, const float* __restrict__ dw_w,
              unsigned short* __restrict__ wt_ff1_1, unsigned short* __restrict__ wt_ff1_2,
              unsigned short* __restrict__ wt_qkv,   unsigned short* __restrict__ wt_proj,
              unsigned short* __restrict__ wt_ff2_1, unsigned short* __restrict__ wt_ff2_2,
              unsigned short* __restrict__ wt_pwin,  float* __restrict__ bperm,
              unsigned short* __restrict__ wt_pwout, float* __restrict__ dwwT)
{
  __shared__ float t[32][33];
  const int tid = threadIdx.x;
  int bid = blockIdx.x;

  const float* src = nullptr; unsigned short* dst = nullptr;
  int K = 0, N = 0, gx = 0;
  if (bid < 2304)        { src = ff1_w1; dst = wt_ff1_1; K = 768;  N = 3072; gx = 96; }
  else if ((bid -= 2304) < 2304) { src = ff1_w2; dst = wt_ff1_2; K = 3072; N = 768;  gx = 24; }
  else if ((bid -= 2304) < 1728) { src = qkv_w;  dst = wt_qkv;   K = 768;  N = 2304; gx = 72; }
  else if ((bid -= 1728) < 576)  { src = proj_w; dst = wt_proj;  K = 768;  N = 768;  gx = 24; }
  else if ((bid -= 576)  < 2304) { src = ff2_w1; dst = wt_ff2_1; K = 768;  N = 3072; gx = 96; }
  else if ((bid -= 2304) < 2304) { src = ff2_w2; dst = wt_ff2_2; K = 3072; N = 768;  gx = 24; }
  else if ((bid -= 2304) < 1536) {
    const int r = bid;
    const int blk = r >> 7, g = (r >> 4) & 7, tt = r & 15;
    const int orig = blk*64 + ((g >> 1) << 4) + tt + ((g & 1) ? 768 : 0);
    const float* s2 = pwin_w + (size_t)orig * 768;
    unsigned short* d2 = wt_pwin + (size_t)r * 768;
    d2[tid] = f2bf(s2[tid]); d2[tid+256] = f2bf(s2[tid+256]); d2[tid+512] = f2bf(s2[tid+512]);
    if (tid == 0) bperm[r] = pwin_b[orig];
    return;
  }
  else if ((bid -= 1536) < 1024) {
    for (int i = bid*256 + tid; i < 768*768; i += 1024*256)
      wt_pwout[i] = f2bf(pwout_w[i]);
    return;
  }
  else {
    const int id = (bid - 1024)*256 + tid;
    if (id < 9*768) {
      const int k = id / 768, d = id % 768;
      dwwT[id] = dw_w[d*9 + k];
    }
    return;
  }

  const int tx = tid & 31, ty = tid >> 5;    // (32, 8)
  const int n0 = (bid % gx) * 32, k0 = (bid / gx) * 32;
#pragma unroll
  for (int i = 0; i < 4; i++) t[ty + i*8][tx] = src[(size_t)(k0 + ty + i*8)*N + n0 + tx];
  __syncthreads();
#pragma unroll
  for (int i = 0; i < 4; i++)
    dst[(size_t)(n0 + ty + i*8)*K + k0 + tx] = f2bf(t[tx][ty + i*8]);
}

// ---------------- fused attention v4 (R8-proven): QBLK=128, 8 waves ----------------
// LDS = Kl 9216 + Vt 9344 + Pl 18432 + relh 8192 = 45184 B -> 3 blocks/CU x 8 waves;
// grid 768 = exactly 3/CU. Natural VGPR ~48 (no min-waves bound — see R9 spill).
__global__ __launch_bounds__(512)
void attn_kernel(const unsigned short* __restrict__ qkv,
                 const unsigned short* __restrict__ vtr,  // [bh][64][1024]
                 const float* __restrict__ rel,           // (2047, 12)
                 unsigned short* __restrict__ out)
{
  const int bh = blockIdx.x; const int b = bh / Hh, h = bh % Hh;
  const int q0 = blockIdx.y * 128;
  const int tid = threadIdx.x, wv = tid >> 6, lane = tid & 63;
  const int lr = lane & 15, lg = lane >> 4;

  __shared__ __align__(16) unsigned short Kl[64*72];        // [key][d], pitch 72
  __shared__ __align__(16) unsigned short Vt[64*72 + 64];   // [d][key], pitch 72 + stagger
  __shared__ __align__(16) unsigned short Pl[8*16*72];      // per-wave [q][key], pitch 72
  __shared__ float relh[2048];

  for (int i = tid; i < 2047; i += 512) relh[i] = rel[(size_t)i*Hh + h] * 1.44269504f;

  // Q fragments scaled by 0.125*log2e (exp2-domain softmax)
  const size_t qrow = (size_t)(b*Nn + q0 + wv*16 + lr);
  const bf16x8 qraw0 = *(const bf16x8*)(qkv + qrow*2304 + h*64 + lg*8);
  const bf16x8 qraw1 = *(const bf16x8*)(qkv + qrow*2304 + h*64 + 32 + lg*8);
  bf16x8 qf0, qf1;
#pragma unroll
  for (int e = 0; e < 8; e++) {
    qf0[e] = (__bf16)((float)qraw0[e] * 0.180336884f);
    qf1[e] = (__bf16)((float)qraw1[e] * 0.180336884f);
  }

  const int sd = tid >> 3;            // 0..63 (K: key row / V: d row)
  const int sc = (tid & 7) * 8;       // 8-elem chunk
  unsigned short* Pw = Pl + wv*16*72;

  // T14 async staging: one bf16x8 each for K and V per thread
  const unsigned short* kbase = qkv + (size_t)(b*Nn + sd)*2304 + 768 + h*64 + sc;
  const unsigned short* vbase = vtr + ((size_t)bh*64 + sd)*1024 + sc;
  bf16x8 kA = *(const bf16x8*)(kbase);
  bf16x8 vA = *(const bf16x8*)(vbase);

  f32x4 O[4] = {};
  float mrow = -1e30f, lsum = 0.f;    // log2 domain
  const int qq = q0 + wv*16 + lr;

  __syncthreads();  // relh ready

  for (int kt = 0; kt < Nn; kt += 64) {
    { // publish staged regs to LDS
      *(bf16x8*)&Kl[sd*72 + sc] = kA;
      *(bf16x8*)&Vt[sd*72 + (sd>>4)*16 + sc] = vA;
    }
    __syncthreads();

    // issue next tile's loads (latency hides under compute below)
    if (kt + 64 < Nn) {
      kA = *(const bf16x8*)(kbase + (size_t)(kt + 64)*2304);
      vA = *(const bf16x8*)(vbase + kt + 64);
    }

    // QK^T swapped, bias as MFMA C-init: S[key][q=lr]
    const int bidx = kt - qq + (Nn - 1);
    f32x4 s[4];
#pragma unroll
    for (int kb = 0; kb < 4; kb++)
#pragma unroll
      for (int j = 0; j < 4; j++)
        s[kb][j] = relh[bidx + kb*16 + lg*4 + j];
#pragma unroll
    for (int kb = 0; kb < 4; kb++) {
      bf16x8 kfa = *(const bf16x8*)&Kl[(kb*16 + lr)*72 + lg*8];
      bf16x8 kfb = *(const bf16x8*)&Kl[(kb*16 + lr)*72 + 32 + lg*8];
      s[kb] = __builtin_amdgcn_mfma_f32_16x16x32_bf16(kfa, qf0, s[kb], 0, 0, 0);
      s[kb] = __builtin_amdgcn_mfma_f32_16x16x32_bf16(kfb, qf1, s[kb], 0, 0, 0);
    }

    float r = -1e30f;
#pragma unroll
    for (int kb = 0; kb < 4; kb++)
#pragma unroll
      for (int j = 0; j < 4; j++) r = fmaxf(r, s[kb][j]);
    r = fmaxf(r, __shfl_xor(r, 16)); r = fmaxf(r, __shfl_xor(r, 32));

    // defer-max (T13), log2 domain
    if (!__all(r <= mrow + 11.5f)) {
      const float mn = fmaxf(mrow, r);
      const float al = __builtin_amdgcn_exp2f(mrow - mn);
      mrow = mn;
      lsum *= al;
#pragma unroll
      for (int ni = 0; ni < 4; ni++) {
        O[ni][0]*=al; O[ni][1]*=al; O[ni][2]*=al; O[ni][3]*=al;
      }
    }

    float rs = 0.f;
    unsigned int pk[8];
#pragma unroll
    for (int kb = 0; kb < 4; kb++) {
      float p0 = __builtin_amdgcn_exp2f(s[kb][0]-mrow), p1 = __builtin_amdgcn_exp2f(s[kb][1]-mrow);
      float p2 = __builtin_amdgcn_exp2f(s[kb][2]-mrow), p3 = __builtin_amdgcn_exp2f(s[kb][3]-mrow);
      rs += (p0+p1) + (p2+p3);
      pk[kb*2]   = pack2bf(p0, p1);
      pk[kb*2+1] = pack2bf(p2, p3);
    }
    rs += __shfl_xor(rs, 16); rs += __shfl_xor(rs, 32);
    lsum += rs;

#pragma unroll
    for (int kb0 = 0; kb0 < 4; kb0++) {
      const int kb = (kb0 + lg) & 3;
      *(unsigned int*)&Pw[lr*72 + kb*16 + lg*4]     = pk[kb*2];
      *(unsigned int*)&Pw[lr*72 + kb*16 + lg*4 + 2] = pk[kb*2+1];
    }

    // PV: O[d][q] += V^T . P^T (wave-private P; in-order LDS pipe)
    bf16x8 pf0 = *(const bf16x8*)&Pw[lr*72 + lg*8];
    bf16x8 pf1 = *(const bf16x8*)&Pw[lr*72 + 32 + lg*8];
#pragma unroll
    for (int dt = 0; dt < 4; dt++) {
      bf16x8 vf0 = *(const bf16x8*)&Vt[(dt*16 + lr)*72 + dt*16 + lg*8];
      bf16x8 vf1 = *(const bf16x8*)&Vt[(dt*16 + lr)*72 + dt*16 + 32 + lg*8];
      O[dt] = __builtin_amdgcn_mfma_f32_16x16x32_bf16(vf0, pf0, O[dt], 0, 0, 0);
      O[dt] = __builtin_amdgcn_mfma_f32_16x16x32_bf16(vf1, pf1, O[dt], 0, 0, 0);
    }
    __syncthreads();
  }

  const float rl = 1.f / lsum;
#pragma unroll
  for (int dt = 0; dt < 4; dt++) {
    ushort4 o4;
    o4.x = f2bf(O[dt][0]*rl); o4.y = f2bf(O[dt][1]*rl);
    o4.z = f2bf(O[dt][2]*rl); o4.w = f2bf(O[dt][3]*rl);
    *(ushort4*)(out + (size_t)(b*Nn + qq)*Dd + h*64 + dt*16 + lg*4) = o4;
  }
}

// ---------------- conv path ----------------
// dwconv v2: each thread computes 4 consecutive n for 8 channels.
__global__ __launch_bounds__(256)
void dwconv(const unsigned short* __restrict__ glu, const float* __restrict__ dwwT,
            const float* __restrict__ dwb, unsigned short* __restrict__ z)
{
  const int id = blockIdx.x*256 + threadIdx.x;
  if (id >= (Mm/4)*96) return;
  const int t = id / 96, c8 = (id % 96) * 8;
  const int b = t / (Nn/4), n0 = (t % (Nn/4)) * 4;

  bf16x8 zero;
#pragma unroll
  for (int e = 0; e < 8; e++) zero[e] = (__bf16)0.f;

  bf16x8 g[12];
#pragma unroll
  for (int rr = 0; rr < 12; rr++) {
    const int nn = n0 + rr - 4;
    g[rr] = (nn >= 0 && nn < Nn)
        ? *(const bf16x8*)&glu[(size_t)(b*Nn + nn)*768 + c8] : zero;
  }

  float acc[4][8];
#pragma unroll
  for (int j = 0; j < 4; j++)
#pragma unroll
    for (int e = 0; e < 8; e++) acc[j][e] = dwb[c8 + e];

#pragma unroll
  for (int k = 0; k < 9; k++) {
    const float4 w0 = *(const float4*)&dwwT[k*768 + c8];
    const float4 w1 = *(const float4*)&dwwT[k*768 + c8 + 4];
    const float w[8] = {w0.x, w0.y, w0.z, w0.w, w1.x, w1.y, w1.z, w1.w};
#pragma unroll
    for (int j = 0; j < 4; j++)
#pragma unroll
      for (int e = 0; e < 8; e++)
        acc[j][e] += w[e] * (float)g[j + k][e];
  }

#pragma unroll
  for (int j = 0; j < 4; j++) {
    bf16x8 o;
#pragma unroll
    for (int e = 0; e < 8; e++) o[e] = (__bf16)acc[j][e];
    *(bf16x8*)&z[(size_t)(b*Nn + n0 + j)*768 + c8] = o;
  }
}

// bn_part: 256 blocks x 32 rows (was 64x128 at 0.25 blocks/CU -> latency bound)
__global__ __launch_bounds__(192)
void bn_part(const unsigned short* __restrict__ z, float* __restrict__ psum,
             float* __restrict__ psq)
{
  const int blk = blockIdx.x, t = threadIdx.x;   // 256 blocks x 192 threads, 4 ch each
  const int c4 = t * 4;
  float s0=0,s1=0,s2=0,s3=0, q0=0,q1=0,q2=0,q3=0;
  for (int r = 0; r < 32; r++) {
    ushort4 v4 = *(const ushort4*)&z[(size_t)(blk*32 + r)*Dd + c4];
    float a = bf2f(v4.x), b_ = bf2f(v4.y), c = bf2f(v4.z), d = bf2f(v4.w);
    s0 += a; s1 += b_; s2 += c; s3 += d;
    q0 += a*a; q1 += b_*b_; q2 += c*c; q3 += d*d;
  }
  float4 sv = {s0, s1, s2, s3}, qv = {q0, q1, q2, q3};
  *(float4*)&psum[(size_t)blk*Dd + c4] = sv;
  *(float4*)&psq [(size_t)blk*Dd + c4] = qv;
}

__global__ __launch_bounds__(256)
void bn_final(const float* __restrict__ psum, const float* __restrict__ psq,
              const float* __restrict__ g, const float* __restrict__ bb,
              float* __restrict__ scale, float* __restrict__ shift)
{
  const int c = blockIdx.x*256 + threadIdx.x;
  if (c >= Dd) return;
  float s = 0.f, q = 0.f;
  for (int i = 0; i < 256; i++) { s += psum[(size_t)i*Dd + c]; q += psq[(size_t)i*Dd + c]; }
  const float mean = s / (float)Mm;
  const float var  = q / (float)Mm - mean*mean;
  const float sc = g[c] * rsqrtf(var + 1e-5f);
  scale[c] = sc; shift[c] = bb[c] - mean*sc;
}

__global__ __launch_bounds__(256)
void bn_silu(const unsigned short* __restrict__ z, const float* __restrict__ scale,
             const float* __restrict__ shift, unsigned short* __restrict__ out)
{
  const int id = blockIdx.x*256 + threadIdx.x;
  if (id >= Mm*96) return;
  const int row = id / 96, c8 = (id % 96) * 8;
  bf16x8 v = *(const bf16x8*)&z[(size_t)row*Dd + c8];
  bf16x8 o;
#pragma unroll
  for (int e = 0; e < 8; e++) {
    float t = (float)v[e] * scale[c8+e] + shift[c8+e];
    o[e] = (__bf16)(t / (1.f + __expf(-t)));
  }
  *(bf16x8*)&out[(size_t)row*Dd + c8] = o;
}

// ---------------- host ----------------
extern "C" void kernel_launch(void* const* d_in, const int* in_sizes, int n_in,
                              void* d_out, int out_size, void* d_ws, size_t ws_size,
                              hipStream_t stream)
{
  const float* x        = (const float*)d_in[0];
  const float* ff1_ln_g = (const float*)d_in[1];
  const float* ff1_ln_b = (const float*)d_in[2];
  const float* ff1_w1   = (const float*)d_in[3];
  const float* ff1_b1   = (const float*)d_in[4];
  const float* ff1_w2   = (const float*)d_in[5];
  const float* ff1_b2   = (const float*)d_in[6];
  const float* attn_ln_g= (const float*)d_in[7];
  const float* attn_ln_b= (const float*)d_in[8];
  const float* qkv_w    = (const float*)d_in[9];
  const float* qkv_b    = (const float*)d_in[10];
  const float* proj_w   = (const float*)d_in[11];
  const float* proj_b   = (const float*)d_in[12];
  const float* rel_tab  = (const float*)d_in[13];
  const float* conv_ln_g= (const float*)d_in[14];
  const float* conv_ln_b= (const float*)d_in[15];
  const float* pwin_w   = (const float*)d_in[16];
  const float* pwin_b   = (const float*)d_in[17];
  const float* dw_w     = (const float*)d_in[18];
  const float* dw_b     = (const float*)d_in[19];
  const float* bn_g     = (const float*)d_in[20];
  const float* bn_b     = (const float*)d_in[21];
  const float* pwout_w  = (const float*)d_in[22];
  const float* pwout_b  = (const float*)d_in[23];
  const float* ff2_ln_g = (const float*)d_in[24];
  const float* ff2_ln_b = (const float*)d_in[25];
  const float* ff2_w1   = (const float*)d_in[26];
  const float* ff2_b1   = (const float*)d_in[27];
  const float* ff2_w2   = (const float*)d_in[28];
  const float* ff2_b2   = (const float*)d_in[29];
  const float* fin_ln_g = (const float*)d_in[30];
  const float* fin_ln_b = (const float*)d_in[31];

  char* ws = (char*)d_ws;
  size_t off = 0;
  auto alloc = [&](size_t bytes) { char* p = ws + off; off += (bytes + 255) & ~(size_t)255; return p; };
  unsigned short* wt_ff1_1 = (unsigned short*)alloc((size_t)3072*768*2);
  unsigned short* wt_ff1_2 = (unsigned short*)alloc((size_t)768*3072*2);
  unsigned short* wt_qkv   = (unsigned short*)alloc((size_t)2304*768*2);
  unsigned short* wt_proj  = (unsigned short*)alloc((size_t)768*768*2);
  unsigned short* wt_pwin  = (unsigned short*)alloc((size_t)1536*768*2);
  unsigned short* wt_pwout = (unsigned short*)alloc((size_t)768*768*2);
  unsigned short* wt_ff2_1 = (unsigned short*)alloc((size_t)3072*768*2);
  unsigned short* wt_ff2_2 = (unsigned short*)alloc((size_t)768*3072*2);
  unsigned short* ybf      = (unsigned short*)alloc((size_t)Mm*768*2);
  unsigned short* big      = (unsigned short*)alloc((size_t)Mm*3072*2);
  unsigned short* abuf     = (unsigned short*)alloc((size_t)Mm*768*2);
  unsigned short* xbf      = (unsigned short*)alloc((size_t)Mm*768*2);   // bf16 residual
  float* psum    = (float*)alloc((size_t)256*768*4);
  float* psq     = (float*)alloc((size_t)256*768*4);
  float* bnscale = (float*)alloc((size_t)768*4);
  float* bnshift = (float*)alloc((size_t)768*4);
  float* dwwT    = (float*)alloc((size_t)9*768*4);
  float* bperm   = (float*)alloc((size_t)1536*4);
  if (off > ws_size) return;

  // vtr lives in big's unused tail (qkv rows use pitch 2304 of the 3072 alloc)
  unsigned short* vtr = big + (size_t)Mm*2304;

  const dim3 tb(256);

  // --- unified weight prep (1 dispatch) ---
  prep_all<<<14107, tb, 0, stream>>>(ff1_w1, ff1_w2, qkv_w, proj_w, ff2_w1, ff2_w2,
                                     pwin_w, pwin_b, pwout_w, dw_w,
                                     wt_ff1_1, wt_ff1_2, wt_qkv, wt_proj,
                                     wt_ff2_1, wt_ff2_2, wt_pwin, bperm,
                                     wt_pwout, dwwT);

  // --- FFN1: xbf = bf16(x + 0.5*FFN(LN(x))) ---
  ln_kernel<false,true><<<Mm, tb, 0, stream>>>(x, ff1_ln_g, ff1_ln_b, ybf);
  gemm_bt<1,128><<<dim3(3072/128, Mm/128), tb, 0, stream>>>(ybf, wt_ff1_1, ff1_b1, big, nullptr, nullptr, nullptr, Mm, 3072, 768, 0.f);
  gemm_bt<4,64><<<dim3(768/64, Mm/128), tb, 0, stream>>>(big, wt_ff1_2, ff1_b2, nullptr, xbf, x, nullptr, Mm, 768, 3072, 0.5f);

  // --- attention (qkv GEMM writes V transposed into vtr via EPI5) ---
  ln_kernel<true,true><<<Mm, tb, 0, stream>>>(xbf, attn_ln_g, attn_ln_b, ybf);
  gemm_bt<5,128><<<dim3(2304/128, Mm/128), tb, 0, stream>>>(ybf, wt_qkv, qkv_b, big, nullptr, nullptr, vtr, Mm, 2304, 768, 0.f);
  attn_kernel<<<dim3(Bb*Hh, Nn/128), dim3(512), 0, stream>>>(big, vtr, rel_tab, abuf);
  gemm_bt<2,64><<<dim3(768/64, Mm/128), tb, 0, stream>>>(abuf, wt_proj, proj_b, nullptr, xbf, nullptr, nullptr, Mm, 768, 768, 1.0f);

  // --- conv module ---
  ln_kernel<true,true><<<Mm, tb, 0, stream>>>(xbf, conv_ln_g, conv_ln_b, ybf);
  gemm_bt<3,128><<<dim3(1536/128, Mm/128), tb, 0, stream>>>(ybf, wt_pwin, bperm, abuf, nullptr, nullptr, nullptr, Mm, 1536, 768, 0.f);
  dwconv<<<((Mm/4)*96)/256, tb, 0, stream>>>(abuf, dwwT, dw_b, ybf);
  bn_part<<<256, dim3(192), 0, stream>>>(ybf, psum, psq);
  bn_final<<<3, tb, 0, stream>>>(psum, psq, bn_g, bn_b, bnscale, bnshift);
  bn_silu<<<(Mm*96)/256, tb, 0, stream>>>(ybf, bnscale, bnshift, abuf);
  gemm_bt<2,64><<<dim3(768/64, Mm/128), tb, 0, stream>>>(abuf, wt_pwout, pwout_b, nullptr, xbf, nullptr, nullptr, Mm, 768, 768, 1.0f);

  // --- FFN2 ---
  ln_kernel<true,true><<<Mm, tb, 0, stream>>>(xbf, ff2_ln_g, ff2_ln_b, ybf);
  gemm_bt<1,128><<<dim3(3072/128, Mm/128), tb, 0, stream>>>(ybf, wt_ff2_1, ff2_b1, big, nullptr, nullptr, nullptr, Mm, 3072, 768, 0.f);
  gemm_bt<2,64><<<dim3(768/64, Mm/128), tb, 0, stream>>>(big, wt_ff2_2, ff2_b2, nullptr, xbf, nullptr, nullptr, Mm, 768, 3072, 0.5f);

  // --- final LN: reads bf16 residual, writes fp32 d_out ---
  ln_kernel<true,false><<<Mm, tb, 0, stream>>>(xbf, fin_ln_g, fin_ln_b, d_out);
}

// Round 15
// 516.047 us; speedup vs baseline: 1.3849x; 1.0237x over previous
//
#include <hip/hip_runtime.h>
#include <math.h>

// Problem constants
#define Bb 8
#define Nn 1024
#define Dd 768
#define Hh 12
#define Mm 8192   // Bb*Nn

typedef __attribute__((ext_vector_type(4))) float f32x4;
typedef __attribute__((ext_vector_type(8))) __bf16 bf16x8;

__device__ __forceinline__ float bf2f(unsigned short u) {
  union { unsigned int i; float f; } v; v.i = ((unsigned int)u) << 16; return v.f;
}
__device__ __forceinline__ unsigned short f2bf(float f) {
  union { float f; unsigned int i; } v; v.f = f;
  unsigned int u = v.i;
  return (unsigned short)((u + 0x7FFFu + ((u >> 16) & 1u)) >> 16);
}
__device__ __forceinline__ unsigned int pack2bf(float a, float b) {
  union { __bf16 h[2]; unsigned int u; } x;
  x.h[0] = (__bf16)a; x.h[1] = (__bf16)b; return x.u;
}

__device__ __forceinline__ void gload16(const void* g, void* l) {
  __builtin_amdgcn_global_load_lds(
      (const __attribute__((address_space(1))) unsigned int*)g,
      (__attribute__((address_space(3))) unsigned int*)l, 16, 0, 0);
}

// Branch-free GELU (erf via Abramowitz-Stegun 7.1.26, |eps|<=1.5e-7)
__device__ __forceinline__ float gelu_f(float v) {
  const float z = fabsf(v) * 0.7071067811865475f;
  const float t = __builtin_amdgcn_rcpf(1.f + 0.3275911f * z);
  const float poly = t*(0.254829592f + t*(-0.284496736f + t*(1.421413741f +
                     t*(-1.453152027f + t*1.061405429f))));
  float er = 1.f - poly * __expf(-z * z);
  er = copysignf(er, v);
  return 0.5f * v * (1.f + er);
}

// ---------------- GEMM: C[M,N] = epi(A[M,K] * Bt[N,K]^T + bias) ----------------
// BK=64 K-step, 2-phase. LDS rows 128B pitch, T2 XOR-swizzle (rule-#21 pattern).
// NT = 128 or 64. XCD-chunked bijective swizzle (m204).
// EPI 0: store bf16; 1: GELU->bf16; 2: Resb += scale*v (bf16 residual RMW);
// EPI 3: GLU (N/2 bf16); EPI 4: Resb = Xin(fp32) + scale*v (bf16);
// EPI 5: qkv with fused V-transpose (V cols -> Vtr)
template<int EPI, int NT>
__global__ __launch_bounds__(256)
void gemm_bt(const unsigned short* __restrict__ A,
             const unsigned short* __restrict__ Bt,
             const float* __restrict__ bias,
             unsigned short* __restrict__ Cbf,
             unsigned short* __restrict__ Resb,
             const float* __restrict__ Xin,
             unsigned short* __restrict__ Vtr,
             int M, int N, int K, float scale)
{
  __shared__ __align__(16) unsigned short Asm[128*64];
  __shared__ __align__(16) unsigned short Bsm[NT*64];
  const int tid = threadIdx.x;
  const int wv = tid >> 6, lane = tid & 63;
  const int lr = lane & 15, lg = lane >> 4;
  const int wr = wv >> 1, wc = wv & 1;
  constexpr int JN = NT / 32;       // col-groups of 16 per wave

  // ---- bijective XCD-chunked swizzle ----
  const int gx = gridDim.x, gy = gridDim.y;
  const int nwg = gx * gy;
  const int lin = blockIdx.y * gx + blockIdx.x;
  const int q8 = nwg >> 3, r8 = nwg & 7;
  const int xcd = lin & 7, lidx = lin >> 3;
  const int wg = ((xcd < r8) ? xcd * (q8 + 1) : r8 * (q8 + 1) + (xcd - r8) * q8) + lidx;
  const int bx = wg % gx;
  const int by = wg / gx;

  const int n0 = bx * NT, m0 = by * 128;

  f32x4 acc[4][JN] = {};

  const int srow8 = lane >> 3;                    // row within 8-row group
  const int scol  = ((lane & 7) ^ srow8) * 8;     // pre-swizzled source col (elems)
  const unsigned short* Agp = A + (size_t)(m0 + wv*32 + srow8)*K + scol;
  const unsigned short* Bgp = (NT == 128)
      ? Bt + (size_t)(n0 + wv*32 + srow8)*K + scol
      : Bt + (size_t)(n0 + wv*16 + srow8)*K + scol;
  const int swr = (lr & 7) << 4;                  // read-side XOR (bytes)

  for (int kt = 0; kt < K; kt += 64) {
#pragma unroll
    for (int k = 0; k < 4; k++)
      gload16(Agp + (size_t)(k*8)*K + kt, Asm + (wv*32 + k*8)*64);
    if (NT == 128) {
#pragma unroll
      for (int k = 0; k < 4; k++)
        gload16(Bgp + (size_t)(k*8)*K + kt, Bsm + (wv*32 + k*8)*64);
    } else {
#pragma unroll
      for (int k = 0; k < 2; k++)
        gload16(Bgp + (size_t)(k*8)*K + kt, Bsm + (wv*16 + k*8)*64);
    }
    __syncthreads();   // drains vmcnt -> LDS tiles ready
    bf16x8 af[4], af2[4], bfr[JN], bfr2[JN];
#pragma unroll
    for (int i = 0; i < 4; i++) {
      const char* base = (const char*)Asm + (wr*64 + i*16 + lr)*128;
      af[i]  = *(const bf16x8*)(base + ((lg*16)      ^ swr));
      af2[i] = *(const bf16x8*)(base + ((lg*16 + 64) ^ swr));
    }
#pragma unroll
    for (int j = 0; j < JN; j++) {
      const char* base = (const char*)Bsm + (wc*(NT/2) + j*16 + lr)*128;
      bfr[j]  = *(const bf16x8*)(base + ((lg*16)      ^ swr));
      bfr2[j] = *(const bf16x8*)(base + ((lg*16 + 64) ^ swr));
    }
#pragma unroll
    for (int i = 0; i < 4; i++)
#pragma unroll
      for (int j = 0; j < JN; j++) {
        acc[i][j] = __builtin_amdgcn_mfma_f32_16x16x32_bf16(af[i],  bfr[j],  acc[i][j], 0, 0, 0);
        acc[i][j] = __builtin_amdgcn_mfma_f32_16x16x32_bf16(af2[i], bfr2[j], acc[i][j], 0, 0, 0);
      }
    __syncthreads();   // compute done before next stage overwrites
  }

#pragma unroll
  for (int i = 0; i < 4; i++) {
    const int rg = m0 + wr*64 + i*16 + lg*4;
    if (EPI == 3) {
      // GLU: col-groups alternate u (even) / gate (odd); write N/2 bf16 cols
#pragma unroll
      for (int j = 0; j < JN; j += 2) {
        const int cgu = n0 + wc*(NT/2) + j*16 + lr;
        const float bu = bias[cgu], bg = bias[cgu + 16];
        const int ocol = (n0 >> 1) + wc*(NT/4) + (j >> 1)*16 + lr;
#pragma unroll
        for (int e = 0; e < 4; e++) {
          float u  = acc[i][j][e]   + bu;
          float gt = acc[i][j+1][e] + bg;
          Cbf[(size_t)(rg + e) * (N >> 1) + ocol] = f2bf(u / (1.f + __expf(-gt)));
        }
      }
    } else if (EPI == 5 && n0 >= 1536) {
      // V columns: write transposed into Vtr[(b*Hh+h)*64 + d][n]
#pragma unroll
      for (int j = 0; j < JN; j++) {
        const int cg = n0 + wc*(NT/2) + j*16 + lr;
        const float bv = bias[cg];
        const int vo = cg - 1536;
        const int hh = vo >> 6, d = vo & 63;
        const int bb_ = rg >> 10, nn_ = rg & 1023;
        ushort4 o4;
        o4.x = f2bf(acc[i][j][0] + bv);
        o4.y = f2bf(acc[i][j][1] + bv);
        o4.z = f2bf(acc[i][j][2] + bv);
        o4.w = f2bf(acc[i][j][3] + bv);
        *(ushort4*)(Vtr + (((size_t)bb_*Hh + hh)*64 + d)*1024 + nn_) = o4;
      }
    } else {
#pragma unroll
      for (int j = 0; j < JN; j++) {
        const int cg = n0 + wc*(NT/2) + j*16 + lr;
        const float bv = bias[cg];
#pragma unroll
        for (int e = 0; e < 4; e++) {
          float v = acc[i][j][e] + bv;
          const size_t idx = (size_t)(rg + e) * N + cg;
          if (EPI == 1) {
            Cbf[idx] = f2bf(gelu_f(v));
          } else if (EPI == 0 || EPI == 5) {
            Cbf[idx] = f2bf(v);
          } else if (EPI == 2) {
            Resb[idx] = f2bf(bf2f(Resb[idx]) + scale * v);
          } else {  // EPI 4
            Resb[idx] = f2bf(Xin[idx] + scale * v);
          }
        }
      }
    }
  }
}

// ---------------- LayerNorm: wave-per-row, barrier-free ----------------
// 12 elems/lane x 64 lanes; stats via 6-step shfl_xor; 4 rows/block, grid Mm/4.
template<bool IBF, bool OBF>
__global__ __launch_bounds__(256)
void ln_kernel(const void* __restrict__ xin, const float* __restrict__ g,
               const float* __restrict__ b, void* __restrict__ out)
{
  const int lane = threadIdx.x & 63;
  const int row = blockIdx.x * 4 + (threadIdx.x >> 6);
  const int c = lane * 4;
  float v[12];
  if (IBF) {
    const unsigned short* xr = (const unsigned short*)xin + (size_t)row * Dd;
#pragma unroll
    for (int p = 0; p < 3; p++) {
      ushort4 u = *(const ushort4*)&xr[c + p*256];
      v[p*4+0] = bf2f(u.x); v[p*4+1] = bf2f(u.y);
      v[p*4+2] = bf2f(u.z); v[p*4+3] = bf2f(u.w);
    }
  } else {
    const float* xr = (const float*)xin + (size_t)row * Dd;
#pragma unroll
    for (int p = 0; p < 3; p++) {
      float4 f = *(const float4*)&xr[c + p*256];
      v[p*4+0] = f.x; v[p*4+1] = f.y; v[p*4+2] = f.z; v[p*4+3] = f.w;
    }
  }
  float s = 0.f, q = 0.f;
#pragma unroll
  for (int i = 0; i < 12; i++) { s += v[i]; q += v[i]*v[i]; }
#pragma unroll
  for (int off = 32; off; off >>= 1) { s += __shfl_xor(s, off); q += __shfl_xor(q, off); }
  const float mean = s * (1.f/768.f);
  const float rstd = rsqrtf(q*(1.f/768.f) - mean*mean + 1e-5f);
#pragma unroll
  for (int p = 0; p < 3; p++) {
    const float4 gg  = *(const float4*)&g[c + p*256];
    const float4 bb4 = *(const float4*)&b[c + p*256];
    const float y0 = (v[p*4+0]-mean)*rstd*gg.x + bb4.x;
    const float y1 = (v[p*4+1]-mean)*rstd*gg.y + bb4.y;
    const float y2 = (v[p*4+2]-mean)*rstd*gg.z + bb4.z;
    const float y3 = (v[p*4+3]-mean)*rstd*gg.w + bb4.w;
    if (OBF) {
      ushort4 o4 = { f2bf(y0), f2bf(y1), f2bf(y2), f2bf(y3) };
      *(ushort4*)((unsigned short*)out + (size_t)row*Dd + c + p*256) = o4;
    } else {
      float4 o4 = { y0, y1, y2, y3 };
      *(float4*)((float*)out + (size_t)row*Dd + c + p*256) = o4;
    }
  }
}

// ---------------- unified weight prep (single dispatch) ----------------
__global__ __launch_bounds__(256)
void prep_all(const float* __restrict__ ff1_w1, const float* __restrict__ ff1_w2,
              const float* __restrict__ qkv_w,  const float* __restrict__ proj_w,
              const float* __restrict__ ff2_w1, const float* __restrict__ ff2_w2,
              const float* __restrict__ pwin_w, const float* __restrict__ pwin_b,
              const float* __restrict__ pwout_w, const float* __restrict__ dw_w,
              unsigned short* __restrict__ wt_ff1_1, unsigned short* __restrict__ wt_ff1_2,
              unsigned short* __restrict__ wt_qkv,   unsigned short* __restrict__ wt_proj,
              unsigned short* __restrict__ wt_ff2_1, unsigned short* __restrict__ wt_ff2_2,
              unsigned short* __restrict__ wt_pwin,  float* __restrict__ bperm,
              unsigned short* __restrict__ wt_pwout, float* __restrict__ dwwT)
{
  __shared__ float t[32][33];
  const int tid = threadIdx.x;
  int bid = blockIdx.x;

  const float* src = nullptr; unsigned short* dst = nullptr;
  int K = 0, N = 0, gx = 0;
  if (bid < 2304)        { src = ff1_w1; dst = wt_ff1_1; K = 768;  N = 3072; gx = 96; }
  else if ((bid -= 2304) < 2304) { src = ff1_w2; dst = wt_ff1_2; K = 3072; N = 768;  gx = 24; }
  else if ((bid -= 2304) < 1728) { src = qkv_w;  dst = wt_qkv;   K = 768;  N = 2304; gx = 72; }
  else if ((bid -= 1728) < 576)  { src = proj_w; dst = wt_proj;  K = 768;  N = 768;  gx = 24; }
  else if ((bid -= 576)  < 2304) { src = ff2_w1; dst = wt_ff2_1; K = 768;  N = 3072; gx = 96; }
  else if ((bid -= 2304) < 2304) { src = ff2_w2; dst = wt_ff2_2; K = 3072; N = 768;  gx = 24; }
  else if ((bid -= 2304) < 1536) {
    const int r = bid;
    const int blk = r >> 7, g = (r >> 4) & 7, tt = r & 15;
    const int orig = blk*64 + ((g >> 1) << 4) + tt + ((g & 1) ? 768 : 0);
    const float* s2 = pwin_w + (size_t)orig * 768;
    unsigned short* d2 = wt_pwin + (size_t)r * 768;
    d2[tid] = f2bf(s2[tid]); d2[tid+256] = f2bf(s2[tid+256]); d2[tid+512] = f2bf(s2[tid+512]);
    if (tid == 0) bperm[r] = pwin_b[orig];
    return;
  }
  else if ((bid -= 1536) < 1024) {
    for (int i = bid*256 + tid; i < 768*768; i += 1024*256)
      wt_pwout[i] = f2bf(pwout_w[i]);
    return;
  }
  else {
    const int id = (bid - 1024)*256 + tid;
    if (id < 9*768) {
      const int k = id / 768, d = id % 768;
      dwwT[id] = dw_w[d*9 + k];
    }
    return;
  }

  const int tx = tid & 31, ty = tid >> 5;    // (32, 8)
  const int n0 = (bid % gx) * 32, k0 = (bid / gx) * 32;
#pragma unroll
  for (int i = 0; i < 4; i++) t[ty + i*8][tx] = src[(size_t)(k0 + ty + i*8)*N + n0 + tx];
  __syncthreads();
#pragma unroll
  for (int i = 0; i < 4; i++)
    dst[(size_t)(n0 + ty + i*8)*K + k0 + tx] = f2bf(t[tx][ty + i*8]);
}

// ---------------- fused attention v4 (R8-proven): QBLK=128, 8 waves ----------------
// LDS = Kl 9216 + Vt 9344 + Pl 18432 + relh 8192 = 45184 B -> 3 blocks/CU x 8 waves;
// grid 768 = exactly 3/CU. Natural VGPR ~48 (no min-waves bound — see R9 spill).
__global__ __launch_bounds__(512)
void attn_kernel(const unsigned short* __restrict__ qkv,
                 const unsigned short* __restrict__ vtr,  // [bh][64][1024]
                 const float* __restrict__ rel,           // (2047, 12)
                 unsigned short* __restrict__ out)
{
  const int bh = blockIdx.x; const int b = bh / Hh, h = bh % Hh;
  const int q0 = blockIdx.y * 128;
  const int tid = threadIdx.x, wv = tid >> 6, lane = tid & 63;
  const int lr = lane & 15, lg = lane >> 4;

  __shared__ __align__(16) unsigned short Kl[64*72];        // [key][d], pitch 72
  __shared__ __align__(16) unsigned short Vt[64*72 + 64];   // [d][key], pitch 72 + stagger
  __shared__ __align__(16) unsigned short Pl[8*16*72];      // per-wave [q][key], pitch 72
  __shared__ float relh[2048];

  for (int i = tid; i < 2047; i += 512) relh[i] = rel[(size_t)i*Hh + h] * 1.44269504f;

  // Q fragments scaled by 0.125*log2e (exp2-domain softmax)
  const size_t qrow = (size_t)(b*Nn + q0 + wv*16 + lr);
  const bf16x8 qraw0 = *(const bf16x8*)(qkv + qrow*2304 + h*64 + lg*8);
  const bf16x8 qraw1 = *(const bf16x8*)(qkv + qrow*2304 + h*64 + 32 + lg*8);
  bf16x8 qf0, qf1;
#pragma unroll
  for (int e = 0; e < 8; e++) {
    qf0[e] = (__bf16)((float)qraw0[e] * 0.180336884f);
    qf1[e] = (__bf16)((float)qraw1[e] * 0.180336884f);
  }

  const int sd = tid >> 3;            // 0..63 (K: key row / V: d row)
  const int sc = (tid & 7) * 8;       // 8-elem chunk
  unsigned short* Pw = Pl + wv*16*72;

  // T14 async staging: one bf16x8 each for K and V per thread
  const unsigned short* kbase = qkv + (size_t)(b*Nn + sd)*2304 + 768 + h*64 + sc;
  const unsigned short* vbase = vtr + ((size_t)bh*64 + sd)*1024 + sc;
  bf16x8 kA = *(const bf16x8*)(kbase);
  bf16x8 vA = *(const bf16x8*)(vbase);

  f32x4 O[4] = {};
  float mrow = -1e30f, lsum = 0.f;    // log2 domain
  const int qq = q0 + wv*16 + lr;

  __syncthreads();  // relh ready

  for (int kt = 0; kt < Nn; kt += 64) {
    { // publish staged regs to LDS
      *(bf16x8*)&Kl[sd*72 + sc] = kA;
      *(bf16x8*)&Vt[sd*72 + (sd>>4)*16 + sc] = vA;
    }
    __syncthreads();

    // issue next tile's loads (latency hides under compute below)
    if (kt + 64 < Nn) {
      kA = *(const bf16x8*)(kbase + (size_t)(kt + 64)*2304);
      vA = *(const bf16x8*)(vbase + kt + 64);
    }

    // QK^T swapped, bias as MFMA C-init: S[key][q=lr]
    const int bidx = kt - qq + (Nn - 1);
    f32x4 s[4];
#pragma unroll
    for (int kb = 0; kb < 4; kb++)
#pragma unroll
      for (int j = 0; j < 4; j++)
        s[kb][j] = relh[bidx + kb*16 + lg*4 + j];
#pragma unroll
    for (int kb = 0; kb < 4; kb++) {
      bf16x8 kfa = *(const bf16x8*)&Kl[(kb*16 + lr)*72 + lg*8];
      bf16x8 kfb = *(const bf16x8*)&Kl[(kb*16 + lr)*72 + 32 + lg*8];
      s[kb] = __builtin_amdgcn_mfma_f32_16x16x32_bf16(kfa, qf0, s[kb], 0, 0, 0);
      s[kb] = __builtin_amdgcn_mfma_f32_16x16x32_bf16(kfb, qf1, s[kb], 0, 0, 0);
    }

    float r = -1e30f;
#pragma unroll
    for (int kb = 0; kb < 4; kb++)
#pragma unroll
      for (int j = 0; j < 4; j++) r = fmaxf(r, s[kb][j]);
    r = fmaxf(r, __shfl_xor(r, 16)); r = fmaxf(r, __shfl_xor(r, 32));

    // defer-max (T13), log2 domain
    if (!__all(r <= mrow + 11.5f)) {
      const float mn = fmaxf(mrow, r);
      const float al = __builtin_amdgcn_exp2f(mrow - mn);
      mrow = mn;
      lsum *= al;
#pragma unroll
      for (int ni = 0; ni < 4; ni++) {
        O[ni][0]*=al; O[ni][1]*=al; O[ni][2]*=al; O[ni][3]*=al;
      }
    }

    float rs = 0.f;
    unsigned int pk[8];
#pragma unroll
    for (int kb = 0; kb < 4; kb++) {
      float p0 = __builtin_amdgcn_exp2f(s[kb][0]-mrow), p1 = __builtin_amdgcn_exp2f(s[kb][1]-mrow);
      float p2 = __builtin_amdgcn_exp2f(s[kb][2]-mrow), p3 = __builtin_amdgcn_exp2f(s[kb][3]-mrow);
      rs += (p0+p1) + (p2+p3);
      pk[kb*2]   = pack2bf(p0, p1);
      pk[kb*2+1] = pack2bf(p2, p3);
    }
    rs += __shfl_xor(rs, 16); rs += __shfl_xor(rs, 32);
    lsum += rs;

#pragma unroll
    for (int kb0 = 0; kb0 < 4; kb0++) {
      const int kb = (kb0 + lg) & 3;
      *(unsigned int*)&Pw[lr*72 + kb*16 + lg*4]     = pk[kb*2];
      *(unsigned int*)&Pw[lr*72 + kb*16 + lg*4 + 2] = pk[kb*2+1];
    }

    // PV: O[d][q] += V^T . P^T (wave-private P; in-order LDS pipe)
    bf16x8 pf0 = *(const bf16x8*)&Pw[lr*72 + lg*8];
    bf16x8 pf1 = *(const bf16x8*)&Pw[lr*72 + 32 + lg*8];
#pragma unroll
    for (int dt = 0; dt < 4; dt++) {
      bf16x8 vf0 = *(const bf16x8*)&Vt[(dt*16 + lr)*72 + dt*16 + lg*8];
      bf16x8 vf1 = *(const bf16x8*)&Vt[(dt*16 + lr)*72 + dt*16 + 32 + lg*8];
      O[dt] = __builtin_amdgcn_mfma_f32_16x16x32_bf16(vf0, pf0, O[dt], 0, 0, 0);
      O[dt] = __builtin_amdgcn_mfma_f32_16x16x32_bf16(vf1, pf1, O[dt], 0, 0, 0);
    }
    __syncthreads();
  }

  const float rl = 1.f / lsum;
#pragma unroll
  for (int dt = 0; dt < 4; dt++) {
    ushort4 o4;
    o4.x = f2bf(O[dt][0]*rl); o4.y = f2bf(O[dt][1]*rl);
    o4.z = f2bf(O[dt][2]*rl); o4.w = f2bf(O[dt][3]*rl);
    *(ushort4*)(out + (size_t)(b*Nn + qq)*Dd + h*64 + dt*16 + lg*4) = o4;
  }
}

// ---------------- conv path ----------------
// dwconv v2: each thread computes 4 consecutive n for 8 channels.
__global__ __launch_bounds__(256)
void dwconv(const unsigned short* __restrict__ glu, const float* __restrict__ dwwT,
            const float* __restrict__ dwb, unsigned short* __restrict__ z)
{
  const int id = blockIdx.x*256 + threadIdx.x;
  if (id >= (Mm/4)*96) return;
  const int t = id / 96, c8 = (id % 96) * 8;
  const int b = t / (Nn/4), n0 = (t % (Nn/4)) * 4;

  bf16x8 zero;
#pragma unroll
  for (int e = 0; e < 8; e++) zero[e] = (__bf16)0.f;

  bf16x8 g[12];
#pragma unroll
  for (int rr = 0; rr < 12; rr++) {
    const int nn = n0 + rr - 4;
    g[rr] = (nn >= 0 && nn < Nn)
        ? *(const bf16x8*)&glu[(size_t)(b*Nn + nn)*768 + c8] : zero;
  }

  float acc[4][8];
#pragma unroll
  for (int j = 0; j < 4; j++)
#pragma unroll
    for (int e = 0; e < 8; e++) acc[j][e] = dwb[c8 + e];

#pragma unroll
  for (int k = 0; k < 9; k++) {
    const float4 w0 = *(const float4*)&dwwT[k*768 + c8];
    const float4 w1 = *(const float4*)&dwwT[k*768 + c8 + 4];
    const float w[8] = {w0.x, w0.y, w0.z, w0.w, w1.x, w1.y, w1.z, w1.w};
#pragma unroll
    for (int j = 0; j < 4; j++)
#pragma unroll
      for (int e = 0; e < 8; e++)
        acc[j][e] += w[e] * (float)g[j + k][e];
  }

#pragma unroll
  for (int j = 0; j < 4; j++) {
    bf16x8 o;
#pragma unroll
    for (int e = 0; e < 8; e++) o[e] = (__bf16)acc[j][e];
    *(bf16x8*)&z[(size_t)(b*Nn + n0 + j)*768 + c8] = o;
  }
}

// bn_part: 256 blocks x 32 rows
__global__ __launch_bounds__(192)
void bn_part(const unsigned short* __restrict__ z, float* __restrict__ psum,
             float* __restrict__ psq)
{
  const int blk = blockIdx.x, t = threadIdx.x;   // 256 blocks x 192 threads, 4 ch each
  const int c4 = t * 4;
  float s0=0,s1=0,s2=0,s3=0, q0=0,q1=0,q2=0,q3=0;
  for (int r = 0; r < 32; r++) {
    ushort4 v4 = *(const ushort4*)&z[(size_t)(blk*32 + r)*Dd + c4];
    float a = bf2f(v4.x), b_ = bf2f(v4.y), c = bf2f(v4.z), d = bf2f(v4.w);
    s0 += a; s1 += b_; s2 += c; s3 += d;
    q0 += a*a; q1 += b_*b_; q2 += c*c; q3 += d*d;
  }
  float4 sv = {s0, s1, s2, s3}, qv = {q0, q1, q2, q3};
  *(float4*)&psum[(size_t)blk*Dd + c4] = sv;
  *(float4*)&psq [(size_t)blk*Dd + c4] = qv;
}

__global__ __launch_bounds__(256)
void bn_final(const float* __restrict__ psum, const float* __restrict__ psq,
              const float* __restrict__ g, const float* __restrict__ bb,
              float* __restrict__ scale, float* __restrict__ shift)
{
  const int c = blockIdx.x*256 + threadIdx.x;
  if (c >= Dd) return;
  float s = 0.f, q = 0.f;
  for (int i = 0; i < 256; i++) { s += psum[(size_t)i*Dd + c]; q += psq[(size_t)i*Dd + c]; }
  const float mean = s / (float)Mm;
  const float var  = q / (float)Mm - mean*mean;
  const float sc = g[c] * rsqrtf(var + 1e-5f);
  scale[c] = sc; shift[c] = bb[c] - mean*sc;
}

__global__ __launch_bounds__(256)
void bn_silu(const unsigned short* __restrict__ z, const float* __restrict__ scale,
             const float* __restrict__ shift, unsigned short* __restrict__ out)
{
  const int id = blockIdx.x*256 + threadIdx.x;
  if (id >= Mm*96) return;
  const int row = id / 96, c8 = (id % 96) * 8;
  bf16x8 v = *(const bf16x8*)&z[(size_t)row*Dd + c8];
  bf16x8 o;
#pragma unroll
  for (int e = 0; e < 8; e++) {
    float t = (float)v[e] * scale[c8+e] + shift[c8+e];
    o[e] = (__bf16)(t / (1.f + __expf(-t)));
  }
  *(bf16x8*)&out[(size_t)row*Dd + c8] = o;
}

// ---------------- host ----------------
extern "C" void kernel_launch(void* const* d_in, const int* in_sizes, int n_in,
                              void* d_out, int out_size, void* d_ws, size_t ws_size,
                              hipStream_t stream)
{
  const float* x        = (const float*)d_in[0];
  const float* ff1_ln_g = (const float*)d_in[1];
  const float* ff1_ln_b = (const float*)d_in[2];
  const float* ff1_w1   = (const float*)d_in[3];
  const float* ff1_b1   = (const float*)d_in[4];
  const float* ff1_w2   = (const float*)d_in[5];
  const float* ff1_b2   = (const float*)d_in[6];
  const float* attn_ln_g= (const float*)d_in[7];
  const float* attn_ln_b= (const float*)d_in[8];
  const float* qkv_w    = (const float*)d_in[9];
  const float* qkv_b    = (const float*)d_in[10];
  const float* proj_w   = (const float*)d_in[11];
  const float* proj_b   = (const float*)d_in[12];
  const float* rel_tab  = (const float*)d_in[13];
  const float* conv_ln_g= (const float*)d_in[14];
  const float* conv_ln_b= (const float*)d_in[15];
  const float* pwin_w   = (const float*)d_in[16];
  const float* pwin_b   = (const float*)d_in[17];
  const float* dw_w     = (const float*)d_in[18];
  const float* dw_b     = (const float*)d_in[19];
  const float* bn_g     = (const float*)d_in[20];
  const float* bn_b     = (const float*)d_in[21];
  const float* pwout_w  = (const float*)d_in[22];
  const float* pwout_b  = (const float*)d_in[23];
  const float* ff2_ln_g = (const float*)d_in[24];
  const float* ff2_ln_b = (const float*)d_in[25];
  const float* ff2_w1   = (const float*)d_in[26];
  const float* ff2_b1   = (const float*)d_in[27];
  const float* ff2_w2   = (const float*)d_in[28];
  const float* ff2_b2   = (const float*)d_in[29];
  const float* fin_ln_g = (const float*)d_in[30];
  const float* fin_ln_b = (const float*)d_in[31];

  char* ws = (char*)d_ws;
  size_t off = 0;
  auto alloc = [&](size_t bytes) { char* p = ws + off; off += (bytes + 255) & ~(size_t)255; return p; };
  unsigned short* wt_ff1_1 = (unsigned short*)alloc((size_t)3072*768*2);
  unsigned short* wt_ff1_2 = (unsigned short*)alloc((size_t)768*3072*2);
  unsigned short* wt_qkv   = (unsigned short*)alloc((size_t)2304*768*2);
  unsigned short* wt_proj  = (unsigned short*)alloc((size_t)768*768*2);
  unsigned short* wt_pwin  = (unsigned short*)alloc((size_t)1536*768*2);
  unsigned short* wt_pwout = (unsigned short*)alloc((size_t)768*768*2);
  unsigned short* wt_ff2_1 = (unsigned short*)alloc((size_t)3072*768*2);
  unsigned short* wt_ff2_2 = (unsigned short*)alloc((size_t)768*3072*2);
  unsigned short* ybf      = (unsigned short*)alloc((size_t)Mm*768*2);
  unsigned short* big      = (unsigned short*)alloc((size_t)Mm*3072*2);
  unsigned short* abuf     = (unsigned short*)alloc((size_t)Mm*768*2);
  unsigned short* xbf      = (unsigned short*)alloc((size_t)Mm*768*2);   // bf16 residual
  float* psum    = (float*)alloc((size_t)256*768*4);
  float* psq     = (float*)alloc((size_t)256*768*4);
  float* bnscale = (float*)alloc((size_t)768*4);
  float* bnshift = (float*)alloc((size_t)768*4);
  float* dwwT    = (float*)alloc((size_t)9*768*4);
  float* bperm   = (float*)alloc((size_t)1536*4);
  if (off > ws_size) return;

  // vtr lives in big's unused tail (qkv rows use pitch 2304 of the 3072 alloc)
  unsigned short* vtr = big + (size_t)Mm*2304;

  const dim3 tb(256);

  // --- unified weight prep (1 dispatch) ---
  prep_all<<<14107, tb, 0, stream>>>(ff1_w1, ff1_w2, qkv_w, proj_w, ff2_w1, ff2_w2,
                                     pwin_w, pwin_b, pwout_w, dw_w,
                                     wt_ff1_1, wt_ff1_2, wt_qkv, wt_proj,
                                     wt_ff2_1, wt_ff2_2, wt_pwin, bperm,
                                     wt_pwout, dwwT);

  // --- FFN1: xbf = bf16(x + 0.5*FFN(LN(x))) ---
  ln_kernel<false,true><<<Mm/4, tb, 0, stream>>>(x, ff1_ln_g, ff1_ln_b, ybf);
  gemm_bt<1,128><<<dim3(3072/128, Mm/128), tb, 0, stream>>>(ybf, wt_ff1_1, ff1_b1, big, nullptr, nullptr, nullptr, Mm, 3072, 768, 0.f);
  gemm_bt<4,64><<<dim3(768/64, Mm/128), tb, 0, stream>>>(big, wt_ff1_2, ff1_b2, nullptr, xbf, x, nullptr, Mm, 768, 3072, 0.5f);

  // --- attention (qkv GEMM writes V transposed into vtr via EPI5) ---
  ln_kernel<true,true><<<Mm/4, tb, 0, stream>>>(xbf, attn_ln_g, attn_ln_b, ybf);
  gemm_bt<5,128><<<dim3(2304/128, Mm/128), tb, 0, stream>>>(ybf, wt_qkv, qkv_b, big, nullptr, nullptr, vtr, Mm, 2304, 768, 0.f);
  attn_kernel<<<dim3(Bb*Hh, Nn/128), dim3(512), 0, stream>>>(big, vtr, rel_tab, abuf);
  gemm_bt<2,64><<<dim3(768/64, Mm/128), tb, 0, stream>>>(abuf, wt_proj, proj_b, nullptr, xbf, nullptr, nullptr, Mm, 768, 768, 1.0f);

  // --- conv module ---
  ln_kernel<true,true><<<Mm/4, tb, 0, stream>>>(xbf, conv_ln_g, conv_ln_b, ybf);
  gemm_bt<3,128><<<dim3(1536/128, Mm/128), tb, 0, stream>>>(ybf, wt_pwin, bperm, abuf, nullptr, nullptr, nullptr, Mm, 1536, 768, 0.f);
  dwconv<<<((Mm/4)*96)/256, tb, 0, stream>>>(abuf, dwwT, dw_b, ybf);
  bn_part<<<256, dim3(192), 0, stream>>>(ybf, psum, psq);
  bn_final<<<3, tb, 0, stream>>>(psum, psq, bn_g, bn_b, bnscale, bnshift);
  bn_silu<<<(Mm*96)/256, tb, 0, stream>>>(ybf, bnscale, bnshift, abuf);
  gemm_bt<2,64><<<dim3(768/64, Mm/128), tb, 0, stream>>>(abuf, wt_pwout, pwout_b, nullptr, xbf, nullptr, nullptr, Mm, 768, 768, 1.0f);

  // --- FFN2 ---
  ln_kernel<true,true><<<Mm/4, tb, 0, stream>>>(xbf, ff2_ln_g, ff2_ln_b, ybf);
  gemm_bt<1,128><<<dim3(3072/128, Mm/128), tb, 0, stream>>>(ybf, wt_ff2_1, ff2_b1, big, nullptr, nullptr, nullptr, Mm, 3072, 768, 0.f);
  gemm_bt<2,64><<<dim3(768/64, Mm/128), tb, 0, stream>>>(big, wt_ff2_2, ff2_b2, nullptr, xbf, nullptr, nullptr, Mm, 768, 3072, 0.5f);

  // --- final LN: reads bf16 residual, writes fp32 d_out ---
  ln_kernel<true,false><<<Mm/4, tb, 0, stream>>>(xbf, fin_ln_g, fin_ln_b, d_out);
}